// Round 1
// baseline (4781.246 us; speedup 1.0000x reference)
//
#include <hip/hip_runtime.h>
#include <cstddef>

#define DB 4
#define DL 1024
#define DD 1024
#define DH 16
#define DF 4096

// ---------------------------------------------------------------- transforms
// Wdc_t[(k*D + i)*D + o] = W_dc[(o*D + i)*3 + k]
__global__ __launch_bounds__(256) void tdc_kernel(const float* __restrict__ Wdc,
                                                  float* __restrict__ Wt) {
    int idx = blockIdx.x * 256 + threadIdx.x;       // 3*D*D total
    int o = idx & 1023;
    int rest = idx >> 10;
    int i = rest & 1023;
    int k = rest >> 10;
    Wt[idx] = Wdc[((size_t)o * 1024 + i) * 3 + k];
}

// Wdec_t[s][(k*D + i)*D + o] = W_dec[((s*D + o)*D + i)*2 + k]
__global__ __launch_bounds__(256) void tdec_kernel(const float* __restrict__ Wdec,
                                                   float* __restrict__ Wt) {
    int idx = blockIdx.x * 256 + threadIdx.x;       // 3*2*D*D total
    int o = idx & 1023;
    int rest = idx >> 10;
    int i = rest & 1023;
    rest >>= 10;
    int k = rest & 1;
    int s = rest >> 1;
    Wt[idx] = Wdec[(((size_t)(s * 1024 + o)) * 1024 + i) * 2 + k];
}

// softmax of agg_logits (S=4) + entropy aux loss
__global__ void aux_kernel(const float* __restrict__ logits,
                           float* __restrict__ w, float* __restrict__ aux) {
    if (threadIdx.x == 0 && blockIdx.x == 0) {
        float l0 = logits[0], l1 = logits[1], l2 = logits[2], l3 = logits[3];
        float m = fmaxf(fmaxf(l0, l1), fmaxf(l2, l3));
        float e0 = __expf(l0 - m), e1 = __expf(l1 - m);
        float e2 = __expf(l2 - m), e3 = __expf(l3 - m);
        float s = e0 + e1 + e2 + e3;
        float w0 = e0 / s, w1 = e1 / s, w2 = e2 / s, w3 = e3 / s;
        w[0] = w0; w[1] = w1; w[2] = w2; w[3] = w3;
        *aux = -(w0 * logf(w0 + 1e-9f) + w1 * logf(w1 + 1e-9f) +
                 w2 * logf(w2 + 1e-9f) + w3 * logf(w3 + 1e-9f));
    }
}

// ---------------------------------------------------------------- GEMM
// C[M,N] = act(A[M,K] @ B[K,N] + bias). ACT: 0 none, 1 exact GELU.
// M,N multiples of 64; K multiple of 16.
template <int ACT>
__global__ __launch_bounds__(256) void gemm_kernel(
    const float* __restrict__ A, const float* __restrict__ Bm,
    const float* __restrict__ bias, float* __restrict__ C,
    int M, int N, int K) {
    __shared__ float As[16][68];
    __shared__ float Bs[16][68];
    int tid = threadIdx.x;
    int tx = tid & 15, ty = tid >> 4;
    int m0 = blockIdx.y << 6, n0 = blockIdx.x << 6;
    int a_m = tid >> 2, a_k = (tid & 3) << 2;
    int b_k = tid >> 4, b_n = (tid & 15) << 2;
    const float* Aptr = A + (size_t)(m0 + a_m) * K + a_k;
    const float* Bptr = Bm + (size_t)b_k * N + n0 + b_n;
    float acc[4][4] = {};
    for (int k0 = 0; k0 < K; k0 += 16) {
        float4 av = *(const float4*)(Aptr + k0);
        float4 bv = *(const float4*)(Bptr + (size_t)k0 * N);
        As[a_k + 0][a_m] = av.x;
        As[a_k + 1][a_m] = av.y;
        As[a_k + 2][a_m] = av.z;
        As[a_k + 3][a_m] = av.w;
        *(float4*)&Bs[b_k][b_n] = bv;
        __syncthreads();
#pragma unroll
        for (int kk = 0; kk < 16; kk++) {
            float4 a4 = *(const float4*)&As[kk][ty << 2];
            float4 b4 = *(const float4*)&Bs[kk][tx << 2];
            float ar[4] = {a4.x, a4.y, a4.z, a4.w};
            float br[4] = {b4.x, b4.y, b4.z, b4.w};
#pragma unroll
            for (int r = 0; r < 4; r++)
#pragma unroll
                for (int c = 0; c < 4; c++)
                    acc[r][c] = fmaf(ar[r], br[c], acc[r][c]);
        }
        __syncthreads();
    }
#pragma unroll
    for (int r = 0; r < 4; r++) {
        int m = m0 + (ty << 2) + r;
        float vals[4];
#pragma unroll
        for (int c = 0; c < 4; c++) {
            float v = acc[r][c];
            if (bias) v += bias[n0 + (tx << 2) + c];
            if (ACT == 1) v = 0.5f * v * (1.0f + erff(v * 0.70710678118654752f));
            vals[c] = v;
        }
        float4 o = make_float4(vals[0], vals[1], vals[2], vals[3]);
        *(float4*)&C[(size_t)m * N + n0 + (tx << 2)] = o;
    }
}

// ---------------------------------------------------------------- dilated conv
// xc = relu(dilconv(x; k=3, dil=2, pad=2) + b). Wt layout [3][D][D] (k,i,o).
__global__ __launch_bounds__(256) void convdil_kernel(
    const float* __restrict__ x, const float* __restrict__ Wt,
    const float* __restrict__ bvec, float* __restrict__ out) {
    __shared__ float As[16][68];
    __shared__ float Bs[16][68];
    int tid = threadIdx.x;
    int tx = tid & 15, ty = tid >> 4;
    int m0 = blockIdx.y << 6, n0 = blockIdx.x << 6;
    int a_m = tid >> 2, a_k = (tid & 3) << 2;
    int b_k = tid >> 4, b_n = (tid & 15) << 2;
    int mrow = m0 + a_m;
    int bb = mrow >> 10, ll = mrow & 1023;
    float acc[4][4] = {};
    for (int kp = 0; kp < 3; kp++) {
        int lsrc = ll + 2 * kp - 2;
        bool valid = (lsrc >= 0) && (lsrc < DL);
        const float* xrow = x + ((size_t)(bb << 10) + (size_t)(valid ? lsrc : 0)) * DD + a_k;
        const float* Wp = Wt + (size_t)kp * DD * DD + (size_t)b_k * DD + n0 + b_n;
        for (int k0 = 0; k0 < DD; k0 += 16) {
            float4 av = valid ? *(const float4*)(xrow + k0) : make_float4(0.f, 0.f, 0.f, 0.f);
            float4 bv = *(const float4*)(Wp + (size_t)k0 * DD);
            As[a_k + 0][a_m] = av.x;
            As[a_k + 1][a_m] = av.y;
            As[a_k + 2][a_m] = av.z;
            As[a_k + 3][a_m] = av.w;
            *(float4*)&Bs[b_k][b_n] = bv;
            __syncthreads();
#pragma unroll
            for (int kk = 0; kk < 16; kk++) {
                float4 a4 = *(const float4*)&As[kk][ty << 2];
                float4 b4 = *(const float4*)&Bs[kk][tx << 2];
                float ar[4] = {a4.x, a4.y, a4.z, a4.w};
                float br[4] = {b4.x, b4.y, b4.z, b4.w};
#pragma unroll
                for (int r = 0; r < 4; r++)
#pragma unroll
                    for (int c = 0; c < 4; c++)
                        acc[r][c] = fmaf(ar[r], br[c], acc[r][c]);
            }
            __syncthreads();
        }
    }
#pragma unroll
    for (int r = 0; r < 4; r++) {
        int m = m0 + (ty << 2) + r;
        float vals[4];
#pragma unroll
        for (int c = 0; c < 4; c++)
            vals[c] = fmaxf(acc[r][c] + bvec[n0 + (tx << 2) + c], 0.0f);
        float4 o = make_float4(vals[0], vals[1], vals[2], vals[3]);
        *(float4*)&out[(size_t)m * DD + n0 + (tx << 2)] = o;
    }
}

// ---------------------------------------------------------------- K transpose
// kT[(b*H+h)*64 + d][j] = k[b, j, h*64 + d]
__global__ __launch_bounds__(256) void ktrans_kernel(const float* __restrict__ kin,
                                                     float* __restrict__ kout, int Ls) {
    __shared__ float tile[32][33];
    int j0 = blockIdx.x << 5;
    int d0 = blockIdx.y << 5;
    int by = blockIdx.z;                 // b*H + h
    int b = by >> 4, h = by & 15;
    int tid = threadIdx.x;
    int cc = tid & 31, rr = tid >> 5;    // 8 rows per pass
#pragma unroll
    for (int p = 0; p < 4; p++) {
        int jj = (p << 3) + rr;
        tile[jj][cc] = kin[((size_t)(b * Ls + j0 + jj)) * DD + (h << 6) + d0 + cc];
    }
    __syncthreads();
#pragma unroll
    for (int p = 0; p < 4; p++) {
        int dd = (p << 3) + rr;
        kout[((size_t)by * 64 + d0 + dd) * Ls + j0 + cc] = tile[cc][dd];
    }
}

// ---------------------------------------------------------------- attention
// 4 query rows per block, 256 threads. out (+)= w[s] * softmax(q kT / 8) v
__global__ __launch_bounds__(256) void attn_kernel(
    const float* __restrict__ q, const float* __restrict__ kT,
    const float* __restrict__ v, const float* __restrict__ wagg,
    float* __restrict__ out, int Ls, int sidx) {
    __shared__ float qs[4][64];
    __shared__ float sc[1024][4];
    __shared__ float part[4][64];
    __shared__ float red4[4][4];
    int tid = threadIdx.x;
    int by = blockIdx.y;                 // b*H + h
    int b = by >> 4, h = by & 15;
    int l0 = blockIdx.x << 2;
    {
        int r = tid >> 6, d = tid & 63;
        qs[r][d] = q[((size_t)(b * DL + l0 + r)) * DD + (h << 6) + d];
    }
    __syncthreads();
    const float inv_s = 0.125f;          // 1/sqrt(64)
    int nj = (Ls + 255) >> 8;
    float acc[4][4];
#pragma unroll
    for (int jj = 0; jj < 4; jj++)
#pragma unroll
        for (int r = 0; r < 4; r++) acc[jj][r] = 0.f;
    const float* kbase = kT + (size_t)by * 64 * Ls;
    for (int d4 = 0; d4 < 64; d4 += 4) {
        float4 q0 = *(const float4*)&qs[0][d4];
        float4 q1 = *(const float4*)&qs[1][d4];
        float4 q2 = *(const float4*)&qs[2][d4];
        float4 q3 = *(const float4*)&qs[3][d4];
        const float* kc = kbase + (size_t)d4 * Ls;
        for (int jj = 0; jj < nj; jj++) {
            int jcur = tid + (jj << 8);
            if (jcur < Ls) {
                float k0v = kc[jcur];
                float k1v = kc[jcur + Ls];
                float k2v = kc[jcur + 2 * Ls];
                float k3v = kc[jcur + 3 * Ls];
                acc[jj][0] += q0.x * k0v + q0.y * k1v + q0.z * k2v + q0.w * k3v;
                acc[jj][1] += q1.x * k0v + q1.y * k1v + q1.z * k2v + q1.w * k3v;
                acc[jj][2] += q2.x * k0v + q2.y * k1v + q2.z * k2v + q2.w * k3v;
                acc[jj][3] += q3.x * k0v + q3.y * k1v + q3.z * k2v + q3.w * k3v;
            }
        }
    }
    for (int jj = 0; jj < nj; jj++) {
        int jcur = tid + (jj << 8);
        if (jcur < Ls) {
            sc[jcur][0] = acc[jj][0] * inv_s;
            sc[jcur][1] = acc[jj][1] * inv_s;
            sc[jcur][2] = acc[jj][2] * inv_s;
            sc[jcur][3] = acc[jj][3] * inv_s;
        }
    }
    __syncthreads();
    // rowwise max (rows are float4 components)
    float4 lm = make_float4(-1e30f, -1e30f, -1e30f, -1e30f);
    for (int j = tid; j < Ls; j += 256) {
        float4 s4 = *(const float4*)&sc[j][0];
        lm.x = fmaxf(lm.x, s4.x); lm.y = fmaxf(lm.y, s4.y);
        lm.z = fmaxf(lm.z, s4.z); lm.w = fmaxf(lm.w, s4.w);
    }
#pragma unroll
    for (int o = 32; o > 0; o >>= 1) {
        lm.x = fmaxf(lm.x, __shfl_down(lm.x, o, 64));
        lm.y = fmaxf(lm.y, __shfl_down(lm.y, o, 64));
        lm.z = fmaxf(lm.z, __shfl_down(lm.z, o, 64));
        lm.w = fmaxf(lm.w, __shfl_down(lm.w, o, 64));
    }
    int lane = tid & 63, wid = tid >> 6;
    if (lane == 0) { red4[wid][0] = lm.x; red4[wid][1] = lm.y; red4[wid][2] = lm.z; red4[wid][3] = lm.w; }
    __syncthreads();
    float4 m4;
    m4.x = fmaxf(fmaxf(red4[0][0], red4[1][0]), fmaxf(red4[2][0], red4[3][0]));
    m4.y = fmaxf(fmaxf(red4[0][1], red4[1][1]), fmaxf(red4[2][1], red4[3][1]));
    m4.z = fmaxf(fmaxf(red4[0][2], red4[1][2]), fmaxf(red4[2][2], red4[3][2]));
    m4.w = fmaxf(fmaxf(red4[0][3], red4[1][3]), fmaxf(red4[2][3], red4[3][3]));
    __syncthreads();
    // exp + sum
    float4 lsum = make_float4(0.f, 0.f, 0.f, 0.f);
    for (int j = tid; j < Ls; j += 256) {
        float4 s4 = *(const float4*)&sc[j][0];
        s4.x = __expf(s4.x - m4.x); s4.y = __expf(s4.y - m4.y);
        s4.z = __expf(s4.z - m4.z); s4.w = __expf(s4.w - m4.w);
        *(float4*)&sc[j][0] = s4;
        lsum.x += s4.x; lsum.y += s4.y; lsum.z += s4.z; lsum.w += s4.w;
    }
#pragma unroll
    for (int o = 32; o > 0; o >>= 1) {
        lsum.x += __shfl_down(lsum.x, o, 64);
        lsum.y += __shfl_down(lsum.y, o, 64);
        lsum.z += __shfl_down(lsum.z, o, 64);
        lsum.w += __shfl_down(lsum.w, o, 64);
    }
    if (lane == 0) { red4[wid][0] = lsum.x; red4[wid][1] = lsum.y; red4[wid][2] = lsum.z; red4[wid][3] = lsum.w; }
    __syncthreads();
    float sum4[4];
#pragma unroll
    for (int r = 0; r < 4; r++)
        sum4[r] = red4[0][r] + red4[1][r] + red4[2][r] + red4[3][r];
    __syncthreads();
    // PV: wave-uniform j per group, coalesced v rows
    int d = tid & 63, g = tid >> 6;
    float pa[4] = {0.f, 0.f, 0.f, 0.f};
    for (int j = g; j < Ls; j += 4) {
        float vv = v[((size_t)(b * Ls + j)) * DD + (h << 6) + d];
        float4 p4 = *(const float4*)&sc[j][0];
        pa[0] += p4.x * vv; pa[1] += p4.y * vv; pa[2] += p4.z * vv; pa[3] += p4.w * vv;
    }
    float wsc = wagg[sidx];
#pragma unroll
    for (int r = 0; r < 4; r++) {
        part[g][d] = pa[r];
        __syncthreads();
        if (g == 0) {
            float o = (part[0][d] + part[1][d] + part[2][d] + part[3][d]) * wsc / sum4[r];
            size_t oi = ((size_t)(b * DL + l0 + r)) * DD + (h << 6) + d;
            if (sidx == 0) out[oi] = o; else out[oi] += o;
        }
        __syncthreads();
    }
}

// ---------------------------------------------------------------- add + LN
__global__ __launch_bounds__(256) void addln_kernel(
    const float* __restrict__ a, const float* __restrict__ bsrc,
    const float* __restrict__ gam, const float* __restrict__ bet,
    float* __restrict__ out) {
    __shared__ float redA[4], redB[4];
    int row = blockIdx.x, tid = threadIdx.x;
    size_t base = (size_t)row * DD + (tid << 2);
    float4 av = *(const float4*)&a[base];
    float4 bv = *(const float4*)&bsrc[base];
    float s0 = av.x + bv.x, s1 = av.y + bv.y, s2 = av.z + bv.z, s3 = av.w + bv.w;
    float lsum = s0 + s1 + s2 + s3;
    float lsq = s0 * s0 + s1 * s1 + s2 * s2 + s3 * s3;
#pragma unroll
    for (int o = 32; o > 0; o >>= 1) {
        lsum += __shfl_down(lsum, o, 64);
        lsq += __shfl_down(lsq, o, 64);
    }
    int lane = tid & 63, wid = tid >> 6;
    if (lane == 0) { redA[wid] = lsum; redB[wid] = lsq; }
    __syncthreads();
    float tsum = redA[0] + redA[1] + redA[2] + redA[3];
    float tsq = redB[0] + redB[1] + redB[2] + redB[3];
    float mean = tsum * (1.0f / DD);
    float var = tsq * (1.0f / DD) - mean * mean;
    float rstd = rsqrtf(var + 1e-5f);
    float4 gv = *(const float4*)&gam[tid << 2];
    float4 bev = *(const float4*)&bet[tid << 2];
    float4 o;
    o.x = (s0 - mean) * rstd * gv.x + bev.x;
    o.y = (s1 - mean) * rstd * gv.y + bev.y;
    o.z = (s2 - mean) * rstd * gv.z + bev.z;
    o.w = (s3 - mean) * rstd * gv.w + bev.w;
    *(float4*)&out[base] = o;
}

// ---------------------------------------------------------------- launcher
extern "C" void kernel_launch(void* const* d_in, const int* in_sizes, int n_in,
                              void* d_out, int out_size, void* d_ws, size_t ws_size,
                              hipStream_t stream) {
    (void)in_sizes; (void)n_in; (void)out_size; (void)ws_size;
    const float* x   = (const float*)d_in[0];
    const float* Wdc = (const float*)d_in[1];
    const float* bdc = (const float*)d_in[2];
    const float* Wdec= (const float*)d_in[3];
    const float* Wq  = (const float*)d_in[4];
    const float* Wk  = (const float*)d_in[5];
    const float* Wv  = (const float*)d_in[6];
    const float* Wo  = (const float*)d_in[7];
    const float* agg = (const float*)d_in[8];
    const float* g1  = (const float*)d_in[9];
    const float* be1 = (const float*)d_in[10];
    const float* g2  = (const float*)d_in[11];
    const float* be2 = (const float*)d_in[12];
    const float* W1  = (const float*)d_in[13];
    const float* b1  = (const float*)d_in[14];
    const float* W2  = (const float*)d_in[15];
    const float* b2  = (const float*)d_in[16];
    float* out = (float*)d_out;

    float* ws = (float*)d_ws;
    size_t off = 0;
    auto alloc = [&](size_t n) { float* p = ws + off; off += n; return p; };
    float* wdct   = alloc((size_t)3 * DD * DD);
    float* wdect  = alloc((size_t)6 * DD * DD);
    float* wagg   = alloc(64);
    float* xc     = alloc((size_t)DB * DL * DD);
    float* s1     = alloc((size_t)DB * (DL / 2) * DD);
    float* s2     = alloc((size_t)DB * (DL / 4) * DD);
    float* s3     = alloc((size_t)DB * (DL / 8) * DD);
    float* attacc = alloc((size_t)DB * DL * DD);
    float* x1     = alloc((size_t)DB * DL * DD);
    float* mahab  = alloc((size_t)DB * DL * DD);
    float* qb     = alloc((size_t)DB * DL * DD);
    float* kb     = alloc((size_t)DB * DL * DD);
    float* kt     = alloc((size_t)DB * DL * DD);
    float* vb     = alloc((size_t)DB * DL * DD);
    float* hb = qb;      // 16M floats spanning qb..vb (free after attention)
    float* fb = attacc;  // free after maha GEMM

    dim3 blk(256);
    tdc_kernel<<<dim3(3 * DD * DD / 256), blk, 0, stream>>>(Wdc, wdct);
    tdec_kernel<<<dim3(6 * DD * DD / 256), blk, 0, stream>>>(Wdec, wdect);
    aux_kernel<<<dim3(1), dim3(64), 0, stream>>>(agg, wagg, out + (size_t)DB * DL * DD);

    // 1. dilated conv + relu
    convdil_kernel<<<dim3(DD / 64, DB * DL / 64), blk, 0, stream>>>(x, wdct, bdc, xc);

    // 2. decomposition convs as GEMMs over [B*Ls/2, 2D]
    gemm_kernel<0><<<dim3(DD / 64, (DB * DL / 2) / 64), blk, 0, stream>>>(
        xc, wdect, nullptr, s1, DB * DL / 2, DD, 2 * DD);
    gemm_kernel<0><<<dim3(DD / 64, (DB * DL / 4) / 64), blk, 0, stream>>>(
        s1, wdect + (size_t)2 * DD * DD, nullptr, s2, DB * DL / 4, DD, 2 * DD);
    gemm_kernel<0><<<dim3(DD / 64, (DB * DL / 8) / 64), blk, 0, stream>>>(
        s2, wdect + (size_t)4 * DD * DD, nullptr, s3, DB * DL / 8, DD, 2 * DD);

    // 3. multiscale attention, accumulated with aggregation weights
    const float* scl[4] = {xc, s1, s2, s3};
    for (int s = 0; s < 4; s++) {
        int Ls = DL >> s;
        int rows = DB * Ls;
        gemm_kernel<0><<<dim3(DD / 64, (DB * DL) / 64), blk, 0, stream>>>(
            xc, Wq + (size_t)s * DD * DD, nullptr, qb, DB * DL, DD, DD);
        gemm_kernel<0><<<dim3(DD / 64, rows / 64), blk, 0, stream>>>(
            scl[s], Wk + (size_t)s * DD * DD, nullptr, kb, rows, DD, DD);
        gemm_kernel<0><<<dim3(DD / 64, rows / 64), blk, 0, stream>>>(
            scl[s], Wv, nullptr, vb, rows, DD, DD);
        ktrans_kernel<<<dim3(Ls / 32, 2, DB * DH), blk, 0, stream>>>(kb, kt, Ls);
        attn_kernel<<<dim3(DL / 4, DB * DH), blk, 0, stream>>>(qb, kt, vb, wagg, attacc, Ls, s);
    }

    // 4. shared output projection after convex aggregation
    gemm_kernel<0><<<dim3(DD / 64, (DB * DL) / 64), blk, 0, stream>>>(
        attacc, Wo, nullptr, mahab, DB * DL, DD, DD);

    // 5. residual + LN1
    addln_kernel<<<dim3(DB * DL), blk, 0, stream>>>(x, mahab, g1, be1, x1);

    // 6. FFN with exact GELU
    gemm_kernel<1><<<dim3(DF / 64, (DB * DL) / 64), blk, 0, stream>>>(
        x1, W1, b1, hb, DB * DL, DF, DD);
    gemm_kernel<0><<<dim3(DD / 64, (DB * DL) / 64), blk, 0, stream>>>(
        hb, W2, b2, fb, DB * DL, DD, DF);

    // 7. residual + LN2 -> out
    addln_kernel<<<dim3(DB * DL), blk, 0, stream>>>(x1, fb, g2, be2, out);
}

// Round 2
// 3297.607 us; speedup vs baseline: 1.4499x; 1.4499x over previous
//
#include <hip/hip_runtime.h>
#include <cstddef>

#define DB 4
#define DL 1024
#define DD 1024
#define DH 16
#define DF 4096

typedef __attribute__((ext_vector_type(8))) short short8;
typedef __attribute__((ext_vector_type(4))) float float4v;

static __device__ __forceinline__ short f2bf(float f) {
    unsigned u = __float_as_uint(f);
    unsigned r = (u + 0x7FFFu + ((u >> 16) & 1u)) >> 16;   // RNE
    return (short)r;
}

// ---------------------------------------------------------------- transforms
// Wdc_t[(k*D + i)*D + o] = W_dc[(o*D + i)*3 + k]
__global__ __launch_bounds__(256) void tdc_kernel(const float* __restrict__ Wdc,
                                                  float* __restrict__ Wt) {
    int idx = blockIdx.x * 256 + threadIdx.x;       // 3*D*D total
    int o = idx & 1023;
    int rest = idx >> 10;
    int i = rest & 1023;
    int k = rest >> 10;
    Wt[idx] = Wdc[((size_t)o * 1024 + i) * 3 + k];
}

// Wdec_t[s][(k*D + i)*D + o] = W_dec[((s*D + o)*D + i)*2 + k]
__global__ __launch_bounds__(256) void tdec_kernel(const float* __restrict__ Wdec,
                                                   float* __restrict__ Wt) {
    int idx = blockIdx.x * 256 + threadIdx.x;       // 3*2*D*D total
    int o = idx & 1023;
    int rest = idx >> 10;
    int i = rest & 1023;
    rest >>= 10;
    int k = rest & 1;
    int s = rest >> 1;
    Wt[idx] = Wdec[(((size_t)(s * 1024 + o)) * 1024 + i) * 2 + k];
}

// softmax of agg_logits (S=4) + entropy aux loss
__global__ void aux_kernel(const float* __restrict__ logits,
                           float* __restrict__ w, float* __restrict__ aux) {
    if (threadIdx.x == 0 && blockIdx.x == 0) {
        float l0 = logits[0], l1 = logits[1], l2 = logits[2], l3 = logits[3];
        float m = fmaxf(fmaxf(l0, l1), fmaxf(l2, l3));
        float e0 = __expf(l0 - m), e1 = __expf(l1 - m);
        float e2 = __expf(l2 - m), e3 = __expf(l3 - m);
        float s = e0 + e1 + e2 + e3;
        float w0 = e0 / s, w1 = e1 / s, w2 = e2 / s, w3 = e3 / s;
        w[0] = w0; w[1] = w1; w[2] = w2; w[3] = w3;
        *aux = -(w0 * logf(w0 + 1e-9f) + w1 * logf(w1 + 1e-9f) +
                 w2 * logf(w2 + 1e-9f) + w3 * logf(w3 + 1e-9f));
    }
}

// ---------------------------------------------------------------- GEMM
// C[M,N] = act(A[M,K] @ B[K,N] + bias). ACT: 0 none, 1 exact GELU.
// OBF: 0 fp32 out, 1 bf16 out. M,N multiples of 64; K multiple of 16.
template <int ACT, int OBF>
__global__ __launch_bounds__(256) void gemm_kernel(
    const float* __restrict__ A, const float* __restrict__ Bm,
    const float* __restrict__ bias, void* __restrict__ Cv,
    int M, int N, int K) {
    __shared__ float As[16][68];
    __shared__ float Bs[16][68];
    int tid = threadIdx.x;
    int tx = tid & 15, ty = tid >> 4;
    int m0 = blockIdx.y << 6, n0 = blockIdx.x << 6;
    int a_m = tid >> 2, a_k = (tid & 3) << 2;
    int b_k = tid >> 4, b_n = (tid & 15) << 2;
    const float* Aptr = A + (size_t)(m0 + a_m) * K + a_k;
    const float* Bptr = Bm + (size_t)b_k * N + n0 + b_n;
    float acc[4][4] = {};
    for (int k0 = 0; k0 < K; k0 += 16) {
        float4 av = *(const float4*)(Aptr + k0);
        float4 bv = *(const float4*)(Bptr + (size_t)k0 * N);
        As[a_k + 0][a_m] = av.x;
        As[a_k + 1][a_m] = av.y;
        As[a_k + 2][a_m] = av.z;
        As[a_k + 3][a_m] = av.w;
        *(float4*)&Bs[b_k][b_n] = bv;
        __syncthreads();
#pragma unroll
        for (int kk = 0; kk < 16; kk++) {
            float4 a4 = *(const float4*)&As[kk][ty << 2];
            float4 b4 = *(const float4*)&Bs[kk][tx << 2];
            float ar[4] = {a4.x, a4.y, a4.z, a4.w};
            float br[4] = {b4.x, b4.y, b4.z, b4.w};
#pragma unroll
            for (int r = 0; r < 4; r++)
#pragma unroll
                for (int c = 0; c < 4; c++)
                    acc[r][c] = fmaf(ar[r], br[c], acc[r][c]);
        }
        __syncthreads();
    }
#pragma unroll
    for (int r = 0; r < 4; r++) {
        int m = m0 + (ty << 2) + r;
        float vals[4];
#pragma unroll
        for (int c = 0; c < 4; c++) {
            float v = acc[r][c];
            if (bias) v += bias[n0 + (tx << 2) + c];
            if (ACT == 1) v = 0.5f * v * (1.0f + erff(v * 0.70710678118654752f));
            vals[c] = v;
        }
        if (OBF) {
            short* C = (short*)Cv;
            ushort4 uo;
            uo.x = (unsigned short)f2bf(vals[0]);
            uo.y = (unsigned short)f2bf(vals[1]);
            uo.z = (unsigned short)f2bf(vals[2]);
            uo.w = (unsigned short)f2bf(vals[3]);
            *(ushort4*)&C[(size_t)m * N + n0 + (tx << 2)] = uo;
        } else {
            float* C = (float*)Cv;
            float4 o = make_float4(vals[0], vals[1], vals[2], vals[3]);
            *(float4*)&C[(size_t)m * N + n0 + (tx << 2)] = o;
        }
    }
}

// ---------------------------------------------------------------- dilated conv
// xc = relu(dilconv(x; k=3, dil=2, pad=2) + b). Wt layout [3][D][D] (k,i,o).
__global__ __launch_bounds__(256) void convdil_kernel(
    const float* __restrict__ x, const float* __restrict__ Wt,
    const float* __restrict__ bvec, float* __restrict__ out) {
    __shared__ float As[16][68];
    __shared__ float Bs[16][68];
    int tid = threadIdx.x;
    int tx = tid & 15, ty = tid >> 4;
    int m0 = blockIdx.y << 6, n0 = blockIdx.x << 6;
    int a_m = tid >> 2, a_k = (tid & 3) << 2;
    int b_k = tid >> 4, b_n = (tid & 15) << 2;
    int mrow = m0 + a_m;
    int bb = mrow >> 10, ll = mrow & 1023;
    float acc[4][4] = {};
    for (int kp = 0; kp < 3; kp++) {
        int lsrc = ll + 2 * kp - 2;
        bool valid = (lsrc >= 0) && (lsrc < DL);
        const float* xrow = x + ((size_t)(bb << 10) + (size_t)(valid ? lsrc : 0)) * DD + a_k;
        const float* Wp = Wt + (size_t)kp * DD * DD + (size_t)b_k * DD + n0 + b_n;
        for (int k0 = 0; k0 < DD; k0 += 16) {
            float4 av = valid ? *(const float4*)(xrow + k0) : make_float4(0.f, 0.f, 0.f, 0.f);
            float4 bv = *(const float4*)(Wp + (size_t)k0 * DD);
            As[a_k + 0][a_m] = av.x;
            As[a_k + 1][a_m] = av.y;
            As[a_k + 2][a_m] = av.z;
            As[a_k + 3][a_m] = av.w;
            *(float4*)&Bs[b_k][b_n] = bv;
            __syncthreads();
#pragma unroll
            for (int kk = 0; kk < 16; kk++) {
                float4 a4 = *(const float4*)&As[kk][ty << 2];
                float4 b4 = *(const float4*)&Bs[kk][tx << 2];
                float ar[4] = {a4.x, a4.y, a4.z, a4.w};
                float br[4] = {b4.x, b4.y, b4.z, b4.w};
#pragma unroll
                for (int r = 0; r < 4; r++)
#pragma unroll
                    for (int c = 0; c < 4; c++)
                        acc[r][c] = fmaf(ar[r], br[c], acc[r][c]);
            }
            __syncthreads();
        }
    }
#pragma unroll
    for (int r = 0; r < 4; r++) {
        int m = m0 + (ty << 2) + r;
        float vals[4];
#pragma unroll
        for (int c = 0; c < 4; c++)
            vals[c] = fmaxf(acc[r][c] + bvec[n0 + (tx << 2) + c], 0.0f);
        float4 o = make_float4(vals[0], vals[1], vals[2], vals[3]);
        *(float4*)&out[(size_t)m * DD + n0 + (tx << 2)] = o;
    }
}

// ---------------------------------------------------------------- V transpose
// vt[(b*H+h)*64 + d][j] (bf16) = v[b, j, h*64 + d] (fp32)
__global__ __launch_bounds__(256) void vtrans_kernel(const float* __restrict__ vin,
                                                     short* __restrict__ vout, int Ls) {
    __shared__ float tile[32][33];
    int j0 = blockIdx.x << 5;
    int d0 = blockIdx.y << 5;
    int by = blockIdx.z;                 // b*H + h
    int b = by >> 4, h = by & 15;
    int tid = threadIdx.x;
    int cc = tid & 31, rr = tid >> 5;    // 8 rows per pass
#pragma unroll
    for (int p = 0; p < 4; p++) {
        int jj = (p << 3) + rr;
        tile[jj][cc] = vin[((size_t)(b * Ls + j0 + jj)) * DD + (h << 6) + d0 + cc];
    }
    __syncthreads();
#pragma unroll
    for (int p = 0; p < 4; p++) {
        int dd = (p << 3) + rr;
        vout[((size_t)by * 64 + d0 + dd) * Ls + j0 + cc] = f2bf(tile[cc][dd]);
    }
}

// ---------------------------------------------------------------- attention
// Flash-style MFMA attention. Per wave: 16 q-rows, full K/V sweep in 64-key
// chunks. No __syncthreads (per-wave LDS slice only for the P C->A transform).
// out (+)= wagg[sidx] * softmax(Q K^T / 8) V
__global__ __launch_bounds__(256) void attn_mfma_kernel(
    const short* __restrict__ qb, const short* __restrict__ kb,
    const short* __restrict__ vt, const float* __restrict__ wagg,
    float* __restrict__ out, int Ls, int sidx) {
    __shared__ float plds[4][16][68];
    int tid = threadIdx.x;
    int w = tid >> 6, lane = tid & 63;
    int lq = lane & 15, quad = lane >> 4;
    int bh = blockIdx.y;
    int b = bh >> 4, h = bh & 15;
    int q0 = (blockIdx.x << 6) + (w << 4);

    // Q fragments (held in regs for the whole sweep)
    const short* qbase = qb + ((size_t)(b * DL + q0 + lq)) * DD + (h << 6);
    short8 qf0 = *(const short8*)(qbase + quad * 8);
    short8 qf1 = *(const short8*)(qbase + 32 + quad * 8);

    float4v O[4];
    float m_run[4], l_run[4];
#pragma unroll
    for (int t = 0; t < 4; t++) O[t] = (float4v){0.f, 0.f, 0.f, 0.f};
#pragma unroll
    for (int r = 0; r < 4; r++) { m_run[r] = -1e30f; l_run[r] = 0.f; }

    const short* kbase = kb + (size_t)b * Ls * DD + (h << 6);
    const short* vbase = vt + (size_t)bh * 64 * Ls;

    for (int c0 = 0; c0 < Ls; c0 += 64) {
        // S^ = Q K^T for 64 keys (4 n-tiles x 2 k-steps)
        float4v S[4];
#pragma unroll
        for (int t = 0; t < 4; t++) {
            S[t] = (float4v){0.f, 0.f, 0.f, 0.f};
            const short* kp = kbase + (size_t)(c0 + (t << 4) + lq) * DD;
            short8 kf0 = *(const short8*)(kp + quad * 8);
            short8 kf1 = *(const short8*)(kp + 32 + quad * 8);
            S[t] = __builtin_amdgcn_mfma_f32_16x16x32_bf16(qf0, kf0, S[t], 0, 0, 0);
            S[t] = __builtin_amdgcn_mfma_f32_16x16x32_bf16(qf1, kf1, S[t], 0, 0, 0);
        }
        // scale
#pragma unroll
        for (int t = 0; t < 4; t++)
#pragma unroll
            for (int r = 0; r < 4; r++) S[t][r] *= 0.125f;
        // online softmax: rows are q = quad*4 + r (same layout as O rows)
        float mx[4], rs[4], alpha[4];
#pragma unroll
        for (int r = 0; r < 4; r++) {
            float m01 = fmaxf(S[0][r], S[1][r]);
            float m23 = fmaxf(S[2][r], S[3][r]);
            float m = fmaxf(m01, m23);
            m = fmaxf(m, __shfl_xor(m, 1, 64));
            m = fmaxf(m, __shfl_xor(m, 2, 64));
            m = fmaxf(m, __shfl_xor(m, 4, 64));
            m = fmaxf(m, __shfl_xor(m, 8, 64));
            mx[r] = m;
        }
#pragma unroll
        for (int r = 0; r < 4; r++) {
            float m_new = fmaxf(m_run[r], mx[r]);
            alpha[r] = __expf(m_run[r] - m_new);
            m_run[r] = m_new;
            float s = 0.f;
#pragma unroll
            for (int t = 0; t < 4; t++) {
                float p = __expf(S[t][r] - m_new);
                S[t][r] = p;
                s += p;
            }
            s += __shfl_xor(s, 1, 64);
            s += __shfl_xor(s, 2, 64);
            s += __shfl_xor(s, 4, 64);
            s += __shfl_xor(s, 8, 64);
            rs[r] = s;
            l_run[r] = l_run[r] * alpha[r] + s;
        }
#pragma unroll
        for (int t = 0; t < 4; t++)
#pragma unroll
            for (int r = 0; r < 4; r++) O[t][r] *= alpha[r];
        // P: C-layout -> A-layout via per-wave LDS slice (no barrier needed)
#pragma unroll
        for (int t = 0; t < 4; t++)
#pragma unroll
            for (int r = 0; r < 4; r++)
                plds[w][(quad << 2) + r][(t << 4) + lq] = S[t][r];
#pragma unroll
        for (int ks = 0; ks < 2; ks++) {
            const float* pr = &plds[w][lq][(ks << 5) + (quad << 3)];
            float4v p0 = *(const float4v*)pr;
            float4v p1 = *(const float4v*)(pr + 4);
            short8 af;
            af[0] = f2bf(p0[0]); af[1] = f2bf(p0[1]);
            af[2] = f2bf(p0[2]); af[3] = f2bf(p0[3]);
            af[4] = f2bf(p1[0]); af[5] = f2bf(p1[1]);
            af[6] = f2bf(p1[2]); af[7] = f2bf(p1[3]);
#pragma unroll
            for (int t = 0; t < 4; t++) {
                short8 vf = *(const short8*)(vbase + (size_t)((t << 4) + lq) * Ls +
                                             c0 + (ks << 5) + quad * 8);
                O[t] = __builtin_amdgcn_mfma_f32_16x16x32_bf16(af, vf, O[t], 0, 0, 0);
            }
        }
    }
    float wsc = wagg[sidx];
    float inv[4];
#pragma unroll
    for (int r = 0; r < 4; r++) inv[r] = wsc / l_run[r];
#pragma unroll
    for (int r = 0; r < 4; r++) {
        int qout = q0 + (quad << 2) + r;
        size_t obase = ((size_t)(b * DL + qout)) * DD + (h << 6) + lq;
#pragma unroll
        for (int t = 0; t < 4; t++) {
            float val = O[t][r] * inv[r];
            size_t oi = obase + (t << 4);
            if (sidx == 0) out[oi] = val;
            else out[oi] += val;
        }
    }
}

// ---------------------------------------------------------------- add + LN
__global__ __launch_bounds__(256) void addln_kernel(
    const float* __restrict__ a, const float* __restrict__ bsrc,
    const float* __restrict__ gam, const float* __restrict__ bet,
    float* __restrict__ out) {
    __shared__ float redA[4], redB[4];
    int row = blockIdx.x, tid = threadIdx.x;
    size_t base = (size_t)row * DD + (tid << 2);
    float4 av = *(const float4*)&a[base];
    float4 bv = *(const float4*)&bsrc[base];
    float s0 = av.x + bv.x, s1 = av.y + bv.y, s2 = av.z + bv.z, s3 = av.w + bv.w;
    float lsum = s0 + s1 + s2 + s3;
    float lsq = s0 * s0 + s1 * s1 + s2 * s2 + s3 * s3;
#pragma unroll
    for (int o = 32; o > 0; o >>= 1) {
        lsum += __shfl_down(lsum, o, 64);
        lsq += __shfl_down(lsq, o, 64);
    }
    int lane = tid & 63, wid = tid >> 6;
    if (lane == 0) { redA[wid] = lsum; redB[wid] = lsq; }
    __syncthreads();
    float tsum = redA[0] + redA[1] + redA[2] + redA[3];
    float tsq = redB[0] + redB[1] + redB[2] + redB[3];
    float mean = tsum * (1.0f / DD);
    float var = tsq * (1.0f / DD) - mean * mean;
    float rstd = rsqrtf(var + 1e-5f);
    float4 gv = *(const float4*)&gam[tid << 2];
    float4 bev = *(const float4*)&bet[tid << 2];
    float4 o;
    o.x = (s0 - mean) * rstd * gv.x + bev.x;
    o.y = (s1 - mean) * rstd * gv.y + bev.y;
    o.z = (s2 - mean) * rstd * gv.z + bev.z;
    o.w = (s3 - mean) * rstd * gv.w + bev.w;
    *(float4*)&out[base] = o;
}

// ---------------------------------------------------------------- launcher
extern "C" void kernel_launch(void* const* d_in, const int* in_sizes, int n_in,
                              void* d_out, int out_size, void* d_ws, size_t ws_size,
                              hipStream_t stream) {
    (void)in_sizes; (void)n_in; (void)out_size; (void)ws_size;
    const float* x   = (const float*)d_in[0];
    const float* Wdc = (const float*)d_in[1];
    const float* bdc = (const float*)d_in[2];
    const float* Wdec= (const float*)d_in[3];
    const float* Wq  = (const float*)d_in[4];
    const float* Wk  = (const float*)d_in[5];
    const float* Wv  = (const float*)d_in[6];
    const float* Wo  = (const float*)d_in[7];
    const float* agg = (const float*)d_in[8];
    const float* g1  = (const float*)d_in[9];
    const float* be1 = (const float*)d_in[10];
    const float* g2  = (const float*)d_in[11];
    const float* be2 = (const float*)d_in[12];
    const float* W1  = (const float*)d_in[13];
    const float* b1  = (const float*)d_in[14];
    const float* W2  = (const float*)d_in[15];
    const float* b2  = (const float*)d_in[16];
    float* out = (float*)d_out;

    float* ws = (float*)d_ws;
    size_t off = 0;
    auto alloc = [&](size_t n) { float* p = ws + off; off += n; return p; };
    const size_t M1 = 1024 * 1024;
    float* wdct   = alloc(3 * M1);
    float* wdect  = alloc(6 * M1);
    float* wagg   = alloc(64);
    float* xc     = alloc(4 * M1);
    float* s1     = alloc(2 * M1);
    float* s2     = alloc(1 * M1);
    float* s3     = alloc(M1 / 2);
    float* attacc = alloc(4 * M1);
    float* x1     = alloc(4 * M1);
    float* mahab  = alloc(4 * M1);
    float* big    = alloc(16 * M1);   // attention buffers, later FFN hidden
    short* qbh = (short*)big;               // 4M bf16
    short* kbh = (short*)(big + 2 * M1);    // 4M bf16
    float* vb  = big + 4 * M1;              // 4M fp32
    short* vth = (short*)(big + 8 * M1);    // up to 4M bf16
    float* hb  = big;                       // FFN hidden (after attention done)
    float* fb  = attacc;                    // free after maha GEMM

    dim3 blk(256);
    tdc_kernel<<<dim3(3 * DD * DD / 256), blk, 0, stream>>>(Wdc, wdct);
    tdec_kernel<<<dim3(6 * DD * DD / 256), blk, 0, stream>>>(Wdec, wdect);
    aux_kernel<<<dim3(1), dim3(64), 0, stream>>>(agg, wagg, out + (size_t)DB * DL * DD);

    // 1. dilated conv + relu
    convdil_kernel<<<dim3(DD / 64, DB * DL / 64), blk, 0, stream>>>(x, wdct, bdc, xc);

    // 2. decomposition convs as GEMMs over [B*Ls/2, 2D]
    gemm_kernel<0, 0><<<dim3(DD / 64, (DB * DL / 2) / 64), blk, 0, stream>>>(
        xc, wdect, nullptr, s1, DB * DL / 2, DD, 2 * DD);
    gemm_kernel<0, 0><<<dim3(DD / 64, (DB * DL / 4) / 64), blk, 0, stream>>>(
        s1, wdect + (size_t)2 * DD * DD, nullptr, s2, DB * DL / 4, DD, 2 * DD);
    gemm_kernel<0, 0><<<dim3(DD / 64, (DB * DL / 8) / 64), blk, 0, stream>>>(
        s2, wdect + (size_t)4 * DD * DD, nullptr, s3, DB * DL / 8, DD, 2 * DD);

    // 3. multiscale attention (bf16 MFMA flash), accumulated with agg weights
    const float* scl[4] = {xc, s1, s2, s3};
    for (int s = 0; s < 4; s++) {
        int Ls = DL >> s;
        int rows = DB * Ls;
        gemm_kernel<0, 1><<<dim3(DD / 64, (DB * DL) / 64), blk, 0, stream>>>(
            xc, Wq + (size_t)s * DD * DD, nullptr, qbh, DB * DL, DD, DD);
        gemm_kernel<0, 1><<<dim3(DD / 64, rows / 64), blk, 0, stream>>>(
            scl[s], Wk + (size_t)s * DD * DD, nullptr, kbh, rows, DD, DD);
        gemm_kernel<0, 0><<<dim3(DD / 64, rows / 64), blk, 0, stream>>>(
            scl[s], Wv, nullptr, vb, rows, DD, DD);
        vtrans_kernel<<<dim3(Ls / 32, 2, DB * DH), blk, 0, stream>>>(vb, vth, Ls);
        attn_mfma_kernel<<<dim3(DL / 64, DB * DH), blk, 0, stream>>>(
            qbh, kbh, vth, wagg, attacc, Ls, s);
    }

    // 4. shared output projection after convex aggregation
    gemm_kernel<0, 0><<<dim3(DD / 64, (DB * DL) / 64), blk, 0, stream>>>(
        attacc, Wo, nullptr, mahab, DB * DL, DD, DD);

    // 5. residual + LN1
    addln_kernel<<<dim3(DB * DL), blk, 0, stream>>>(x, mahab, g1, be1, x1);

    // 6. FFN with exact GELU
    gemm_kernel<1, 0><<<dim3(DF / 64, (DB * DL) / 64), blk, 0, stream>>>(
        x1, W1, b1, hb, DB * DL, DF, DD);
    gemm_kernel<0, 0><<<dim3(DD / 64, (DB * DL) / 64), blk, 0, stream>>>(
        hb, W2, b2, fb, DB * DL, DD, DF);

    // 7. residual + LN2 -> out
    addln_kernel<<<dim3(DB * DL), blk, 0, stream>>>(x1, fb, g2, be2, out);
}

// Round 3
// 1200.346 us; speedup vs baseline: 3.9832x; 2.7472x over previous
//
#include <hip/hip_runtime.h>
#include <cstddef>

#define DB 4
#define DL 1024
#define DD 1024
#define DH 16
#define DF 4096

typedef __attribute__((ext_vector_type(8))) short short8;
typedef __attribute__((ext_vector_type(4))) float float4v;

static __device__ __forceinline__ short f2bf(float f) {
    unsigned u = __float_as_uint(f);
    unsigned r = (u + 0x7FFFu + ((u >> 16) & 1u)) >> 16;   // RNE
    return (short)r;
}

#define GLOAD_LDS16(gp, lp)                                                          \
    __builtin_amdgcn_global_load_lds(                                                \
        (const __attribute__((address_space(1))) void*)(gp),                         \
        (__attribute__((address_space(3))) void*)(lp), 16, 0, 0)

// ---------------------------------------------------------------- weight prep
// wdc_bt[k][o][i] = bf16(W_dc[(o*D + i)*3 + k])   (B^T per tap, [N=o][K=i])
__global__ __launch_bounds__(256) void wdcprep_kernel(const float* __restrict__ W,
                                                      short* __restrict__ Wt) {
    int idx = blockIdx.x * 256 + threadIdx.x;           // 3*D*D
    int i = idx & 1023;
    int o = (idx >> 10) & 1023;
    int k = idx >> 20;
    Wt[idx] = f2bf(W[((size_t)o * 1024 + i) * 3 + k]);
}

// wdec_bt[s][n][k2*D+i] = bf16(W_dec[((s*D+n)*D + i)*2 + k2])  ([N][K=2D])
__global__ __launch_bounds__(256) void wdecprep_kernel(const float* __restrict__ W,
                                                       short* __restrict__ Wt) {
    int idx = blockIdx.x * 256 + threadIdx.x;           // 3*2*D*D
    int i = idx & 1023;
    int k2 = (idx >> 10) & 1;
    int n = (idx >> 11) & 1023;
    int s = idx >> 21;
    Wt[idx] = f2bf(W[(((size_t)(s * 1024 + n)) * 1024 + i) * 2 + k2]);
}

// transpose-cast: in fp32 [K][N] -> out bf16 [N][K]
__global__ __launch_bounds__(256) void tc_kernel(const float* __restrict__ in,
                                                 short* __restrict__ outp, int K, int N) {
    __shared__ float tile[32][33];
    int n0 = blockIdx.x << 5, k0 = blockIdx.y << 5;
    int tid = threadIdx.x;
    int cc = tid & 31, rr = tid >> 5;
#pragma unroll
    for (int p = 0; p < 4; p++) {
        int kk = (p << 3) + rr;
        tile[kk][cc] = in[(size_t)(k0 + kk) * N + n0 + cc];
    }
    __syncthreads();
#pragma unroll
    for (int p = 0; p < 4; p++) {
        int nn = (p << 3) + rr;
        outp[(size_t)(n0 + nn) * K + k0 + cc] = f2bf(tile[cc][nn]);
    }
}

// zero-padded bf16 x: xpad[b][l+2][d] = bf16(x[b][l][d]), rows 0,1,L+2,L+3 = 0
__global__ __launch_bounds__(256) void xpad_kernel(const float* __restrict__ x,
                                                   short* __restrict__ xp) {
    int idx = blockIdx.x * 256 + threadIdx.x;           // 4*1028*1024
    int d = idx & 1023;
    int row = (idx >> 10) % 1028;
    int b = (idx >> 10) / 1028;
    int l = row - 2;
    float v = (l >= 0 && l < DL) ? x[((size_t)(b * DL + l)) * DD + d] : 0.f;
    xp[idx] = f2bf(v);
}

// fp32 -> bf16 elementwise
__global__ __launch_bounds__(256) void cast_kernel(const float* __restrict__ in,
                                                   short* __restrict__ outp, int n) {
    int idx = blockIdx.x * 256 + threadIdx.x;
    if (idx < n) outp[idx] = f2bf(in[idx]);
}

// softmax of agg_logits (S=4) + entropy aux loss
__global__ void aux_kernel(const float* __restrict__ logits,
                           float* __restrict__ w, float* __restrict__ aux) {
    if (threadIdx.x == 0 && blockIdx.x == 0) {
        float l0 = logits[0], l1 = logits[1], l2 = logits[2], l3 = logits[3];
        float m = fmaxf(fmaxf(l0, l1), fmaxf(l2, l3));
        float e0 = __expf(l0 - m), e1 = __expf(l1 - m);
        float e2 = __expf(l2 - m), e3 = __expf(l3 - m);
        float s = e0 + e1 + e2 + e3;
        float w0 = e0 / s, w1 = e1 / s, w2 = e2 / s, w3 = e3 / s;
        w[0] = w0; w[1] = w1; w[2] = w2; w[3] = w3;
        *aux = -(w0 * logf(w0 + 1e-9f) + w1 * logf(w1 + 1e-9f) +
                 w2 * logf(w2 + 1e-9f) + w3 * logf(w3 + 1e-9f));
    }
}

// ---------------------------------------------------------------- MFMA GEMM
// C[M,N] = act(A[M,K] @ B[K,N] + bias), A bf16 [M][K], Bt bf16 [N][K].
// 128x128 tile, BK=32, 4 waves -> 64x64 each, 16x16x32 bf16 MFMA.
// ACT: 0 none, 1 exact GELU, 2 ReLU. OBF: 0 fp32 out, 1 bf16 out.
template <int ACT, int OBF>
__global__ __launch_bounds__(256) void mgemm_kernel(
    const short* __restrict__ A, const short* __restrict__ Bt,
    const float* __restrict__ bias, void* __restrict__ Cv,
    int M, int N, int K) {
    __shared__ short As[128 * 32];
    __shared__ short Bs[128 * 32];
    int tid = threadIdx.x;
    int wave = tid >> 6, lane = tid & 63;
    int lq = lane & 15, quad = lane >> 4;
    int m0 = blockIdx.y << 7, n0 = blockIdx.x << 7;
    int wm = (wave & 1) << 6, wn = (wave >> 1) << 6;
    int r0 = tid >> 2, r1 = (256 + tid) >> 2;
    int kc0 = (tid & 3) << 3, kc1 = kc0;                // ((256+tid)&3)==(tid&3)
    const short* Ag0 = A + (size_t)(m0 + r0) * K + kc0;
    const short* Ag1 = A + (size_t)(m0 + r1) * K + kc1;
    const short* Bg0 = Bt + (size_t)(n0 + r0) * K + kc0;
    const short* Bg1 = Bt + (size_t)(n0 + r1) * K + kc1;
    float4v acc[4][4];
#pragma unroll
    for (int mi = 0; mi < 4; mi++)
#pragma unroll
        for (int ni = 0; ni < 4; ni++) acc[mi][ni] = (float4v){0.f, 0.f, 0.f, 0.f};

    for (int k0 = 0; k0 < K; k0 += 32) {
        __syncthreads();
        GLOAD_LDS16(Ag0 + k0, As + tid * 8);
        GLOAD_LDS16(Ag1 + k0, As + (256 + tid) * 8);
        GLOAD_LDS16(Bg0 + k0, Bs + tid * 8);
        GLOAD_LDS16(Bg1 + k0, Bs + (256 + tid) * 8);
        __syncthreads();
        short8 af[4], bfr[4];
#pragma unroll
        for (int mi = 0; mi < 4; mi++)
            af[mi] = *(const short8*)(As + ((wm + (mi << 4) + lq) << 5) + (quad << 3));
#pragma unroll
        for (int ni = 0; ni < 4; ni++)
            bfr[ni] = *(const short8*)(Bs + ((wn + (ni << 4) + lq) << 5) + (quad << 3));
#pragma unroll
        for (int mi = 0; mi < 4; mi++)
#pragma unroll
            for (int ni = 0; ni < 4; ni++)
                acc[mi][ni] = __builtin_amdgcn_mfma_f32_16x16x32_bf16(
                    af[mi], bfr[ni], acc[mi][ni], 0, 0, 0);
    }
#pragma unroll
    for (int ni = 0; ni < 4; ni++) {
        int col = n0 + wn + (ni << 4) + lq;
        float bv = bias ? bias[col] : 0.f;
#pragma unroll
        for (int mi = 0; mi < 4; mi++) {
#pragma unroll
            for (int r = 0; r < 4; r++) {
                int row = m0 + wm + (mi << 4) + (quad << 2) + r;
                float v = acc[mi][ni][r] + bv;
                if (ACT == 1) v = 0.5f * v * (1.0f + erff(v * 0.70710678118654752f));
                if (ACT == 2) v = fmaxf(v, 0.f);
                if (OBF) ((short*)Cv)[(size_t)row * N + col] = f2bf(v);
                else ((float*)Cv)[(size_t)row * N + col] = v;
            }
        }
    }
}

// ---------------------------------------------------------------- conv MFMA
// xc = relu(dilconv(x; k=3, dil=2, pad=2) + b), from xpad [B][1028][D] bf16,
// wdc_bt [3][D(o)][D(i)] bf16. Out bf16 [B*L][D].
__global__ __launch_bounds__(256) void convdil_mfma_kernel(
    const short* __restrict__ xp, const short* __restrict__ Wt,
    const float* __restrict__ bvec, short* __restrict__ outp) {
    __shared__ short As[128 * 32];
    __shared__ short Bs[128 * 32];
    int tid = threadIdx.x;
    int wave = tid >> 6, lane = tid & 63;
    int lq = lane & 15, quad = lane >> 4;
    int m0 = blockIdx.y << 7, n0 = blockIdx.x << 7;
    int wm = (wave & 1) << 6, wn = (wave >> 1) << 6;
    int b = m0 >> 10, ll0 = m0 & 1023;
    int r0 = tid >> 2, r1 = (256 + tid) >> 2;
    int kc = (tid & 3) << 3;
    float4v acc[4][4];
#pragma unroll
    for (int mi = 0; mi < 4; mi++)
#pragma unroll
        for (int ni = 0; ni < 4; ni++) acc[mi][ni] = (float4v){0.f, 0.f, 0.f, 0.f};

    for (int kp = 0; kp < 3; kp++) {
        const short* Abase = xp + ((size_t)(b * 1028 + ll0 + 2 * kp)) * DD + kc;
        const short* Bbase = Wt + (size_t)kp * DD * DD;
        const short* Bg0 = Bbase + (size_t)(n0 + r0) * DD + kc;
        const short* Bg1 = Bbase + (size_t)(n0 + r1) * DD + kc;
        for (int k0 = 0; k0 < DD; k0 += 32) {
            __syncthreads();
            GLOAD_LDS16(Abase + (size_t)r0 * DD + k0, As + tid * 8);
            GLOAD_LDS16(Abase + (size_t)r1 * DD + k0, As + (256 + tid) * 8);
            GLOAD_LDS16(Bg0 + k0, Bs + tid * 8);
            GLOAD_LDS16(Bg1 + k0, Bs + (256 + tid) * 8);
            __syncthreads();
            short8 af[4], bfr[4];
#pragma unroll
            for (int mi = 0; mi < 4; mi++)
                af[mi] = *(const short8*)(As + ((wm + (mi << 4) + lq) << 5) + (quad << 3));
#pragma unroll
            for (int ni = 0; ni < 4; ni++)
                bfr[ni] = *(const short8*)(Bs + ((wn + (ni << 4) + lq) << 5) + (quad << 3));
#pragma unroll
            for (int mi = 0; mi < 4; mi++)
#pragma unroll
                for (int ni = 0; ni < 4; ni++)
                    acc[mi][ni] = __builtin_amdgcn_mfma_f32_16x16x32_bf16(
                        af[mi], bfr[ni], acc[mi][ni], 0, 0, 0);
        }
    }
#pragma unroll
    for (int ni = 0; ni < 4; ni++) {
        int col = n0 + wn + (ni << 4) + lq;
        float bv = bvec[col];
#pragma unroll
        for (int mi = 0; mi < 4; mi++)
#pragma unroll
            for (int r = 0; r < 4; r++) {
                int row = m0 + wm + (mi << 4) + (quad << 2) + r;
                float v = fmaxf(acc[mi][ni][r] + bv, 0.f);
                outp[(size_t)row * DD + col] = f2bf(v);
            }
    }
}

// ---------------------------------------------------------------- V transpose
// vt[(b*H+h)*64 + d][j] (bf16) = v[b, j, h*64 + d] (fp32)
__global__ __launch_bounds__(256) void vtrans_kernel(const float* __restrict__ vin,
                                                     short* __restrict__ vout, int Ls) {
    __shared__ float tile[32][33];
    int j0 = blockIdx.x << 5;
    int d0 = blockIdx.y << 5;
    int by = blockIdx.z;                 // b*H + h
    int b = by >> 4, h = by & 15;
    int tid = threadIdx.x;
    int cc = tid & 31, rr = tid >> 5;
#pragma unroll
    for (int p = 0; p < 4; p++) {
        int jj = (p << 3) + rr;
        tile[jj][cc] = vin[((size_t)(b * Ls + j0 + jj)) * DD + (h << 6) + d0 + cc];
    }
    __syncthreads();
#pragma unroll
    for (int p = 0; p < 4; p++) {
        int dd = (p << 3) + rr;
        vout[((size_t)by * 64 + d0 + dd) * Ls + j0 + cc] = f2bf(tile[cc][dd]);
    }
}

// ---------------------------------------------------------------- attention
// Flash-style MFMA attention. Per wave: 16 q-rows, full K/V sweep in 64-key
// chunks. out (+)= wagg[sidx] * softmax(Q K^T / 8) V
__global__ __launch_bounds__(256) void attn_mfma_kernel(
    const short* __restrict__ qb, const short* __restrict__ kb,
    const short* __restrict__ vt, const float* __restrict__ wagg,
    float* __restrict__ out, int Ls, int sidx) {
    __shared__ float plds[4][16][68];
    int tid = threadIdx.x;
    int w = tid >> 6, lane = tid & 63;
    int lq = lane & 15, quad = lane >> 4;
    int bh = blockIdx.y;
    int b = bh >> 4, h = bh & 15;
    int q0 = (blockIdx.x << 6) + (w << 4);

    const short* qbase = qb + ((size_t)(b * DL + q0 + lq)) * DD + (h << 6);
    short8 qf0 = *(const short8*)(qbase + quad * 8);
    short8 qf1 = *(const short8*)(qbase + 32 + quad * 8);

    float4v O[4];
    float m_run[4], l_run[4];
#pragma unroll
    for (int t = 0; t < 4; t++) O[t] = (float4v){0.f, 0.f, 0.f, 0.f};
#pragma unroll
    for (int r = 0; r < 4; r++) { m_run[r] = -1e30f; l_run[r] = 0.f; }

    const short* kbase = kb + (size_t)b * Ls * DD + (h << 6);
    const short* vbase = vt + (size_t)bh * 64 * Ls;

    for (int c0 = 0; c0 < Ls; c0 += 64) {
        float4v S[4];
#pragma unroll
        for (int t = 0; t < 4; t++) {
            S[t] = (float4v){0.f, 0.f, 0.f, 0.f};
            const short* kp = kbase + (size_t)(c0 + (t << 4) + lq) * DD;
            short8 kf0 = *(const short8*)(kp + quad * 8);
            short8 kf1 = *(const short8*)(kp + 32 + quad * 8);
            S[t] = __builtin_amdgcn_mfma_f32_16x16x32_bf16(qf0, kf0, S[t], 0, 0, 0);
            S[t] = __builtin_amdgcn_mfma_f32_16x16x32_bf16(qf1, kf1, S[t], 0, 0, 0);
        }
#pragma unroll
        for (int t = 0; t < 4; t++)
#pragma unroll
            for (int r = 0; r < 4; r++) S[t][r] *= 0.125f;
        float mx[4], alpha[4];
#pragma unroll
        for (int r = 0; r < 4; r++) {
            float m01 = fmaxf(S[0][r], S[1][r]);
            float m23 = fmaxf(S[2][r], S[3][r]);
            float m = fmaxf(m01, m23);
            m = fmaxf(m, __shfl_xor(m, 1, 64));
            m = fmaxf(m, __shfl_xor(m, 2, 64));
            m = fmaxf(m, __shfl_xor(m, 4, 64));
            m = fmaxf(m, __shfl_xor(m, 8, 64));
            mx[r] = m;
        }
#pragma unroll
        for (int r = 0; r < 4; r++) {
            float m_new = fmaxf(m_run[r], mx[r]);
            alpha[r] = __expf(m_run[r] - m_new);
            m_run[r] = m_new;
            float s = 0.f;
#pragma unroll
            for (int t = 0; t < 4; t++) {
                float p = __expf(S[t][r] - m_new);
                S[t][r] = p;
                s += p;
            }
            s += __shfl_xor(s, 1, 64);
            s += __shfl_xor(s, 2, 64);
            s += __shfl_xor(s, 4, 64);
            s += __shfl_xor(s, 8, 64);
            l_run[r] = l_run[r] * alpha[r] + s;
        }
#pragma unroll
        for (int t = 0; t < 4; t++)
#pragma unroll
            for (int r = 0; r < 4; r++) O[t][r] *= alpha[r];
#pragma unroll
        for (int t = 0; t < 4; t++)
#pragma unroll
            for (int r = 0; r < 4; r++)
                plds[w][(quad << 2) + r][(t << 4) + lq] = S[t][r];
#pragma unroll
        for (int ks = 0; ks < 2; ks++) {
            const float* pr = &plds[w][lq][(ks << 5) + (quad << 3)];
            float4v p0 = *(const float4v*)pr;
            float4v p1 = *(const float4v*)(pr + 4);
            short8 af;
            af[0] = f2bf(p0[0]); af[1] = f2bf(p0[1]);
            af[2] = f2bf(p0[2]); af[3] = f2bf(p0[3]);
            af[4] = f2bf(p1[0]); af[5] = f2bf(p1[1]);
            af[6] = f2bf(p1[2]); af[7] = f2bf(p1[3]);
#pragma unroll
            for (int t = 0; t < 4; t++) {
                short8 vf = *(const short8*)(vbase + (size_t)((t << 4) + lq) * Ls +
                                             c0 + (ks << 5) + quad * 8);
                O[t] = __builtin_amdgcn_mfma_f32_16x16x32_bf16(af, vf, O[t], 0, 0, 0);
            }
        }
    }
    float wsc = wagg[sidx];
    float inv[4];
#pragma unroll
    for (int r = 0; r < 4; r++) inv[r] = wsc / l_run[r];
#pragma unroll
    for (int r = 0; r < 4; r++) {
        int qout = q0 + (quad << 2) + r;
        size_t obase = ((size_t)(b * DL + qout)) * DD + (h << 6) + lq;
#pragma unroll
        for (int t = 0; t < 4; t++) {
            float val = O[t][r] * inv[r];
            size_t oi = obase + (t << 4);
            if (sidx == 0) out[oi] = val;
            else out[oi] += val;
        }
    }
}

// ---------------------------------------------------------------- add + LN
// OBF: also write bf16 copy for downstream GEMM A.
template <int OBF>
__global__ __launch_bounds__(256) void addln_kernel(
    const float* __restrict__ a, const float* __restrict__ bsrc,
    const float* __restrict__ gam, const float* __restrict__ bet,
    float* __restrict__ out, short* __restrict__ outb) {
    __shared__ float redA[4], redB[4];
    int row = blockIdx.x, tid = threadIdx.x;
    size_t base = (size_t)row * DD + (tid << 2);
    float4 av = *(const float4*)&a[base];
    float4 bv = *(const float4*)&bsrc[base];
    float s0 = av.x + bv.x, s1 = av.y + bv.y, s2 = av.z + bv.z, s3 = av.w + bv.w;
    float lsum = s0 + s1 + s2 + s3;
    float lsq = s0 * s0 + s1 * s1 + s2 * s2 + s3 * s3;
#pragma unroll
    for (int o = 32; o > 0; o >>= 1) {
        lsum += __shfl_down(lsum, o, 64);
        lsq += __shfl_down(lsq, o, 64);
    }
    int lane = tid & 63, wid = tid >> 6;
    if (lane == 0) { redA[wid] = lsum; redB[wid] = lsq; }
    __syncthreads();
    float tsum = redA[0] + redA[1] + redA[2] + redA[3];
    float tsq = redB[0] + redB[1] + redB[2] + redB[3];
    float mean = tsum * (1.0f / DD);
    float var = tsq * (1.0f / DD) - mean * mean;
    float rstd = rsqrtf(var + 1e-5f);
    float4 gv = *(const float4*)&gam[tid << 2];
    float4 bev = *(const float4*)&bet[tid << 2];
    float4 o;
    o.x = (s0 - mean) * rstd * gv.x + bev.x;
    o.y = (s1 - mean) * rstd * gv.y + bev.y;
    o.z = (s2 - mean) * rstd * gv.z + bev.z;
    o.w = (s3 - mean) * rstd * gv.w + bev.w;
    *(float4*)&out[base] = o;
    if (OBF) {
        ushort4 u;
        u.x = (unsigned short)f2bf(o.x);
        u.y = (unsigned short)f2bf(o.y);
        u.z = (unsigned short)f2bf(o.z);
        u.w = (unsigned short)f2bf(o.w);
        *(ushort4*)&outb[base] = u;
    }
}

// ---------------------------------------------------------------- launcher
extern "C" void kernel_launch(void* const* d_in, const int* in_sizes, int n_in,
                              void* d_out, int out_size, void* d_ws, size_t ws_size,
                              hipStream_t stream) {
    (void)in_sizes; (void)n_in; (void)out_size; (void)ws_size;
    const float* x   = (const float*)d_in[0];
    const float* Wdc = (const float*)d_in[1];
    const float* bdc = (const float*)d_in[2];
    const float* Wdec= (const float*)d_in[3];
    const float* Wq  = (const float*)d_in[4];
    const float* Wk  = (const float*)d_in[5];
    const float* Wv  = (const float*)d_in[6];
    const float* Wo  = (const float*)d_in[7];
    const float* agg = (const float*)d_in[8];
    const float* g1  = (const float*)d_in[9];
    const float* be1 = (const float*)d_in[10];
    const float* g2  = (const float*)d_in[11];
    const float* be2 = (const float*)d_in[12];
    const float* W1  = (const float*)d_in[13];
    const float* b1  = (const float*)d_in[14];
    const float* W2  = (const float*)d_in[15];
    const float* b2  = (const float*)d_in[16];
    float* out = (float*)d_out;

    float* ws = (float*)d_ws;
    size_t off = 0;
    auto alloc = [&](size_t nfloats) { float* p = ws + off; off += nfloats; return p; };
    const size_t M1 = 1024 * 1024;
    short* wdc_bt  = (short*)alloc(3 * M1 / 2);     // 3M bf16
    short* wdec_bt = (short*)alloc(3 * M1);         // 6M bf16
    short* wqt     = (short*)alloc(2 * M1);         // 4M bf16
    short* wkt     = (short*)alloc(2 * M1);         // 4M bf16
    short* wvt     = (short*)alloc(M1 / 2);
    short* wot     = (short*)alloc(M1 / 2);
    short* w1t     = (short*)alloc(2 * M1);
    short* w2t     = (short*)alloc(2 * M1);
    float* wagg    = alloc(64);
    short* xpad    = (short*)alloc(2105344);        // 4*1028*1024 bf16
    short* xcb     = (short*)alloc(2 * M1);         // 4M bf16
    short* s1b     = (short*)alloc(M1);             // 2M bf16
    short* s2b     = (short*)alloc(M1 / 2);
    short* s3b     = (short*)alloc(M1 / 4);
    float* attacc  = alloc(4 * M1);
    short* attb    = (short*)alloc(2 * M1);
    float* x1      = alloc(4 * M1);
    short* x1b     = (short*)alloc(2 * M1);
    float* mahab   = alloc(4 * M1);
    float* big     = alloc(10 * M1);                // attention bufs / FFN hidden
    short* qbh = (short*)big;                       // 4M bf16
    short* kbh = (short*)(big + 2 * M1);            // 4M bf16
    float* vb  = big + 4 * M1;                      // 4M fp32
    short* vth = (short*)(big + 8 * M1);            // 4M bf16
    short* hb  = (short*)big;                       // FFN hidden 16M bf16
    float* fb  = attacc;                            // free after attb cast

    dim3 blk(256);
    // ---- prep (bf16 weights, padded x, agg weights)
    wdcprep_kernel<<<dim3(3 * M1 / 256), blk, 0, stream>>>(Wdc, wdc_bt);
    wdecprep_kernel<<<dim3(6 * M1 / 256), blk, 0, stream>>>(Wdec, wdec_bt);
    for (int s = 0; s < 4; s++) {
        tc_kernel<<<dim3(32, 32), blk, 0, stream>>>(Wq + s * M1, wqt + s * M1, DD, DD);
        tc_kernel<<<dim3(32, 32), blk, 0, stream>>>(Wk + s * M1, wkt + s * M1, DD, DD);
    }
    tc_kernel<<<dim3(32, 32), blk, 0, stream>>>(Wv, wvt, DD, DD);
    tc_kernel<<<dim3(32, 32), blk, 0, stream>>>(Wo, wot, DD, DD);
    tc_kernel<<<dim3(128, 32), blk, 0, stream>>>(W1, w1t, DD, DF);
    tc_kernel<<<dim3(32, 128), blk, 0, stream>>>(W2, w2t, DF, DD);
    xpad_kernel<<<dim3(2105344 * 2 / 256), blk, 0, stream>>>(x, xpad);
    aux_kernel<<<dim3(1), dim3(64), 0, stream>>>(agg, wagg, out + (size_t)DB * DL * DD);

    // 1. dilated conv + relu (MFMA, 3 tap-GEMMs)
    convdil_mfma_kernel<<<dim3(DD / 128, DB * DL / 128), blk, 0, stream>>>(
        xpad, wdc_bt, bdc, xcb);

    // 2. decomposition convs as GEMMs over [rows, 2D]
    mgemm_kernel<0, 1><<<dim3(DD / 128, (DB * DL / 2) / 128), blk, 0, stream>>>(
        xcb, wdec_bt, nullptr, s1b, DB * DL / 2, DD, 2 * DD);
    mgemm_kernel<0, 1><<<dim3(DD / 128, (DB * DL / 4) / 128), blk, 0, stream>>>(
        s1b, wdec_bt + 2 * M1, nullptr, s2b, DB * DL / 4, DD, 2 * DD);
    mgemm_kernel<0, 1><<<dim3(DD / 128, (DB * DL / 8) / 128), blk, 0, stream>>>(
        s2b, wdec_bt + 4 * M1, nullptr, s3b, DB * DL / 8, DD, 2 * DD);

    // 3. multiscale attention (bf16 MFMA flash), accumulated with agg weights
    const short* scl[4] = {xcb, s1b, s2b, s3b};
    for (int s = 0; s < 4; s++) {
        int Ls = DL >> s;
        int rows = DB * Ls;
        mgemm_kernel<0, 1><<<dim3(DD / 128, (DB * DL) / 128), blk, 0, stream>>>(
            xcb, wqt + s * M1, nullptr, qbh, DB * DL, DD, DD);
        mgemm_kernel<0, 1><<<dim3(DD / 128, rows / 128), blk, 0, stream>>>(
            scl[s], wkt + s * M1, nullptr, kbh, rows, DD, DD);
        mgemm_kernel<0, 0><<<dim3(DD / 128, rows / 128), blk, 0, stream>>>(
            scl[s], wvt, nullptr, vb, rows, DD, DD);
        vtrans_kernel<<<dim3(Ls / 32, 2, DB * DH), blk, 0, stream>>>(vb, vth, Ls);
        attn_mfma_kernel<<<dim3(DL / 64, DB * DH), blk, 0, stream>>>(
            qbh, kbh, vth, wagg, attacc, Ls, s);
    }

    // 4. shared output projection after convex aggregation
    cast_kernel<<<dim3(4 * M1 / 256), blk, 0, stream>>>(attacc, attb, 4 * M1);
    mgemm_kernel<0, 0><<<dim3(DD / 128, (DB * DL) / 128), blk, 0, stream>>>(
        attb, wot, nullptr, mahab, DB * DL, DD, DD);

    // 5. residual + LN1 (fp32 + bf16 copies)
    addln_kernel<1><<<dim3(DB * DL), blk, 0, stream>>>(x, mahab, g1, be1, x1, x1b);

    // 6. FFN with exact GELU
    mgemm_kernel<1, 1><<<dim3(DF / 128, (DB * DL) / 128), blk, 0, stream>>>(
        x1b, w1t, b1, hb, DB * DL, DF, DD);
    mgemm_kernel<0, 0><<<dim3(DD / 128, (DB * DL) / 128), blk, 0, stream>>>(
        hb, w2t, b2, fb, DB * DL, DD, DF);

    // 7. residual + LN2 -> out
    addln_kernel<0><<<dim3(DB * DL), blk, 0, stream>>>(x1, fb, g2, be2, out, nullptr);
}

// Round 4
// 1043.814 us; speedup vs baseline: 4.5806x; 1.1500x over previous
//
#include <hip/hip_runtime.h>
#include <cstddef>

#define DB 4
#define DL 1024
#define DD 1024
#define DH 16
#define DF 4096

typedef __attribute__((ext_vector_type(8))) short short8;
typedef __attribute__((ext_vector_type(4))) float float4v;

static __device__ __forceinline__ short f2bf(float f) {
    unsigned u = __float_as_uint(f);
    unsigned r = (u + 0x7FFFu + ((u >> 16) & 1u)) >> 16;   // RNE
    return (short)r;
}
static __device__ __forceinline__ float bf2f(short s) {
    return __uint_as_float(((unsigned)(unsigned short)s) << 16);
}

#define GLOAD_LDS16(gp, lp)                                                          \
    __builtin_amdgcn_global_load_lds(                                                \
        (const __attribute__((address_space(1))) void*)(gp),                         \
        (__attribute__((address_space(3))) void*)(lp), 16, 0, 0)

// ---------------------------------------------------------------- weight prep
// wdc_bt[k][o][i] = bf16(W_dc[(o*D + i)*3 + k])   (B^T per tap, [N=o][K=i])
__global__ __launch_bounds__(256) void wdcprep_kernel(const float* __restrict__ W,
                                                      short* __restrict__ Wt) {
    int idx = blockIdx.x * 256 + threadIdx.x;           // 3*D*D
    int i = idx & 1023;
    int o = (idx >> 10) & 1023;
    int k = idx >> 20;
    Wt[idx] = f2bf(W[((size_t)o * 1024 + i) * 3 + k]);
}

// wdec_bt[s][n][k2*D+i] = bf16(W_dec[((s*D+n)*D + i)*2 + k2])  ([N][K=2D])
__global__ __launch_bounds__(256) void wdecprep_kernel(const float* __restrict__ W,
                                                       short* __restrict__ Wt) {
    int idx = blockIdx.x * 256 + threadIdx.x;           // 3*2*D*D
    int i = idx & 1023;
    int k2 = (idx >> 10) & 1;
    int n = (idx >> 11) & 1023;
    int s = idx >> 21;
    Wt[idx] = f2bf(W[(((size_t)(s * 1024 + n)) * 1024 + i) * 2 + k2]);
}

// transpose-cast: in fp32 [K][N] -> out bf16 [N][K]
__global__ __launch_bounds__(256) void tc_kernel(const float* __restrict__ in,
                                                 short* __restrict__ outp, int K, int N) {
    __shared__ float tile[32][33];
    int n0 = blockIdx.x << 5, k0 = blockIdx.y << 5;
    int tid = threadIdx.x;
    int cc = tid & 31, rr = tid >> 5;
#pragma unroll
    for (int p = 0; p < 4; p++) {
        int kk = (p << 3) + rr;
        tile[kk][cc] = in[(size_t)(k0 + kk) * N + n0 + cc];
    }
    __syncthreads();
#pragma unroll
    for (int p = 0; p < 4; p++) {
        int nn = (p << 3) + rr;
        outp[(size_t)(n0 + nn) * K + k0 + cc] = f2bf(tile[cc][nn]);
    }
}

// zero-padded bf16 x: xpad[b][l+2][d] = bf16(x[b][l][d]), rows 0,1,L+2,L+3 = 0
__global__ __launch_bounds__(256) void xpad_kernel(const float* __restrict__ x,
                                                   short* __restrict__ xp) {
    int idx = blockIdx.x * 256 + threadIdx.x;           // 4*1028*1024
    int d = idx & 1023;
    int row = (idx >> 10) % 1028;
    int b = (idx >> 10) / 1028;
    int l = row - 2;
    float v = (l >= 0 && l < DL) ? x[((size_t)(b * DL + l)) * DD + d] : 0.f;
    xp[idx] = f2bf(v);
}

// softmax of agg_logits (S=4) + entropy aux loss
__global__ void aux_kernel(const float* __restrict__ logits,
                           float* __restrict__ w, float* __restrict__ aux) {
    if (threadIdx.x == 0 && blockIdx.x == 0) {
        float l0 = logits[0], l1 = logits[1], l2 = logits[2], l3 = logits[3];
        float m = fmaxf(fmaxf(l0, l1), fmaxf(l2, l3));
        float e0 = __expf(l0 - m), e1 = __expf(l1 - m);
        float e2 = __expf(l2 - m), e3 = __expf(l3 - m);
        float s = e0 + e1 + e2 + e3;
        float w0 = e0 / s, w1 = e1 / s, w2 = e2 / s, w3 = e3 / s;
        w[0] = w0; w[1] = w1; w[2] = w2; w[3] = w3;
        *aux = -(w0 * logf(w0 + 1e-9f) + w1 * logf(w1 + 1e-9f) +
                 w2 * logf(w2 + 1e-9f) + w3 * logf(w3 + 1e-9f));
    }
}

// ---------------------------------------------------------------- MFMA GEMM
// C[M,N] = act(A[M,K] @ B[K,N] + bias), A bf16 [M][K], Bt bf16 [N][K].
// 128x128 tile, BK=32, 4 waves -> 64x64 each, 16x16x32 bf16 MFMA.
// ACT: 0 none, 1 exact GELU. OBF: 0 fp32 out, 1 bf16 out.
template <int ACT, int OBF>
__global__ __launch_bounds__(256) void mgemm_kernel(
    const short* __restrict__ A, const short* __restrict__ Bt,
    const float* __restrict__ bias, void* __restrict__ Cv,
    int M, int N, int K) {
    __shared__ short As[128 * 32];
    __shared__ short Bs[128 * 32];
    int tid = threadIdx.x;
    int wave = tid >> 6, lane = tid & 63;
    int lq = lane & 15, quad = lane >> 4;
    int m0 = blockIdx.y << 7, n0 = blockIdx.x << 7;
    int wm = (wave & 1) << 6, wn = (wave >> 1) << 6;
    int r0 = tid >> 2, r1 = (256 + tid) >> 2;
    int kc0 = (tid & 3) << 3;
    const short* Ag0 = A + (size_t)(m0 + r0) * K + kc0;
    const short* Ag1 = A + (size_t)(m0 + r1) * K + kc0;
    const short* Bg0 = Bt + (size_t)(n0 + r0) * K + kc0;
    const short* Bg1 = Bt + (size_t)(n0 + r1) * K + kc0;
    float4v acc[4][4];
#pragma unroll
    for (int mi = 0; mi < 4; mi++)
#pragma unroll
        for (int ni = 0; ni < 4; ni++) acc[mi][ni] = (float4v){0.f, 0.f, 0.f, 0.f};

    for (int k0 = 0; k0 < K; k0 += 32) {
        __syncthreads();
        GLOAD_LDS16(Ag0 + k0, As + tid * 8);
        GLOAD_LDS16(Ag1 + k0, As + (256 + tid) * 8);
        GLOAD_LDS16(Bg0 + k0, Bs + tid * 8);
        GLOAD_LDS16(Bg1 + k0, Bs + (256 + tid) * 8);
        __syncthreads();
        short8 af[4], bfr[4];
#pragma unroll
        for (int mi = 0; mi < 4; mi++)
            af[mi] = *(const short8*)(As + ((wm + (mi << 4) + lq) << 5) + (quad << 3));
#pragma unroll
        for (int ni = 0; ni < 4; ni++)
            bfr[ni] = *(const short8*)(Bs + ((wn + (ni << 4) + lq) << 5) + (quad << 3));
#pragma unroll
        for (int mi = 0; mi < 4; mi++)
#pragma unroll
            for (int ni = 0; ni < 4; ni++)
                acc[mi][ni] = __builtin_amdgcn_mfma_f32_16x16x32_bf16(
                    af[mi], bfr[ni], acc[mi][ni], 0, 0, 0);
    }
#pragma unroll
    for (int ni = 0; ni < 4; ni++) {
        int col = n0 + wn + (ni << 4) + lq;
        float bv = bias ? bias[col] : 0.f;
#pragma unroll
        for (int mi = 0; mi < 4; mi++) {
#pragma unroll
            for (int r = 0; r < 4; r++) {
                int row = m0 + wm + (mi << 4) + (quad << 2) + r;
                float v = acc[mi][ni][r] + bv;
                if (ACT == 1) v = 0.5f * v * (1.0f + erff(v * 0.70710678118654752f));
                if (OBF) ((short*)Cv)[(size_t)row * N + col] = f2bf(v);
                else ((float*)Cv)[(size_t)row * N + col] = v;
            }
        }
    }
}

// ---------------------------------------------------------------- conv MFMA
__global__ __launch_bounds__(256) void convdil_mfma_kernel(
    const short* __restrict__ xp, const short* __restrict__ Wt,
    const float* __restrict__ bvec, short* __restrict__ outp) {
    __shared__ short As[128 * 32];
    __shared__ short Bs[128 * 32];
    int tid = threadIdx.x;
    int wave = tid >> 6, lane = tid & 63;
    int lq = lane & 15, quad = lane >> 4;
    int m0 = blockIdx.y << 7, n0 = blockIdx.x << 7;
    int wm = (wave & 1) << 6, wn = (wave >> 1) << 6;
    int b = m0 >> 10, ll0 = m0 & 1023;
    int r0 = tid >> 2, r1 = (256 + tid) >> 2;
    int kc = (tid & 3) << 3;
    float4v acc[4][4];
#pragma unroll
    for (int mi = 0; mi < 4; mi++)
#pragma unroll
        for (int ni = 0; ni < 4; ni++) acc[mi][ni] = (float4v){0.f, 0.f, 0.f, 0.f};

    for (int kp = 0; kp < 3; kp++) {
        const short* Abase = xp + ((size_t)(b * 1028 + ll0 + 2 * kp)) * DD + kc;
        const short* Bbase = Wt + (size_t)kp * DD * DD;
        const short* Bg0 = Bbase + (size_t)(n0 + r0) * DD + kc;
        const short* Bg1 = Bbase + (size_t)(n0 + r1) * DD + kc;
        for (int k0 = 0; k0 < DD; k0 += 32) {
            __syncthreads();
            GLOAD_LDS16(Abase + (size_t)r0 * DD + k0, As + tid * 8);
            GLOAD_LDS16(Abase + (size_t)r1 * DD + k0, As + (256 + tid) * 8);
            GLOAD_LDS16(Bg0 + k0, Bs + tid * 8);
            GLOAD_LDS16(Bg1 + k0, Bs + (256 + tid) * 8);
            __syncthreads();
            short8 af[4], bfr[4];
#pragma unroll
            for (int mi = 0; mi < 4; mi++)
                af[mi] = *(const short8*)(As + ((wm + (mi << 4) + lq) << 5) + (quad << 3));
#pragma unroll
            for (int ni = 0; ni < 4; ni++)
                bfr[ni] = *(const short8*)(Bs + ((wn + (ni << 4) + lq) << 5) + (quad << 3));
#pragma unroll
            for (int mi = 0; mi < 4; mi++)
#pragma unroll
                for (int ni = 0; ni < 4; ni++)
                    acc[mi][ni] = __builtin_amdgcn_mfma_f32_16x16x32_bf16(
                        af[mi], bfr[ni], acc[mi][ni], 0, 0, 0);
        }
    }
#pragma unroll
    for (int ni = 0; ni < 4; ni++) {
        int col = n0 + wn + (ni << 4) + lq;
        float bv = bvec[col];
#pragma unroll
        for (int mi = 0; mi < 4; mi++)
#pragma unroll
            for (int r = 0; r < 4; r++) {
                int row = m0 + wm + (mi << 4) + (quad << 2) + r;
                float v = fmaxf(acc[mi][ni][r] + bv, 0.f);
                outp[(size_t)row * DD + col] = f2bf(v);
            }
    }
}

// ---------------------------------------------------------------- V transpose
// vt[(b*H+h)*64 + d][j] = kv[b, j, 1024 + h*64 + d]  (bf16 -> bf16)
__global__ __launch_bounds__(256) void vtrans_bf_kernel(const short* __restrict__ kvp,
                                                        short* __restrict__ vout, int Ls) {
    __shared__ short tile[32][33];
    int j0 = blockIdx.x << 5;
    int d0 = blockIdx.y << 5;
    int bh = blockIdx.z;
    int b = bh >> 4, h = bh & 15;
    int tid = threadIdx.x;
    int cc = tid & 31, rr = tid >> 5;
#pragma unroll
    for (int p = 0; p < 4; p++) {
        int jj = (p << 3) + rr;
        tile[jj][cc] = kvp[((size_t)(b * Ls + j0 + jj) << 11) + 1024 + (h << 6) + d0 + cc];
    }
    __syncthreads();
#pragma unroll
    for (int p = 0; p < 4; p++) {
        int dd = (p << 3) + rr;
        vout[((size_t)(bh * 64 + d0 + dd)) * Ls + j0 + cc] = tile[cc][dd];
    }
}

// ---------------------------------------------------------------- attention
// All 4 scales in one dispatch (blockIdx.z = scale). Fixed-max softmax
// (exp without running max -- scores are O(1), exact by shift invariance),
// deferred denominator (zero cross-lane ops in loop). Writes normalized
// per-scale output (bf16) to opart[s].
__global__ __launch_bounds__(256) void attn_fused_kernel(
    const short* __restrict__ qb4,
    const short* __restrict__ kv0, const short* __restrict__ kv1,
    const short* __restrict__ kv2, const short* __restrict__ kv3,
    const short* __restrict__ vt0, const short* __restrict__ vt1,
    const short* __restrict__ vt2, const short* __restrict__ vt3,
    short* __restrict__ opart) {
    __shared__ float plds[4][16][68];
    int tid = threadIdx.x;
    int w = tid >> 6, lane = tid & 63;
    int lq = lane & 15, quad = lane >> 4;
    int s = blockIdx.z;
    int Ls = DL >> s;
    const short* kvp = s == 0 ? kv0 : s == 1 ? kv1 : s == 2 ? kv2 : kv3;
    const short* vtp = s == 0 ? vt0 : s == 1 ? vt1 : s == 2 ? vt2 : vt3;
    int bh = blockIdx.y;
    int b = bh >> 4, h = bh & 15;
    int q0 = (blockIdx.x << 6) + (w << 4);

    const short* qbase = qb4 + ((size_t)(b * DL + q0 + lq) << 12) + (s << 10) +
                         (h << 6) + (quad << 3);
    short8 qf0 = *(const short8*)qbase;
    short8 qf1 = *(const short8*)(qbase + 32);

    float4v O[4];
    float lpart[4] = {0.f, 0.f, 0.f, 0.f};
#pragma unroll
    for (int t = 0; t < 4; t++) O[t] = (float4v){0.f, 0.f, 0.f, 0.f};

    const short* kbase = kvp + (h << 6) + (quad << 3);
    const short* vbase = vtp + ((size_t)(bh << 6)) * Ls;
    const float c_exp = 0.18033688f;    // log2(e)/8

    for (int c0 = 0; c0 < Ls; c0 += 64) {
        float4v S[4];
#pragma unroll
        for (int t = 0; t < 4; t++) {
            const short* kp = kbase + ((size_t)(c0 + (t << 4) + lq) << 11);
            short8 kf0 = *(const short8*)kp;
            short8 kf1 = *(const short8*)(kp + 32);
            float4v z = (float4v){0.f, 0.f, 0.f, 0.f};
            z = __builtin_amdgcn_mfma_f32_16x16x32_bf16(qf0, kf0, z, 0, 0, 0);
            S[t] = __builtin_amdgcn_mfma_f32_16x16x32_bf16(qf1, kf1, z, 0, 0, 0);
        }
        // P = exp(S/8) = 2^(S*log2e/8); accumulate per-lane partial row sums
#pragma unroll
        for (int t = 0; t < 4; t++)
#pragma unroll
            for (int r = 0; r < 4; r++) {
                float p = exp2f(S[t][r] * c_exp);
                S[t][r] = p;
                lpart[r] += p;
            }
        // P: C-layout -> A-layout via per-wave LDS slice (no barrier)
#pragma unroll
        for (int t = 0; t < 4; t++)
#pragma unroll
            for (int r = 0; r < 4; r++)
                plds[w][(quad << 2) + r][(t << 4) + lq] = S[t][r];
#pragma unroll
        for (int ks = 0; ks < 2; ks++) {
            const float* pr = &plds[w][lq][(ks << 5) + (quad << 3)];
            float4v p0 = *(const float4v*)pr;
            float4v p1 = *(const float4v*)(pr + 4);
            short8 af;
            af[0] = f2bf(p0[0]); af[1] = f2bf(p0[1]);
            af[2] = f2bf(p0[2]); af[3] = f2bf(p0[3]);
            af[4] = f2bf(p1[0]); af[5] = f2bf(p1[1]);
            af[6] = f2bf(p1[2]); af[7] = f2bf(p1[3]);
#pragma unroll
            for (int t = 0; t < 4; t++) {
                short8 vf = *(const short8*)(vbase + (size_t)((t << 4) + lq) * Ls +
                                             c0 + (ks << 5) + (quad << 3));
                O[t] = __builtin_amdgcn_mfma_f32_16x16x32_bf16(af, vf, O[t], 0, 0, 0);
            }
        }
    }
    // final denominator reduce (once per kernel): lanes sharing a quad
    float linv[4];
#pragma unroll
    for (int r = 0; r < 4; r++) {
        float l = lpart[r];
        l += __shfl_xor(l, 1, 64);
        l += __shfl_xor(l, 2, 64);
        l += __shfl_xor(l, 4, 64);
        l += __shfl_xor(l, 8, 64);
        linv[r] = 1.0f / l;
    }
    short* ob = opart + ((size_t)s << 22);
#pragma unroll
    for (int r = 0; r < 4; r++) {
        size_t rbase = ((size_t)(b * DL + q0 + (quad << 2) + r) << 10) + (h << 6) + lq;
#pragma unroll
        for (int t = 0; t < 4; t++)
            ob[rbase + (t << 4)] = f2bf(O[t][r] * linv[r]);
    }
}

// ---------------------------------------------------------------- combine
// attb = bf16( sum_s wagg[s] * opart[s] ), 8 elems/thread over 4M elems
__global__ __launch_bounds__(256) void combine_kernel(const short* __restrict__ op,
                                                      const float* __restrict__ wagg,
                                                      short* __restrict__ attb) {
    int idx = (blockIdx.x * 256 + threadIdx.x) << 3;
    float w0 = wagg[0], w1 = wagg[1], w2 = wagg[2], w3 = wagg[3];
    short8 a0 = *(const short8*)(op + idx);
    short8 a1 = *(const short8*)(op + (1u << 22) + idx);
    short8 a2 = *(const short8*)(op + (2u << 22) + idx);
    short8 a3 = *(const short8*)(op + (3u << 22) + idx);
    short8 o;
#pragma unroll
    for (int j = 0; j < 8; j++)
        o[j] = f2bf(w0 * bf2f(a0[j]) + w1 * bf2f(a1[j]) +
                    w2 * bf2f(a2[j]) + w3 * bf2f(a3[j]));
    *(short8*)(attb + idx) = o;
}

// ---------------------------------------------------------------- add + LN
template <int OBF>
__global__ __launch_bounds__(256) void addln_kernel(
    const float* __restrict__ a, const float* __restrict__ bsrc,
    const float* __restrict__ gam, const float* __restrict__ bet,
    float* __restrict__ out, short* __restrict__ outb) {
    __shared__ float redA[4], redB[4];
    int row = blockIdx.x, tid = threadIdx.x;
    size_t base = (size_t)row * DD + (tid << 2);
    float4 av = *(const float4*)&a[base];
    float4 bv = *(const float4*)&bsrc[base];
    float s0 = av.x + bv.x, s1 = av.y + bv.y, s2 = av.z + bv.z, s3 = av.w + bv.w;
    float lsum = s0 + s1 + s2 + s3;
    float lsq = s0 * s0 + s1 * s1 + s2 * s2 + s3 * s3;
#pragma unroll
    for (int o = 32; o > 0; o >>= 1) {
        lsum += __shfl_down(lsum, o, 64);
        lsq += __shfl_down(lsq, o, 64);
    }
    int lane = tid & 63, wid = tid >> 6;
    if (lane == 0) { redA[wid] = lsum; redB[wid] = lsq; }
    __syncthreads();
    float tsum = redA[0] + redA[1] + redA[2] + redA[3];
    float tsq = redB[0] + redB[1] + redB[2] + redB[3];
    float mean = tsum * (1.0f / DD);
    float var = tsq * (1.0f / DD) - mean * mean;
    float rstd = rsqrtf(var + 1e-5f);
    float4 gv = *(const float4*)&gam[tid << 2];
    float4 bev = *(const float4*)&bet[tid << 2];
    float4 o;
    o.x = (s0 - mean) * rstd * gv.x + bev.x;
    o.y = (s1 - mean) * rstd * gv.y + bev.y;
    o.z = (s2 - mean) * rstd * gv.z + bev.z;
    o.w = (s3 - mean) * rstd * gv.w + bev.w;
    *(float4*)&out[base] = o;
    if (OBF) {
        ushort4 u;
        u.x = (unsigned short)f2bf(o.x);
        u.y = (unsigned short)f2bf(o.y);
        u.z = (unsigned short)f2bf(o.z);
        u.w = (unsigned short)f2bf(o.w);
        *(ushort4*)&outb[base] = u;
    }
}

// ---------------------------------------------------------------- launcher
extern "C" void kernel_launch(void* const* d_in, const int* in_sizes, int n_in,
                              void* d_out, int out_size, void* d_ws, size_t ws_size,
                              hipStream_t stream) {
    (void)in_sizes; (void)n_in; (void)out_size; (void)ws_size;
    const float* x   = (const float*)d_in[0];
    const float* Wdc = (const float*)d_in[1];
    const float* bdc = (const float*)d_in[2];
    const float* Wdec= (const float*)d_in[3];
    const float* Wq  = (const float*)d_in[4];
    const float* Wk  = (const float*)d_in[5];
    const float* Wv  = (const float*)d_in[6];
    const float* Wo  = (const float*)d_in[7];
    const float* agg = (const float*)d_in[8];
    const float* g1  = (const float*)d_in[9];
    const float* be1 = (const float*)d_in[10];
    const float* g2  = (const float*)d_in[11];
    const float* be2 = (const float*)d_in[12];
    const float* W1  = (const float*)d_in[13];
    const float* b1  = (const float*)d_in[14];
    const float* W2  = (const float*)d_in[15];
    const float* b2  = (const float*)d_in[16];
    float* out = (float*)d_out;

    float* ws = (float*)d_ws;
    size_t off = 0;
    auto alloc = [&](size_t nfloats) { float* p = ws + off; off += nfloats; return p; };
    const size_t M1 = 1024 * 1024;
    short* wdc_bt  = (short*)alloc(3 * M1 / 2);     // 3M bf16
    short* wdec_bt = (short*)alloc(3 * M1);         // 6M bf16
    short* wq4t    = (short*)alloc(2 * M1);         // 4M bf16: 4x Wq^T stacked
    short* wkvt    = (short*)alloc(4 * M1);         // 4 scales x [Wk[s]^T;Wv^T] (2M bf16 each)
    short* wot     = (short*)alloc(M1 / 2);
    short* w1t     = (short*)alloc(2 * M1);
    short* w2t     = (short*)alloc(2 * M1);
    float* wagg    = alloc(64);
    short* xpad    = (short*)alloc(2105344);        // 4*1028*1024 bf16
    short* xcb     = (short*)alloc(2 * M1);
    short* s1b     = (short*)alloc(M1);
    short* s2b     = (short*)alloc(M1 / 2);
    short* s3b     = (short*)alloc(M1 / 4);
    short* qb4     = (short*)alloc(8 * M1);         // [4096][4096] bf16; later FFN hidden
    short* kv0     = (short*)alloc(4 * M1);         // [4096][2048] bf16; later mahab/fb
    short* kv1     = (short*)alloc(2 * M1);
    short* kv2     = (short*)alloc(M1);
    short* kv3     = (short*)alloc(M1 / 2);
    short* vt0     = (short*)alloc(2 * M1);         // [4096][1024] bf16
    short* vt1     = (short*)alloc(M1);
    short* vt2     = (short*)alloc(M1 / 2);
    short* vt3     = (short*)alloc(M1 / 4);
    short* oparts  = (short*)alloc(8 * M1);         // 4 x 4M bf16
    short* attb    = (short*)alloc(2 * M1);
    float* x1      = alloc(4 * M1);
    short* x1b     = (short*)alloc(2 * M1);
    short* hb      = qb4;                           // FFN hidden [4096][4096] bf16
    float* mahab   = (float*)kv0;                   // 4M fp32
    float* fb      = (float*)kv0;                   // 4M fp32 (after mahab dead)

    dim3 blk(256);
    // ---- prep
    wdcprep_kernel<<<dim3(3 * M1 / 256), blk, 0, stream>>>(Wdc, wdc_bt);
    wdecprep_kernel<<<dim3(6 * M1 / 256), blk, 0, stream>>>(Wdec, wdec_bt);
    for (int s = 0; s < 4; s++) {
        tc_kernel<<<dim3(32, 32), blk, 0, stream>>>(Wq + s * M1, wq4t + s * M1, DD, DD);
        tc_kernel<<<dim3(32, 32), blk, 0, stream>>>(Wk + s * M1, wkvt + s * 2 * M1, DD, DD);
        tc_kernel<<<dim3(32, 32), blk, 0, stream>>>(Wv, wkvt + s * 2 * M1 + M1, DD, DD);
    }
    tc_kernel<<<dim3(32, 32), blk, 0, stream>>>(Wo, wot, DD, DD);
    tc_kernel<<<dim3(128, 32), blk, 0, stream>>>(W1, w1t, DD, DF);
    tc_kernel<<<dim3(32, 128), blk, 0, stream>>>(W2, w2t, DF, DD);
    xpad_kernel<<<dim3(2105344 * 2 / 256), blk, 0, stream>>>(x, xpad);
    aux_kernel<<<dim3(1), dim3(64), 0, stream>>>(agg, wagg, out + (size_t)DB * DL * DD);

    // 1. dilated conv + relu
    convdil_mfma_kernel<<<dim3(DD / 128, DB * DL / 128), blk, 0, stream>>>(
        xpad, wdc_bt, bdc, xcb);

    // 2. decomposition convs
    mgemm_kernel<0, 1><<<dim3(DD / 128, (DB * DL / 2) / 128), blk, 0, stream>>>(
        xcb, wdec_bt, nullptr, s1b, DB * DL / 2, DD, 2 * DD);
    mgemm_kernel<0, 1><<<dim3(DD / 128, (DB * DL / 4) / 128), blk, 0, stream>>>(
        s1b, wdec_bt + 2 * M1, nullptr, s2b, DB * DL / 4, DD, 2 * DD);
    mgemm_kernel<0, 1><<<dim3(DD / 128, (DB * DL / 8) / 128), blk, 0, stream>>>(
        s2b, wdec_bt + 4 * M1, nullptr, s3b, DB * DL / 8, DD, 2 * DD);

    // 3a. batched Q projection (all 4 scales, N=4096)
    mgemm_kernel<0, 1><<<dim3(32, 32), blk, 0, stream>>>(
        xcb, wq4t, nullptr, qb4, DB * DL, 4 * DD, DD);

    // 3b. fused K|V projections per scale (N=2048) + V transpose
    const short* scl[4] = {xcb, s1b, s2b, s3b};
    short* kvs[4] = {kv0, kv1, kv2, kv3};
    short* vts[4] = {vt0, vt1, vt2, vt3};
    for (int s = 0; s < 4; s++) {
        int Ls = DL >> s;
        int rows = DB * Ls;
        mgemm_kernel<0, 1><<<dim3(16, rows / 128), blk, 0, stream>>>(
            scl[s], wkvt + s * 2 * M1, nullptr, kvs[s], rows, 2048, DD);
        vtrans_bf_kernel<<<dim3(Ls / 32, 2, DB * DH), blk, 0, stream>>>(kvs[s], vts[s], Ls);
    }

    // 3c. all-scale fused attention (one dispatch)
    attn_fused_kernel<<<dim3(DL / 64, DB * DH, 4), blk, 0, stream>>>(
        qb4, kv0, kv1, kv2, kv3, vt0, vt1, vt2, vt3, oparts);

    // 3d. convex aggregation
    combine_kernel<<<dim3(4 * M1 / (256 * 8)), blk, 0, stream>>>(oparts, wagg, attb);

    // 4. shared output projection
    mgemm_kernel<0, 0><<<dim3(DD / 128, (DB * DL) / 128), blk, 0, stream>>>(
        attb, wot, nullptr, mahab, DB * DL, DD, DD);

    // 5. residual + LN1
    addln_kernel<1><<<dim3(DB * DL), blk, 0, stream>>>(x, mahab, g1, be1, x1, x1b);

    // 6. FFN with exact GELU
    mgemm_kernel<1, 1><<<dim3(DF / 128, (DB * DL) / 128), blk, 0, stream>>>(
        x1b, w1t, b1, hb, DB * DL, DF, DD);
    mgemm_kernel<0, 0><<<dim3(DD / 128, (DB * DL) / 128), blk, 0, stream>>>(
        hb, w2t, b2, fb, DB * DL, DD, DF);

    // 7. residual + LN2 -> out
    addln_kernel<0><<<dim3(DB * DL), blk, 0, stream>>>(x1, fb, g2, be2, out, nullptr);
}

// Round 5
// 1030.104 us; speedup vs baseline: 4.6415x; 1.0133x over previous
//
#include <hip/hip_runtime.h>
#include <cstddef>

#define DB 4
#define DL 1024
#define DD 1024
#define DH 16
#define DF 4096

typedef __attribute__((ext_vector_type(8))) short short8;
typedef __attribute__((ext_vector_type(4))) float float4v;

static __device__ __forceinline__ short f2bf(float f) {
    unsigned u = __float_as_uint(f);
    unsigned r = (u + 0x7FFFu + ((u >> 16) & 1u)) >> 16;   // RNE
    return (short)r;
}
static __device__ __forceinline__ float bf2f(short s) {
    return __uint_as_float(((unsigned)(unsigned short)s) << 16);
}

#define GLOAD_LDS16(gp, lp)                                                          \
    __builtin_amdgcn_global_load_lds(                                                \
        (const __attribute__((address_space(1))) void*)(gp),                         \
        (__attribute__((address_space(3))) void*)(lp), 16, 0, 0)

// ---------------------------------------------------------------- weight prep
// wdc_bt[k][o][i] = bf16(W_dc[(o*D + i)*3 + k])   (B^T per tap, [N=o][K=i])
__global__ __launch_bounds__(256) void wdcprep_kernel(const float* __restrict__ W,
                                                      short* __restrict__ Wt) {
    int idx = blockIdx.x * 256 + threadIdx.x;           // 3*D*D
    int i = idx & 1023;
    int o = (idx >> 10) & 1023;
    int k = idx >> 20;
    Wt[idx] = f2bf(W[((size_t)o * 1024 + i) * 3 + k]);
}

// wdec_bt[s][n][k2*D+i] = bf16(W_dec[((s*D+n)*D + i)*2 + k2])  ([N][K=2D])
__global__ __launch_bounds__(256) void wdecprep_kernel(const float* __restrict__ W,
                                                       short* __restrict__ Wt) {
    int idx = blockIdx.x * 256 + threadIdx.x;           // 3*2*D*D
    int i = idx & 1023;
    int k2 = (idx >> 10) & 1;
    int n = (idx >> 11) & 1023;
    int s = idx >> 21;
    Wt[idx] = f2bf(W[(((size_t)(s * 1024 + n)) * 1024 + i) * 2 + k2]);
}

// generic transpose-cast: in fp32 [K][N] -> out bf16 [N][K]
__global__ __launch_bounds__(256) void tc_kernel(const float* __restrict__ in,
                                                 short* __restrict__ outp, int K, int N) {
    __shared__ float tile[32][33];
    int n0 = blockIdx.x << 5, k0 = blockIdx.y << 5;
    int tid = threadIdx.x;
    int cc = tid & 31, rr = tid >> 5;
#pragma unroll
    for (int p = 0; p < 4; p++) {
        int kk = (p << 3) + rr;
        tile[kk][cc] = in[(size_t)(k0 + kk) * N + n0 + cc];
    }
    __syncthreads();
#pragma unroll
    for (int p = 0; p < 4; p++) {
        int nn = (p << 3) + rr;
        outp[(size_t)(n0 + nn) * K + k0 + cc] = f2bf(tile[cc][nn]);
    }
}

// batched square (1024x1024) transpose-casts, z selects the weight:
// z 0-3: Wq[z] -> wq4t+z*M ; z 4-7: Wk[z-4] -> wkvt+(z-4)*2M ;
// z 8-11: Wv -> wkvt+(z-8)*2M+M ; z 12: Wo -> wot
__global__ __launch_bounds__(256) void tcsq_kernel(
    const float* __restrict__ Wq, const float* __restrict__ Wk,
    const float* __restrict__ Wv, const float* __restrict__ Wo,
    short* __restrict__ wq4t, short* __restrict__ wkvt, short* __restrict__ wot) {
    const size_t M1 = 1024 * 1024;
    int z = blockIdx.z;
    const float* src;
    short* dst;
    if (z < 4)      { src = Wq + (size_t)z * M1;       dst = wq4t + (size_t)z * M1; }
    else if (z < 8) { src = Wk + (size_t)(z - 4) * M1; dst = wkvt + (size_t)(z - 4) * 2 * M1; }
    else if (z < 12){ src = Wv;                        dst = wkvt + (size_t)(z - 8) * 2 * M1 + M1; }
    else            { src = Wo;                        dst = wot; }
    __shared__ float tile[32][33];
    int n0 = blockIdx.x << 5, k0 = blockIdx.y << 5;
    int tid = threadIdx.x;
    int cc = tid & 31, rr = tid >> 5;
#pragma unroll
    for (int p = 0; p < 4; p++) {
        int kk = (p << 3) + rr;
        tile[kk][cc] = src[(size_t)(k0 + kk) * DD + n0 + cc];
    }
    __syncthreads();
#pragma unroll
    for (int p = 0; p < 4; p++) {
        int nn = (p << 3) + rr;
        dst[(size_t)(n0 + nn) * DD + k0 + cc] = f2bf(tile[cc][nn]);
    }
}

// zero-padded bf16 x: xpad[b][l+2][d] = bf16(x[b][l][d]), rows 0,1,L+2,L+3 = 0
__global__ __launch_bounds__(256) void xpad_kernel(const float* __restrict__ x,
                                                   short* __restrict__ xp) {
    int idx = blockIdx.x * 256 + threadIdx.x;           // 4*1028*1024
    int d = idx & 1023;
    int row = (idx >> 10) % 1028;
    int b = (idx >> 10) / 1028;
    int l = row - 2;
    float v = (l >= 0 && l < DL) ? x[((size_t)(b * DL + l)) * DD + d] : 0.f;
    xp[idx] = f2bf(v);
}

// softmax of agg_logits (S=4) + entropy aux loss
__global__ void aux_kernel(const float* __restrict__ logits,
                           float* __restrict__ w, float* __restrict__ aux) {
    if (threadIdx.x == 0 && blockIdx.x == 0) {
        float l0 = logits[0], l1 = logits[1], l2 = logits[2], l3 = logits[3];
        float m = fmaxf(fmaxf(l0, l1), fmaxf(l2, l3));
        float e0 = __expf(l0 - m), e1 = __expf(l1 - m);
        float e2 = __expf(l2 - m), e3 = __expf(l3 - m);
        float s = e0 + e1 + e2 + e3;
        float w0 = e0 / s, w1 = e1 / s, w2 = e2 / s, w3 = e3 / s;
        w[0] = w0; w[1] = w1; w[2] = w2; w[3] = w3;
        *aux = -(w0 * logf(w0 + 1e-9f) + w1 * logf(w1 + 1e-9f) +
                 w2 * logf(w2 + 1e-9f) + w3 * logf(w3 + 1e-9f));
    }
}

// ---------------------------------------------------------------- MFMA GEMM
// C[M,N] = act(A[M,K] @ B[K,N] + bias), A bf16 [M][K], Bt bf16 [N][K].
// 128x128 tile, BK=32, 4 waves -> 64x64 each, 16x16x32 bf16 MFMA.
template <int ACT, int OBF>
__global__ __launch_bounds__(256) void mgemm_kernel(
    const short* __restrict__ A, const short* __restrict__ Bt,
    const float* __restrict__ bias, void* __restrict__ Cv,
    int M, int N, int K) {
    __shared__ short As[128 * 32];
    __shared__ short Bs[128 * 32];
    int tid = threadIdx.x;
    int wave = tid >> 6, lane = tid & 63;
    int lq = lane & 15, quad = lane >> 4;
    int m0 = blockIdx.y << 7, n0 = blockIdx.x << 7;
    int wm = (wave & 1) << 6, wn = (wave >> 1) << 6;
    int r0 = tid >> 2, r1 = (256 + tid) >> 2;
    int kc0 = (tid & 3) << 3;
    const short* Ag0 = A + (size_t)(m0 + r0) * K + kc0;
    const short* Ag1 = A + (size_t)(m0 + r1) * K + kc0;
    const short* Bg0 = Bt + (size_t)(n0 + r0) * K + kc0;
    const short* Bg1 = Bt + (size_t)(n0 + r1) * K + kc0;
    float4v acc[4][4];
#pragma unroll
    for (int mi = 0; mi < 4; mi++)
#pragma unroll
        for (int ni = 0; ni < 4; ni++) acc[mi][ni] = (float4v){0.f, 0.f, 0.f, 0.f};

    for (int k0 = 0; k0 < K; k0 += 32) {
        __syncthreads();
        GLOAD_LDS16(Ag0 + k0, As + tid * 8);
        GLOAD_LDS16(Ag1 + k0, As + (256 + tid) * 8);
        GLOAD_LDS16(Bg0 + k0, Bs + tid * 8);
        GLOAD_LDS16(Bg1 + k0, Bs + (256 + tid) * 8);
        __syncthreads();
        short8 af[4], bfr[4];
#pragma unroll
        for (int mi = 0; mi < 4; mi++)
            af[mi] = *(const short8*)(As + ((wm + (mi << 4) + lq) << 5) + (quad << 3));
#pragma unroll
        for (int ni = 0; ni < 4; ni++)
            bfr[ni] = *(const short8*)(Bs + ((wn + (ni << 4) + lq) << 5) + (quad << 3));
#pragma unroll
        for (int mi = 0; mi < 4; mi++)
#pragma unroll
            for (int ni = 0; ni < 4; ni++)
                acc[mi][ni] = __builtin_amdgcn_mfma_f32_16x16x32_bf16(
                    af[mi], bfr[ni], acc[mi][ni], 0, 0, 0);
    }
#pragma unroll
    for (int ni = 0; ni < 4; ni++) {
        int col = n0 + wn + (ni << 4) + lq;
        float bv = bias ? bias[col] : 0.f;
#pragma unroll
        for (int mi = 0; mi < 4; mi++) {
#pragma unroll
            for (int r = 0; r < 4; r++) {
                int row = m0 + wm + (mi << 4) + (quad << 2) + r;
                float v = acc[mi][ni][r] + bv;
                if (ACT == 1) v = 0.5f * v * (1.0f + erff(v * 0.70710678118654752f));
                if (OBF) ((short*)Cv)[(size_t)row * N + col] = f2bf(v);
                else ((float*)Cv)[(size_t)row * N + col] = v;
            }
        }
    }
}

// ---------------------------------------------------------------- conv MFMA
__global__ __launch_bounds__(256) void convdil_mfma_kernel(
    const short* __restrict__ xp, const short* __restrict__ Wt,
    const float* __restrict__ bvec, short* __restrict__ outp) {
    __shared__ short As[128 * 32];
    __shared__ short Bs[128 * 32];
    int tid = threadIdx.x;
    int wave = tid >> 6, lane = tid & 63;
    int lq = lane & 15, quad = lane >> 4;
    int m0 = blockIdx.y << 7, n0 = blockIdx.x << 7;
    int wm = (wave & 1) << 6, wn = (wave >> 1) << 6;
    int b = m0 >> 10, ll0 = m0 & 1023;
    int r0 = tid >> 2, r1 = (256 + tid) >> 2;
    int kc = (tid & 3) << 3;
    float4v acc[4][4];
#pragma unroll
    for (int mi = 0; mi < 4; mi++)
#pragma unroll
        for (int ni = 0; ni < 4; ni++) acc[mi][ni] = (float4v){0.f, 0.f, 0.f, 0.f};

    for (int kp = 0; kp < 3; kp++) {
        const short* Abase = xp + ((size_t)(b * 1028 + ll0 + 2 * kp)) * DD + kc;
        const short* Bbase = Wt + (size_t)kp * DD * DD;
        const short* Bg0 = Bbase + (size_t)(n0 + r0) * DD + kc;
        const short* Bg1 = Bbase + (size_t)(n0 + r1) * DD + kc;
        for (int k0 = 0; k0 < DD; k0 += 32) {
            __syncthreads();
            GLOAD_LDS16(Abase + (size_t)r0 * DD + k0, As + tid * 8);
            GLOAD_LDS16(Abase + (size_t)r1 * DD + k0, As + (256 + tid) * 8);
            GLOAD_LDS16(Bg0 + k0, Bs + tid * 8);
            GLOAD_LDS16(Bg1 + k0, Bs + (256 + tid) * 8);
            __syncthreads();
            short8 af[4], bfr[4];
#pragma unroll
            for (int mi = 0; mi < 4; mi++)
                af[mi] = *(const short8*)(As + ((wm + (mi << 4) + lq) << 5) + (quad << 3));
#pragma unroll
            for (int ni = 0; ni < 4; ni++)
                bfr[ni] = *(const short8*)(Bs + ((wn + (ni << 4) + lq) << 5) + (quad << 3));
#pragma unroll
            for (int mi = 0; mi < 4; mi++)
#pragma unroll
                for (int ni = 0; ni < 4; ni++)
                    acc[mi][ni] = __builtin_amdgcn_mfma_f32_16x16x32_bf16(
                        af[mi], bfr[ni], acc[mi][ni], 0, 0, 0);
        }
    }
#pragma unroll
    for (int ni = 0; ni < 4; ni++) {
        int col = n0 + wn + (ni << 4) + lq;
        float bv = bvec[col];
#pragma unroll
        for (int mi = 0; mi < 4; mi++)
#pragma unroll
            for (int r = 0; r < 4; r++) {
                int row = m0 + wm + (mi << 4) + (quad << 2) + r;
                float v = fmaxf(acc[mi][ni][r] + bv, 0.f);
                outp[(size_t)row * DD + col] = f2bf(v);
            }
    }
}

// ---------------------------------------------------------------- V transpose
// vt[(b*H+h)*64 + d][j] = kv[b, j, 1024 + h*64 + d]  (bf16 -> bf16)
__global__ __launch_bounds__(256) void vtrans_bf_kernel(const short* __restrict__ kvp,
                                                        short* __restrict__ vout, int Ls) {
    __shared__ short tile[32][33];
    int j0 = blockIdx.x << 5;
    int d0 = blockIdx.y << 5;
    int bh = blockIdx.z;
    int b = bh >> 4, h = bh & 15;
    int tid = threadIdx.x;
    int cc = tid & 31, rr = tid >> 5;
#pragma unroll
    for (int p = 0; p < 4; p++) {
        int jj = (p << 3) + rr;
        tile[jj][cc] = kvp[((size_t)(b * Ls + j0 + jj) << 11) + 1024 + (h << 6) + d0 + cc];
    }
    __syncthreads();
#pragma unroll
    for (int p = 0; p < 4; p++) {
        int dd = (p << 3) + rr;
        vout[((size_t)(bh * 64 + d0 + dd)) * Ls + j0 + cc] = tile[cc][dd];
    }
}

// ---------------------------------------------------------------- attention
// Uniform-work flash attention. Block = 32 q-rows x one (b,h); 4 waves =
// (2 q-subtiles) x (2 key-halves). Every wave sweeps all 4 scales over its
// key-half (960 keys total -- perfectly uniform grid). Fixed-max softmax is
// additive so key-halves combine exactly per scale via LDS: (Oa+Ob)/(la+lb).
// P staged in LDS as bf16 (direct short8 A-frag reads).
__global__ __launch_bounds__(256) void attn_fused2_kernel(
    const short* __restrict__ qb4,
    const short* __restrict__ kv0, const short* __restrict__ kv1,
    const short* __restrict__ kv2, const short* __restrict__ kv3,
    const short* __restrict__ vt0, const short* __restrict__ vt1,
    const short* __restrict__ vt2, const short* __restrict__ vt3,
    short* __restrict__ opart) {
    __shared__ __align__(16) short plds[4][16][72];
    __shared__ float cO[2][16][68];
    __shared__ float cl[2][16];
    int tid = threadIdx.x;
    int w = tid >> 6, lane = tid & 63;
    int lq = lane & 15, quad = lane >> 4;
    int qw = w & 1, kh = w >> 1;
    int bh = blockIdx.y;
    int b = bh >> 4, h = bh & 15;
    int qrow0 = b * DL + (blockIdx.x << 5) + (qw << 4);
    const float c_exp = 0.18033688f;    // log2(e)/8

#pragma unroll 1
    for (int s = 0; s < 4; s++) {
        int Ls = DL >> s;
        int half = Ls >> 1;
        int cbeg = kh * half, cend = cbeg + half;
        const short* kvp = s == 0 ? kv0 : s == 1 ? kv1 : s == 2 ? kv2 : kv3;
        const short* vtp = s == 0 ? vt0 : s == 1 ? vt1 : s == 2 ? vt2 : vt3;

        const short* qbase = qb4 + ((size_t)(qrow0 + lq) << 12) + (s << 10) +
                             (h << 6) + (quad << 3);
        short8 qf0 = *(const short8*)qbase;
        short8 qf1 = *(const short8*)(qbase + 32);

        const short* kbase = kvp + (h << 6) + (quad << 3);
        const short* vbase = vtp + ((size_t)(bh << 6)) * Ls;

        float4v O[4];
        float lpart[4] = {0.f, 0.f, 0.f, 0.f};
#pragma unroll
        for (int t = 0; t < 4; t++) O[t] = (float4v){0.f, 0.f, 0.f, 0.f};

        for (int c0 = cbeg; c0 < cend; c0 += 64) {
            float4v S[4];
#pragma unroll
            for (int t = 0; t < 4; t++) {
                const short* kp = kbase + ((size_t)(c0 + (t << 4) + lq) << 11);
                short8 kf0 = *(const short8*)kp;
                short8 kf1 = *(const short8*)(kp + 32);
                float4v z = (float4v){0.f, 0.f, 0.f, 0.f};
                z = __builtin_amdgcn_mfma_f32_16x16x32_bf16(qf0, kf0, z, 0, 0, 0);
                S[t] = __builtin_amdgcn_mfma_f32_16x16x32_bf16(qf1, kf1, z, 0, 0, 0);
            }
#pragma unroll
            for (int t = 0; t < 4; t++)
#pragma unroll
                for (int r = 0; r < 4; r++) {
                    float p = exp2f(S[t][r] * c_exp);
                    lpart[r] += p;
                    plds[w][(quad << 2) + r][(t << 4) + lq] = f2bf(p);
                }
#pragma unroll
            for (int ks = 0; ks < 2; ks++) {
                short8 af = *(const short8*)&plds[w][lq][(ks << 5) + (quad << 3)];
#pragma unroll
                for (int t = 0; t < 4; t++) {
                    short8 vf = *(const short8*)(vbase + (size_t)((t << 4) + lq) * Ls +
                                                 c0 + (ks << 5) + (quad << 3));
                    O[t] = __builtin_amdgcn_mfma_f32_16x16x32_bf16(af, vf, O[t], 0, 0, 0);
                }
            }
        }
        // reduce partial denominators across lq lanes
        float lsum[4];
#pragma unroll
        for (int r = 0; r < 4; r++) {
            float l = lpart[r];
            l += __shfl_xor(l, 1, 64);
            l += __shfl_xor(l, 2, 64);
            l += __shfl_xor(l, 4, 64);
            l += __shfl_xor(l, 8, 64);
            lsum[r] = l;
        }
        // combine key-halves (additive) and write normalized per-scale output
        if (kh == 1) {
#pragma unroll
            for (int t = 0; t < 4; t++)
#pragma unroll
                for (int r = 0; r < 4; r++)
                    cO[qw][(quad << 2) + r][(t << 4) + lq] = O[t][r];
            if (lq == 0) {
#pragma unroll
                for (int r = 0; r < 4; r++) cl[qw][(quad << 2) + r] = lsum[r];
            }
        }
        __syncthreads();
        if (kh == 0) {
            short* ob = opart + ((size_t)s << 22);
#pragma unroll
            for (int r = 0; r < 4; r++) {
                float linv = 1.0f / (lsum[r] + cl[qw][(quad << 2) + r]);
                size_t rbase = ((size_t)(qrow0 + (quad << 2) + r) << 10) + (h << 6) + lq;
#pragma unroll
                for (int t = 0; t < 4; t++) {
                    float val = (O[t][r] + cO[qw][(quad << 2) + r][(t << 4) + lq]) * linv;
                    ob[rbase + (t << 4)] = f2bf(val);
                }
            }
        }
        __syncthreads();
    }
}

// ---------------------------------------------------------------- combine
// attb = bf16( sum_s wagg[s] * opart[s] ), 8 elems/thread over 4M elems
__global__ __launch_bounds__(256) void combine_kernel(const short* __restrict__ op,
                                                      const float* __restrict__ wagg,
                                                      short* __restrict__ attb) {
    int idx = (blockIdx.x * 256 + threadIdx.x) << 3;
    float w0 = wagg[0], w1 = wagg[1], w2 = wagg[2], w3 = wagg[3];
    short8 a0 = *(const short8*)(op + idx);
    short8 a1 = *(const short8*)(op + (1u << 22) + idx);
    short8 a2 = *(const short8*)(op + (2u << 22) + idx);
    short8 a3 = *(const short8*)(op + (3u << 22) + idx);
    short8 o;
#pragma unroll
    for (int j = 0; j < 8; j++)
        o[j] = f2bf(w0 * bf2f(a0[j]) + w1 * bf2f(a1[j]) +
                    w2 * bf2f(a2[j]) + w3 * bf2f(a3[j]));
    *(short8*)(attb + idx) = o;
}

// ---------------------------------------------------------------- add + LN
template <int OBF>
__global__ __launch_bounds__(256) void addln_kernel(
    const float* __restrict__ a, const float* __restrict__ bsrc,
    const float* __restrict__ gam, const float* __restrict__ bet,
    float* __restrict__ out, short* __restrict__ outb) {
    __shared__ float redA[4], redB[4];
    int row = blockIdx.x, tid = threadIdx.x;
    size_t base = (size_t)row * DD + (tid << 2);
    float4 av = *(const float4*)&a[base];
    float4 bv = *(const float4*)&bsrc[base];
    float s0 = av.x + bv.x, s1 = av.y + bv.y, s2 = av.z + bv.z, s3 = av.w + bv.w;
    float lsum = s0 + s1 + s2 + s3;
    float lsq = s0 * s0 + s1 * s1 + s2 * s2 + s3 * s3;
#pragma unroll
    for (int o = 32; o > 0; o >>= 1) {
        lsum += __shfl_down(lsum, o, 64);
        lsq += __shfl_down(lsq, o, 64);
    }
    int lane = tid & 63, wid = tid >> 6;
    if (lane == 0) { redA[wid] = lsum; redB[wid] = lsq; }
    __syncthreads();
    float tsum = redA[0] + redA[1] + redA[2] + redA[3];
    float tsq = redB[0] + redB[1] + redB[2] + redB[3];
    float mean = tsum * (1.0f / DD);
    float var = tsq * (1.0f / DD) - mean * mean;
    float rstd = rsqrtf(var + 1e-5f);
    float4 gv = *(const float4*)&gam[tid << 2];
    float4 bev = *(const float4*)&bet[tid << 2];
    float4 o;
    o.x = (s0 - mean) * rstd * gv.x + bev.x;
    o.y = (s1 - mean) * rstd * gv.y + bev.y;
    o.z = (s2 - mean) * rstd * gv.z + bev.z;
    o.w = (s3 - mean) * rstd * gv.w + bev.w;
    *(float4*)&out[base] = o;
    if (OBF) {
        ushort4 u;
        u.x = (unsigned short)f2bf(o.x);
        u.y = (unsigned short)f2bf(o.y);
        u.z = (unsigned short)f2bf(o.z);
        u.w = (unsigned short)f2bf(o.w);
        *(ushort4*)&outb[base] = u;
    }
}

// ---------------------------------------------------------------- launcher
extern "C" void kernel_launch(void* const* d_in, const int* in_sizes, int n_in,
                              void* d_out, int out_size, void* d_ws, size_t ws_size,
                              hipStream_t stream) {
    (void)in_sizes; (void)n_in; (void)out_size; (void)ws_size;
    const float* x   = (const float*)d_in[0];
    const float* Wdc = (const float*)d_in[1];
    const float* bdc = (const float*)d_in[2];
    const float* Wdec= (const float*)d_in[3];
    const float* Wq  = (const float*)d_in[4];
    const float* Wk  = (const float*)d_in[5];
    const float* Wv  = (const float*)d_in[6];
    const float* Wo  = (const float*)d_in[7];
    const float* agg = (const float*)d_in[8];
    const float* g1  = (const float*)d_in[9];
    const float* be1 = (const float*)d_in[10];
    const float* g2  = (const float*)d_in[11];
    const float* be2 = (const float*)d_in[12];
    const float* W1  = (const float*)d_in[13];
    const float* b1  = (const float*)d_in[14];
    const float* W2  = (const float*)d_in[15];
    const float* b2  = (const float*)d_in[16];
    float* out = (float*)d_out;

    float* ws = (float*)d_ws;
    size_t off = 0;
    auto alloc = [&](size_t nfloats) { float* p = ws + off; off += nfloats; return p; };
    const size_t M1 = 1024 * 1024;
    short* wdc_bt  = (short*)alloc(3 * M1 / 2);     // 3M bf16
    short* wdec_bt = (short*)alloc(3 * M1);         // 6M bf16
    short* wq4t    = (short*)alloc(2 * M1);         // 4M bf16: 4x Wq^T stacked
    short* wkvt    = (short*)alloc(4 * M1);         // 4 scales x [Wk[s]^T;Wv^T]
    short* wot     = (short*)alloc(M1 / 2);
    short* w1t     = (short*)alloc(2 * M1);
    short* w2t     = (short*)alloc(2 * M1);
    float* wagg    = alloc(64);
    short* xpad    = (short*)alloc(2105344);        // 4*1028*1024 bf16
    short* xcb     = (short*)alloc(2 * M1);
    short* s1b     = (short*)alloc(M1);
    short* s2b     = (short*)alloc(M1 / 2);
    short* s3b     = (short*)alloc(M1 / 4);
    short* qb4     = (short*)alloc(8 * M1);         // [4096][4096] bf16; later FFN hidden
    short* kv0     = (short*)alloc(4 * M1);         // [4096][2048] bf16; later mahab/fb
    short* kv1     = (short*)alloc(2 * M1);
    short* kv2     = (short*)alloc(M1);
    short* kv3     = (short*)alloc(M1 / 2);
    short* vt0     = (short*)alloc(2 * M1);
    short* vt1     = (short*)alloc(M1);
    short* vt2     = (short*)alloc(M1 / 2);
    short* vt3     = (short*)alloc(M1 / 4);
    short* oparts  = (short*)alloc(8 * M1);         // 4 x 4M bf16
    short* attb    = (short*)alloc(2 * M1);
    float* x1      = alloc(4 * M1);
    short* x1b     = (short*)alloc(2 * M1);
    short* hb      = qb4;                           // FFN hidden [4096][4096] bf16
    float* mahab   = (float*)kv0;                   // 4M fp32
    float* fb      = (float*)kv0;                   // 4M fp32 (after mahab dead)

    dim3 blk(256);
    // ---- prep
    wdcprep_kernel<<<dim3(3 * M1 / 256), blk, 0, stream>>>(Wdc, wdc_bt);
    wdecprep_kernel<<<dim3(6 * M1 / 256), blk, 0, stream>>>(Wdec, wdec_bt);
    tcsq_kernel<<<dim3(32, 32, 13), blk, 0, stream>>>(Wq, Wk, Wv, Wo, wq4t, wkvt, wot);
    tc_kernel<<<dim3(128, 32), blk, 0, stream>>>(W1, w1t, DD, DF);
    tc_kernel<<<dim3(32, 128), blk, 0, stream>>>(W2, w2t, DF, DD);
    xpad_kernel<<<dim3(2105344 * 2 / 256), blk, 0, stream>>>(x, xpad);
    aux_kernel<<<dim3(1), dim3(64), 0, stream>>>(agg, wagg, out + (size_t)DB * DL * DD);

    // 1. dilated conv + relu
    convdil_mfma_kernel<<<dim3(DD / 128, DB * DL / 128), blk, 0, stream>>>(
        xpad, wdc_bt, bdc, xcb);

    // 2. decomposition convs
    mgemm_kernel<0, 1><<<dim3(DD / 128, (DB * DL / 2) / 128), blk, 0, stream>>>(
        xcb, wdec_bt, nullptr, s1b, DB * DL / 2, DD, 2 * DD);
    mgemm_kernel<0, 1><<<dim3(DD / 128, (DB * DL / 4) / 128), blk, 0, stream>>>(
        s1b, wdec_bt + 2 * M1, nullptr, s2b, DB * DL / 4, DD, 2 * DD);
    mgemm_kernel<0, 1><<<dim3(DD / 128, (DB * DL / 8) / 128), blk, 0, stream>>>(
        s2b, wdec_bt + 4 * M1, nullptr, s3b, DB * DL / 8, DD, 2 * DD);

    // 3a. batched Q projection (all 4 scales, N=4096)
    mgemm_kernel<0, 1><<<dim3(32, 32), blk, 0, stream>>>(
        xcb, wq4t, nullptr, qb4, DB * DL, 4 * DD, DD);

    // 3b. fused K|V projections per scale (N=2048) + V transpose
    const short* scl[4] = {xcb, s1b, s2b, s3b};
    short* kvs[4] = {kv0, kv1, kv2, kv3};
    short* vts[4] = {vt0, vt1, vt2, vt3};
    for (int s = 0; s < 4; s++) {
        int Ls = DL >> s;
        int rows = DB * Ls;
        mgemm_kernel<0, 1><<<dim3(16, rows / 128), blk, 0, stream>>>(
            scl[s], wkvt + (size_t)s * 2 * M1, nullptr, kvs[s], rows, 2048, DD);
        vtrans_bf_kernel<<<dim3(Ls / 32, 2, DB * DH), blk, 0, stream>>>(kvs[s], vts[s], Ls);
    }

    // 3c. uniform-work fused attention (one dispatch, 2048 equal blocks)
    attn_fused2_kernel<<<dim3(DL / 32, DB * DH), blk, 0, stream>>>(
        qb4, kv0, kv1, kv2, kv3, vt0, vt1, vt2, vt3, oparts);

    // 3d. convex aggregation
    combine_kernel<<<dim3(4 * M1 / (256 * 8)), blk, 0, stream>>>(oparts, wagg, attb);

    // 4. shared output projection
    mgemm_kernel<0, 0><<<dim3(DD / 128, (DB * DL) / 128), blk, 0, stream>>>(
        attb, wot, nullptr, mahab, DB * DL, DD, DD);

    // 5. residual + LN1
    addln_kernel<1><<<dim3(DB * DL), blk, 0, stream>>>(x, mahab, g1, be1, x1, x1b);

    // 6. FFN with exact GELU
    mgemm_kernel<1, 1><<<dim3(DF / 128, (DB * DL) / 128), blk, 0, stream>>>(
        x1b, w1t, b1, hb, DB * DL, DF, DD);
    mgemm_kernel<0, 0><<<dim3(DD / 128, (DB * DL) / 128), blk, 0, stream>>>(
        hb, w2t, b2, fb, DB * DL, DD, DF);

    // 7. residual + LN2 -> out
    addln_kernel<0><<<dim3(DB * DL), blk, 0, stream>>>(x1, fb, g2, be2, out, nullptr);
}

// Round 6
// 974.973 us; speedup vs baseline: 4.9040x; 1.0565x over previous
//
#include <hip/hip_runtime.h>
#include <cstddef>

#define DB 4
#define DL 1024
#define DD 1024
#define DH 16
#define DF 4096

typedef __attribute__((ext_vector_type(8))) short short8;
typedef __attribute__((ext_vector_type(4))) float float4v;

static __device__ __forceinline__ short f2bf(float f) {
    unsigned u = __float_as_uint(f);
    unsigned r = (u + 0x7FFFu + ((u >> 16) & 1u)) >> 16;   // RNE
    return (short)r;
}
static __device__ __forceinline__ float bf2f(short s) {
    return __uint_as_float(((unsigned)(unsigned short)s) << 16);
}

#if defined(__has_builtin)
#if __has_builtin(__builtin_amdgcn_exp2f)
#define EXP2F(x) __builtin_amdgcn_exp2f(x)
#else
#define EXP2F(x) exp2f(x)
#endif
#else
#define EXP2F(x) exp2f(x)
#endif

#define GLOAD_LDS16(gp, lp)                                                          \
    __builtin_amdgcn_global_load_lds(                                                \
        (const __attribute__((address_space(1))) void*)(gp),                         \
        (__attribute__((address_space(3))) void*)(lp), 16, 0, 0)

// ---------------------------------------------------------------- weight prep
// wdc_bt[k][o][i] = bf16(W_dc[(o*D + i)*3 + k])   (B^T per tap, [N=o][K=i])
__global__ __launch_bounds__(256) void wdcprep_kernel(const float* __restrict__ W,
                                                      short* __restrict__ Wt) {
    int idx = blockIdx.x * 256 + threadIdx.x;           // 3*D*D
    int i = idx & 1023;
    int o = (idx >> 10) & 1023;
    int k = idx >> 20;
    Wt[idx] = f2bf(W[((size_t)o * 1024 + i) * 3 + k]);
}

// wdec_bt[s][n][k2*D+i] = bf16(W_dec[((s*D+n)*D + i)*2 + k2])  ([N][K=2D])
__global__ __launch_bounds__(256) void wdecprep_kernel(const float* __restrict__ W,
                                                       short* __restrict__ Wt) {
    int idx = blockIdx.x * 256 + threadIdx.x;           // 3*2*D*D
    int i = idx & 1023;
    int k2 = (idx >> 10) & 1;
    int n = (idx >> 11) & 1023;
    int s = idx >> 21;
    Wt[idx] = f2bf(W[(((size_t)(s * 1024 + n)) * 1024 + i) * 2 + k2]);
}

// generic transpose-cast: in fp32 [K][N] -> out bf16 [N][K]
__global__ __launch_bounds__(256) void tc_kernel(const float* __restrict__ in,
                                                 short* __restrict__ outp, int K, int N) {
    __shared__ float tile[32][33];
    int n0 = blockIdx.x << 5, k0 = blockIdx.y << 5;
    int tid = threadIdx.x;
    int cc = tid & 31, rr = tid >> 5;
#pragma unroll
    for (int p = 0; p < 4; p++) {
        int kk = (p << 3) + rr;
        tile[kk][cc] = in[(size_t)(k0 + kk) * N + n0 + cc];
    }
    __syncthreads();
#pragma unroll
    for (int p = 0; p < 4; p++) {
        int nn = (p << 3) + rr;
        outp[(size_t)(n0 + nn) * K + k0 + cc] = f2bf(tile[cc][nn]);
    }
}

// batched square (1024x1024) transpose-casts, z selects the weight
__global__ __launch_bounds__(256) void tcsq_kernel(
    const float* __restrict__ Wq, const float* __restrict__ Wk,
    const float* __restrict__ Wv, const float* __restrict__ Wo,
    short* __restrict__ wq4t, short* __restrict__ wkvt, short* __restrict__ wot) {
    const size_t M1 = 1024 * 1024;
    int z = blockIdx.z;
    const float* src;
    short* dst;
    if (z < 4)      { src = Wq + (size_t)z * M1;       dst = wq4t + (size_t)z * M1; }
    else if (z < 8) { src = Wk + (size_t)(z - 4) * M1; dst = wkvt + (size_t)(z - 4) * 2 * M1; }
    else if (z < 12){ src = Wv;                        dst = wkvt + (size_t)(z - 8) * 2 * M1 + M1; }
    else            { src = Wo;                        dst = wot; }
    __shared__ float tile[32][33];
    int n0 = blockIdx.x << 5, k0 = blockIdx.y << 5;
    int tid = threadIdx.x;
    int cc = tid & 31, rr = tid >> 5;
#pragma unroll
    for (int p = 0; p < 4; p++) {
        int kk = (p << 3) + rr;
        tile[kk][cc] = src[(size_t)(k0 + kk) * DD + n0 + cc];
    }
    __syncthreads();
#pragma unroll
    for (int p = 0; p < 4; p++) {
        int nn = (p << 3) + rr;
        dst[(size_t)(n0 + nn) * DD + k0 + cc] = f2bf(tile[cc][nn]);
    }
}

// zero-padded bf16 x: xpad[b][l+2][d] = bf16(x[b][l][d]), rows 0,1,L+2,L+3 = 0
__global__ __launch_bounds__(256) void xpad_kernel(const float* __restrict__ x,
                                                   short* __restrict__ xp) {
    int idx = blockIdx.x * 256 + threadIdx.x;           // 4*1028*1024
    int d = idx & 1023;
    int row = (idx >> 10) % 1028;
    int b = (idx >> 10) / 1028;
    int l = row - 2;
    float v = (l >= 0 && l < DL) ? x[((size_t)(b * DL + l)) * DD + d] : 0.f;
    xp[idx] = f2bf(v);
}

// softmax of agg_logits (S=4) + entropy aux loss
__global__ void aux_kernel(const float* __restrict__ logits,
                           float* __restrict__ w, float* __restrict__ aux) {
    if (threadIdx.x == 0 && blockIdx.x == 0) {
        float l0 = logits[0], l1 = logits[1], l2 = logits[2], l3 = logits[3];
        float m = fmaxf(fmaxf(l0, l1), fmaxf(l2, l3));
        float e0 = __expf(l0 - m), e1 = __expf(l1 - m);
        float e2 = __expf(l2 - m), e3 = __expf(l3 - m);
        float s = e0 + e1 + e2 + e3;
        float w0 = e0 / s, w1 = e1 / s, w2 = e2 / s, w3 = e3 / s;
        w[0] = w0; w[1] = w1; w[2] = w2; w[3] = w3;
        *aux = -(w0 * logf(w0 + 1e-9f) + w1 * logf(w1 + 1e-9f) +
                 w2 * logf(w2 + 1e-9f) + w3 * logf(w3 + 1e-9f));
    }
}

// ---------------------------------------------------------------- MFMA GEMM
// C[M,N] = act(A[M,K] @ B[K,N] + bias), A bf16 [M][K], Bt bf16 [N][K].
// 128x128 tile, BK=32, 4 waves -> 64x64 each, 16x16x32 bf16 MFMA.
template <int ACT, int OBF>
__global__ __launch_bounds__(256) void mgemm_kernel(
    const short* __restrict__ A, const short* __restrict__ Bt,
    const float* __restrict__ bias, void* __restrict__ Cv,
    int M, int N, int K) {
    __shared__ short As[128 * 32];
    __shared__ short Bs[128 * 32];
    int tid = threadIdx.x;
    int wave = tid >> 6, lane = tid & 63;
    int lq = lane & 15, quad = lane >> 4;
    int m0 = blockIdx.y << 7, n0 = blockIdx.x << 7;
    int wm = (wave & 1) << 6, wn = (wave >> 1) << 6;
    int r0 = tid >> 2, r1 = (256 + tid) >> 2;
    int kc0 = (tid & 3) << 3;
    const short* Ag0 = A + (size_t)(m0 + r0) * K + kc0;
    const short* Ag1 = A + (size_t)(m0 + r1) * K + kc0;
    const short* Bg0 = Bt + (size_t)(n0 + r0) * K + kc0;
    const short* Bg1 = Bt + (size_t)(n0 + r1) * K + kc0;
    float4v acc[4][4];
#pragma unroll
    for (int mi = 0; mi < 4; mi++)
#pragma unroll
        for (int ni = 0; ni < 4; ni++) acc[mi][ni] = (float4v){0.f, 0.f, 0.f, 0.f};

    for (int k0 = 0; k0 < K; k0 += 32) {
        __syncthreads();
        GLOAD_LDS16(Ag0 + k0, As + tid * 8);
        GLOAD_LDS16(Ag1 + k0, As + (256 + tid) * 8);
        GLOAD_LDS16(Bg0 + k0, Bs + tid * 8);
        GLOAD_LDS16(Bg1 + k0, Bs + (256 + tid) * 8);
        __syncthreads();
        short8 af[4], bfr[4];
#pragma unroll
        for (int mi = 0; mi < 4; mi++)
            af[mi] = *(const short8*)(As + ((wm + (mi << 4) + lq) << 5) + (quad << 3));
#pragma unroll
        for (int ni = 0; ni < 4; ni++)
            bfr[ni] = *(const short8*)(Bs + ((wn + (ni << 4) + lq) << 5) + (quad << 3));
#pragma unroll
        for (int mi = 0; mi < 4; mi++)
#pragma unroll
            for (int ni = 0; ni < 4; ni++)
                acc[mi][ni] = __builtin_amdgcn_mfma_f32_16x16x32_bf16(
                    af[mi], bfr[ni], acc[mi][ni], 0, 0, 0);
    }
#pragma unroll
    for (int ni = 0; ni < 4; ni++) {
        int col = n0 + wn + (ni << 4) + lq;
        float bv = bias ? bias[col] : 0.f;
#pragma unroll
        for (int mi = 0; mi < 4; mi++) {
#pragma unroll
            for (int r = 0; r < 4; r++) {
                int row = m0 + wm + (mi << 4) + (quad << 2) + r;
                float v = acc[mi][ni][r] + bv;
                if (ACT == 1) v = 0.5f * v * (1.0f + erff(v * 0.70710678118654752f));
                if (OBF) ((short*)Cv)[(size_t)row * N + col] = f2bf(v);
                else ((float*)Cv)[(size_t)row * N + col] = v;
            }
        }
    }
}

// ---------------------------------------------------------------- conv MFMA
__global__ __launch_bounds__(256) void convdil_mfma_kernel(
    const short* __restrict__ xp, const short* __restrict__ Wt,
    const float* __restrict__ bvec, short* __restrict__ outp) {
    __shared__ short As[128 * 32];
    __shared__ short Bs[128 * 32];
    int tid = threadIdx.x;
    int wave = tid >> 6, lane = tid & 63;
    int lq = lane & 15, quad = lane >> 4;
    int m0 = blockIdx.y << 7, n0 = blockIdx.x << 7;
    int wm = (wave & 1) << 6, wn = (wave >> 1) << 6;
    int b = m0 >> 10, ll0 = m0 & 1023;
    int r0 = tid >> 2, r1 = (256 + tid) >> 2;
    int kc = (tid & 3) << 3;
    float4v acc[4][4];
#pragma unroll
    for (int mi = 0; mi < 4; mi++)
#pragma unroll
        for (int ni = 0; ni < 4; ni++) acc[mi][ni] = (float4v){0.f, 0.f, 0.f, 0.f};

    for (int kp = 0; kp < 3; kp++) {
        const short* Abase = xp + ((size_t)(b * 1028 + ll0 + 2 * kp)) * DD + kc;
        const short* Bbase = Wt + (size_t)kp * DD * DD;
        const short* Bg0 = Bbase + (size_t)(n0 + r0) * DD + kc;
        const short* Bg1 = Bbase + (size_t)(n0 + r1) * DD + kc;
        for (int k0 = 0; k0 < DD; k0 += 32) {
            __syncthreads();
            GLOAD_LDS16(Abase + (size_t)r0 * DD + k0, As + tid * 8);
            GLOAD_LDS16(Abase + (size_t)r1 * DD + k0, As + (256 + tid) * 8);
            GLOAD_LDS16(Bg0 + k0, Bs + tid * 8);
            GLOAD_LDS16(Bg1 + k0, Bs + (256 + tid) * 8);
            __syncthreads();
            short8 af[4], bfr[4];
#pragma unroll
            for (int mi = 0; mi < 4; mi++)
                af[mi] = *(const short8*)(As + ((wm + (mi << 4) + lq) << 5) + (quad << 3));
#pragma unroll
            for (int ni = 0; ni < 4; ni++)
                bfr[ni] = *(const short8*)(Bs + ((wn + (ni << 4) + lq) << 5) + (quad << 3));
#pragma unroll
            for (int mi = 0; mi < 4; mi++)
#pragma unroll
                for (int ni = 0; ni < 4; ni++)
                    acc[mi][ni] = __builtin_amdgcn_mfma_f32_16x16x32_bf16(
                        af[mi], bfr[ni], acc[mi][ni], 0, 0, 0);
        }
    }
#pragma unroll
    for (int ni = 0; ni < 4; ni++) {
        int col = n0 + wn + (ni << 4) + lq;
        float bv = bvec[col];
#pragma unroll
        for (int mi = 0; mi < 4; mi++)
#pragma unroll
            for (int r = 0; r < 4; r++) {
                int row = m0 + wm + (mi << 4) + (quad << 2) + r;
                float v = fmaxf(acc[mi][ni][r] + bv, 0.f);
                outp[(size_t)row * DD + col] = f2bf(v);
            }
    }
}

// ---------------------------------------------------------------- K fragment prep
// kfr[bh][g=j>>4][dc 0..7][lq=j&15][8 dims]  <-  kv[(b*Ls+j)][h*64 + dc*8 ..]
// Fragment loads in attention become lane-contiguous (fully coalesced).
__global__ __launch_bounds__(256) void kfrag_kernel(const short* __restrict__ kv,
                                                    short* __restrict__ kfr,
                                                    int Ls, int lsh) {
    int idx = blockIdx.x * 256 + threadIdx.x;   // DB*Ls*128 short8-entries
    int rem = idx & 127;
    int h = rem >> 3, dc = rem & 7;
    int jg = idx >> 7;                           // global key row (b*Ls + j)
    int b = jg >> lsh;
    int j = jg & (Ls - 1);
    short8 v = *(const short8*)(kv + ((size_t)jg << 11) + (h << 6) + (dc << 3));
    int bh = (b << 4) | h;
    int g = j >> 4, lq = j & 15;
    *(short8*)(kfr + (((size_t)bh * (Ls >> 4) + g) << 10) + (dc << 7) + (lq << 3)) = v;
}

// ---------------------------------------------------------------- V fragment prep
// vfr[bh][c=j>>6][ks=(j>>5)&1][t=d>>4][lq=d&15][j&31]  <- kv V-part, via LDS transpose
__global__ __launch_bounds__(256) void vfrag_kernel(const short* __restrict__ kvp,
                                                    short* __restrict__ vfr, int Ls) {
    __shared__ short tile[32][33];
    int j0 = blockIdx.x << 5;
    int d0 = blockIdx.y << 5;
    int bh = blockIdx.z;
    int b = bh >> 4, h = bh & 15;
    int tid = threadIdx.x;
    int cc = tid & 31, rr = tid >> 5;
#pragma unroll
    for (int p = 0; p < 4; p++) {
        int jj = (p << 3) + rr;
        tile[jj][cc] = kvp[((size_t)(b * Ls + j0 + jj) << 11) + 1024 + (h << 6) + d0 + cc];
    }
    __syncthreads();
    int c = j0 >> 6, ks = (j0 >> 5) & 1;
#pragma unroll
    for (int p = 0; p < 4; p++) {
        int d = d0 + (p << 3) + rr;
        int t = d >> 4, lqv = d & 15;
        size_t off = (((size_t)bh * (Ls >> 6) + c) << 12) + (ks << 11) +
                     (t << 9) + (lqv << 5) + cc;
        vfr[off] = tile[cc][(p << 3) + rr];
    }
}

// ---------------------------------------------------------------- attention
// Uniform-work flash attention with FRAGMENT-LAYOUT K/V (all loads coalesced).
// Block = 32 q-rows x one (b,h); 4 waves = (2 q-subtiles) x (2 key-halves).
// Fixed-max softmax (additive across key-halves), P in per-wave LDS as bf16.
__global__ __launch_bounds__(256) void attn_fused3_kernel(
    const short* __restrict__ qb4,
    const short* __restrict__ kf0p, const short* __restrict__ kf1p,
    const short* __restrict__ kf2p, const short* __restrict__ kf3p,
    const short* __restrict__ vf0p, const short* __restrict__ vf1p,
    const short* __restrict__ vf2p, const short* __restrict__ vf3p,
    short* __restrict__ opart) {
    __shared__ __align__(16) short plds[4][16][72];
    __shared__ float cO[2][16][68];
    __shared__ float cl[2][16];
    int tid = threadIdx.x;
    int w = tid >> 6, lane = tid & 63;
    int lq = lane & 15, quad = lane >> 4;
    int qw = w & 1, kh = w >> 1;
    int bh = blockIdx.y;
    int b = bh >> 4, h = bh & 15;
    int qrow0 = b * DL + (blockIdx.x << 5) + (qw << 4);
    const float c_exp = 0.18033688f;    // log2(e)/8

#pragma unroll 1
    for (int s = 0; s < 4; s++) {
        int Ls = DL >> s;
        int half = Ls >> 1;
        int cbeg = kh * half, cend = cbeg + half;
        const short* kfr = s == 0 ? kf0p : s == 1 ? kf1p : s == 2 ? kf2p : kf3p;
        const short* vfr = s == 0 ? vf0p : s == 1 ? vf1p : s == 2 ? vf2p : vf3p;

        const short* qbase = qb4 + ((size_t)(qrow0 + lq) << 12) + (s << 10) +
                             (h << 6) + (quad << 3);
        short8 qf0 = *(const short8*)qbase;
        short8 qf1 = *(const short8*)(qbase + 32);

        const short* kfb = kfr + (((size_t)bh * (Ls >> 4)) << 10) + (quad << 7) + (lq << 3);
        const short* vfb = vfr + (((size_t)bh * (Ls >> 6)) << 12) + (lq << 5) + (quad << 3);

        float4v O[4];
        float lpart[4] = {0.f, 0.f, 0.f, 0.f};
#pragma unroll
        for (int t = 0; t < 4; t++) O[t] = (float4v){0.f, 0.f, 0.f, 0.f};

        for (int c0 = cbeg; c0 < cend; c0 += 64) {
            float4v S[4];
            int g0 = c0 >> 4;
#pragma unroll
            for (int t = 0; t < 4; t++) {
                const short* kp = kfb + ((size_t)(g0 + t) << 10);
                short8 kf0 = *(const short8*)kp;
                short8 kf1 = *(const short8*)(kp + 512);
                float4v z = (float4v){0.f, 0.f, 0.f, 0.f};
                z = __builtin_amdgcn_mfma_f32_16x16x32_bf16(qf0, kf0, z, 0, 0, 0);
                S[t] = __builtin_amdgcn_mfma_f32_16x16x32_bf16(qf1, kf1, z, 0, 0, 0);
            }
#pragma unroll
            for (int t = 0; t < 4; t++)
#pragma unroll
                for (int r = 0; r < 4; r++) {
                    float p = EXP2F(S[t][r] * c_exp);
                    lpart[r] += p;
                    plds[w][(quad << 2) + r][(t << 4) + lq] =
                        (short)(__float_as_uint(p) >> 16);   // trunc-bf16
                }
            const short* vcb = vfb + ((size_t)(c0 >> 6) << 12);
#pragma unroll
            for (int ks = 0; ks < 2; ks++) {
                short8 af = *(const short8*)&plds[w][lq][(ks << 5) + (quad << 3)];
#pragma unroll
                for (int t = 0; t < 4; t++) {
                    short8 vf = *(const short8*)(vcb + (ks << 11) + (t << 9));
                    O[t] = __builtin_amdgcn_mfma_f32_16x16x32_bf16(af, vf, O[t], 0, 0, 0);
                }
            }
        }
        // reduce partial denominators across lq lanes
        float lsum[4];
#pragma unroll
        for (int r = 0; r < 4; r++) {
            float l = lpart[r];
            l += __shfl_xor(l, 1, 64);
            l += __shfl_xor(l, 2, 64);
            l += __shfl_xor(l, 4, 64);
            l += __shfl_xor(l, 8, 64);
            lsum[r] = l;
        }
        // combine key-halves (additive) and write normalized per-scale output
        if (kh == 1) {
#pragma unroll
            for (int t = 0; t < 4; t++)
#pragma unroll
                for (int r = 0; r < 4; r++)
                    cO[qw][(quad << 2) + r][(t << 4) + lq] = O[t][r];
            if (lq == 0) {
#pragma unroll
                for (int r = 0; r < 4; r++) cl[qw][(quad << 2) + r] = lsum[r];
            }
        }
        __syncthreads();
        if (kh == 0) {
            short* ob = opart + ((size_t)s << 22);
#pragma unroll
            for (int r = 0; r < 4; r++) {
                float linv = 1.0f / (lsum[r] + cl[qw][(quad << 2) + r]);
                size_t rbase = ((size_t)(qrow0 + (quad << 2) + r) << 10) + (h << 6) + lq;
#pragma unroll
                for (int t = 0; t < 4; t++) {
                    float val = (O[t][r] + cO[qw][(quad << 2) + r][(t << 4) + lq]) * linv;
                    ob[rbase + (t << 4)] = f2bf(val);
                }
            }
        }
        __syncthreads();
    }
}

// ---------------------------------------------------------------- combine
// attb = bf16( sum_s wagg[s] * opart[s] ), 8 elems/thread over 4M elems
__global__ __launch_bounds__(256) void combine_kernel(const short* __restrict__ op,
                                                      const float* __restrict__ wagg,
                                                      short* __restrict__ attb) {
    int idx = (blockIdx.x * 256 + threadIdx.x) << 3;
    float w0 = wagg[0], w1 = wagg[1], w2 = wagg[2], w3 = wagg[3];
    short8 a0 = *(const short8*)(op + idx);
    short8 a1 = *(const short8*)(op + (1u << 22) + idx);
    short8 a2 = *(const short8*)(op + (2u << 22) + idx);
    short8 a3 = *(const short8*)(op + (3u << 22) + idx);
    short8 o;
#pragma unroll
    for (int j = 0; j < 8; j++)
        o[j] = f2bf(w0 * bf2f(a0[j]) + w1 * bf2f(a1[j]) +
                    w2 * bf2f(a2[j]) + w3 * bf2f(a3[j]));
    *(short8*)(attb + idx) = o;
}

// ---------------------------------------------------------------- add + LN
template <int OBF>
__global__ __launch_bounds__(256) void addln_kernel(
    const float* __restrict__ a, const float* __restrict__ bsrc,
    const float* __restrict__ gam, const float* __restrict__ bet,
    float* __restrict__ out, short* __restrict__ outb) {
    __shared__ float redA[4], redB[4];
    int row = blockIdx.x, tid = threadIdx.x;
    size_t base = (size_t)row * DD + (tid << 2);
    float4 av = *(const float4*)&a[base];
    float4 bv = *(const float4*)&bsrc[base];
    float s0 = av.x + bv.x, s1 = av.y + bv.y, s2 = av.z + bv.z, s3 = av.w + bv.w;
    float lsum = s0 + s1 + s2 + s3;
    float lsq = s0 * s0 + s1 * s1 + s2 * s2 + s3 * s3;
#pragma unroll
    for (int o = 32; o > 0; o >>= 1) {
        lsum += __shfl_down(lsum, o, 64);
        lsq += __shfl_down(lsq, o, 64);
    }
    int lane = tid & 63, wid = tid >> 6;
    if (lane == 0) { redA[wid] = lsum; redB[wid] = lsq; }
    __syncthreads();
    float tsum = redA[0] + redA[1] + redA[2] + redA[3];
    float tsq = redB[0] + redB[1] + redB[2] + redB[3];
    float mean = tsum * (1.0f / DD);
    float var = tsq * (1.0f / DD) - mean * mean;
    float rstd = rsqrtf(var + 1e-5f);
    float4 gv = *(const float4*)&gam[tid << 2];
    float4 bev = *(const float4*)&bet[tid << 2];
    float4 o;
    o.x = (s0 - mean) * rstd * gv.x + bev.x;
    o.y = (s1 - mean) * rstd * gv.y + bev.y;
    o.z = (s2 - mean) * rstd * gv.z + bev.z;
    o.w = (s3 - mean) * rstd * gv.w + bev.w;
    *(float4*)&out[base] = o;
    if (OBF) {
        ushort4 u;
        u.x = (unsigned short)f2bf(o.x);
        u.y = (unsigned short)f2bf(o.y);
        u.z = (unsigned short)f2bf(o.z);
        u.w = (unsigned short)f2bf(o.w);
        *(ushort4*)&outb[base] = u;
    }
}

// ---------------------------------------------------------------- launcher
extern "C" void kernel_launch(void* const* d_in, const int* in_sizes, int n_in,
                              void* d_out, int out_size, void* d_ws, size_t ws_size,
                              hipStream_t stream) {
    (void)in_sizes; (void)n_in; (void)out_size; (void)ws_size;
    const float* x   = (const float*)d_in[0];
    const float* Wdc = (const float*)d_in[1];
    const float* bdc = (const float*)d_in[2];
    const float* Wdec= (const float*)d_in[3];
    const float* Wq  = (const float*)d_in[4];
    const float* Wk  = (const float*)d_in[5];
    const float* Wv  = (const float*)d_in[6];
    const float* Wo  = (const float*)d_in[7];
    const float* agg = (const float*)d_in[8];
    const float* g1  = (const float*)d_in[9];
    const float* be1 = (const float*)d_in[10];
    const float* g2  = (const float*)d_in[11];
    const float* be2 = (const float*)d_in[12];
    const float* W1  = (const float*)d_in[13];
    const float* b1  = (const float*)d_in[14];
    const float* W2  = (const float*)d_in[15];
    const float* b2  = (const float*)d_in[16];
    float* out = (float*)d_out;

    float* ws = (float*)d_ws;
    size_t off = 0;
    auto alloc = [&](size_t nfloats) { float* p = ws + off; off += nfloats; return p; };
    const size_t M1 = 1024 * 1024;
    short* wdc_bt  = (short*)alloc(3 * M1 / 2);
    short* wdec_bt = (short*)alloc(3 * M1);
    short* wq4t    = (short*)alloc(2 * M1);
    short* wkvt    = (short*)alloc(4 * M1);
    short* wot     = (short*)alloc(M1 / 2);
    short* w1t     = (short*)alloc(2 * M1);
    short* w2t     = (short*)alloc(2 * M1);
    float* wagg    = alloc(64);
    short* xpad    = (short*)alloc(2105344);
    short* xcb     = (short*)alloc(2 * M1);
    short* s1b     = (short*)alloc(M1);
    short* s2b     = (short*)alloc(M1 / 2);
    short* s3b     = (short*)alloc(M1 / 4);
    short* qb4     = (short*)alloc(8 * M1);         // later FFN hidden
    short* kv0     = (short*)alloc(4 * M1);         // later mahab/fb
    short* kv1     = (short*)alloc(2 * M1);
    short* kv2     = (short*)alloc(M1);
    short* kv3     = (short*)alloc(M1 / 2);
    short* kfr0    = (short*)alloc(2 * M1);         // K fragment layouts
    short* kfr1    = (short*)alloc(M1);
    short* kfr2    = (short*)alloc(M1 / 2);
    short* kfr3    = (short*)alloc(M1 / 4);
    short* vfr0    = (short*)alloc(2 * M1);         // V fragment layouts
    short* vfr1    = (short*)alloc(M1);
    short* vfr2    = (short*)alloc(M1 / 2);
    short* vfr3    = (short*)alloc(M1 / 4);
    short* oparts  = (short*)alloc(8 * M1);
    short* attb    = (short*)alloc(2 * M1);
    float* x1      = alloc(4 * M1);
    short* x1b     = (short*)alloc(2 * M1);
    short* hb      = qb4;
    float* mahab   = (float*)kv0;
    float* fb      = (float*)kv0;

    dim3 blk(256);
    // ---- prep
    wdcprep_kernel<<<dim3(3 * M1 / 256), blk, 0, stream>>>(Wdc, wdc_bt);
    wdecprep_kernel<<<dim3(6 * M1 / 256), blk, 0, stream>>>(Wdec, wdec_bt);
    tcsq_kernel<<<dim3(32, 32, 13), blk, 0, stream>>>(Wq, Wk, Wv, Wo, wq4t, wkvt, wot);
    tc_kernel<<<dim3(128, 32), blk, 0, stream>>>(W1, w1t, DD, DF);
    tc_kernel<<<dim3(32, 128), blk, 0, stream>>>(W2, w2t, DF, DD);
    xpad_kernel<<<dim3(2105344 * 2 / 256), blk, 0, stream>>>(x, xpad);
    aux_kernel<<<dim3(1), dim3(64), 0, stream>>>(agg, wagg, out + (size_t)DB * DL * DD);

    // 1. dilated conv + relu
    convdil_mfma_kernel<<<dim3(DD / 128, DB * DL / 128), blk, 0, stream>>>(
        xpad, wdc_bt, bdc, xcb);

    // 2. decomposition convs
    mgemm_kernel<0, 1><<<dim3(DD / 128, (DB * DL / 2) / 128), blk, 0, stream>>>(
        xcb, wdec_bt, nullptr, s1b, DB * DL / 2, DD, 2 * DD);
    mgemm_kernel<0, 1><<<dim3(DD / 128, (DB * DL / 4) / 128), blk, 0, stream>>>(
        s1b, wdec_bt + 2 * M1, nullptr, s2b, DB * DL / 4, DD, 2 * DD);
    mgemm_kernel<0, 1><<<dim3(DD / 128, (DB * DL / 8) / 128), blk, 0, stream>>>(
        s2b, wdec_bt + 4 * M1, nullptr, s3b, DB * DL / 8, DD, 2 * DD);

    // 3a. batched Q projection (all 4 scales, N=4096)
    mgemm_kernel<0, 1><<<dim3(32, 32), blk, 0, stream>>>(
        xcb, wq4t, nullptr, qb4, DB * DL, 4 * DD, DD);

    // 3b. fused K|V projections per scale + fragment-layout preps
    const short* scl[4] = {xcb, s1b, s2b, s3b};
    short* kvs[4] = {kv0, kv1, kv2, kv3};
    short* kfrs[4] = {kfr0, kfr1, kfr2, kfr3};
    short* vfrs[4] = {vfr0, vfr1, vfr2, vfr3};
    for (int s = 0; s < 4; s++) {
        int Ls = DL >> s;
        int rows = DB * Ls;
        mgemm_kernel<0, 1><<<dim3(16, rows / 128), blk, 0, stream>>>(
            scl[s], wkvt + (size_t)s * 2 * M1, nullptr, kvs[s], rows, 2048, DD);
        kfrag_kernel<<<dim3(rows / 2), blk, 0, stream>>>(kvs[s], kfrs[s], Ls, 10 - s);
        vfrag_kernel<<<dim3(Ls / 32, 2, DB * DH), blk, 0, stream>>>(kvs[s], vfrs[s], Ls);
    }

    // 3c. uniform-work fused attention (coalesced fragment loads)
    attn_fused3_kernel<<<dim3(DL / 32, DB * DH), blk, 0, stream>>>(
        qb4, kfr0, kfr1, kfr2, kfr3, vfr0, vfr1, vfr2, vfr3, oparts);

    // 3d. convex aggregation
    combine_kernel<<<dim3(4 * M1 / (256 * 8)), blk, 0, stream>>>(oparts, wagg, attb);

    // 4. shared output projection
    mgemm_kernel<0, 0><<<dim3(DD / 128, (DB * DL) / 128), blk, 0, stream>>>(
        attb, wot, nullptr, mahab, DB * DL, DD, DD);

    // 5. residual + LN1
    addln_kernel<1><<<dim3(DB * DL), blk, 0, stream>>>(x, mahab, g1, be1, x1, x1b);

    // 6. FFN with exact GELU
    mgemm_kernel<1, 1><<<dim3(DF / 128, (DB * DL) / 128), blk, 0, stream>>>(
        x1b, w1t, b1, hb, DB * DL, DF, DD);
    mgemm_kernel<0, 0><<<dim3(DD / 128, (DB * DL) / 128), blk, 0, stream>>>(
        hb, w2t, b2, fb, DB * DL, DD, DF);

    // 7. residual + LN2 -> out
    addln_kernel<0><<<dim3(DB * DL), blk, 0, stream>>>(x1, fb, g2, be2, out, nullptr);
}

// Round 7
// 849.514 us; speedup vs baseline: 5.6282x; 1.1477x over previous
//
#include <hip/hip_runtime.h>
#include <cstddef>

#define DB 4
#define DL 1024
#define DD 1024
#define DH 16
#define DF 4096

typedef __attribute__((ext_vector_type(8))) short short8;
typedef __attribute__((ext_vector_type(4))) float float4v;

static __device__ __forceinline__ short f2bf(float f) {
    unsigned u = __float_as_uint(f);
    unsigned r = (u + 0x7FFFu + ((u >> 16) & 1u)) >> 16;   // RNE
    return (short)r;
}
static __device__ __forceinline__ float bf2f(short s) {
    return __uint_as_float(((unsigned)(unsigned short)s) << 16);
}

#define GLOAD_LDS16(gp, lp)                                                          \
    __builtin_amdgcn_global_load_lds(                                                \
        (const __attribute__((address_space(1))) void*)(gp),                         \
        (__attribute__((address_space(3))) void*)(lp), 16, 0, 0)

// ---------------------------------------------------------------- weight prep
__global__ __launch_bounds__(256) void wdcprep_kernel(const float* __restrict__ W,
                                                      short* __restrict__ Wt) {
    int idx = blockIdx.x * 256 + threadIdx.x;           // 3*D*D
    int i = idx & 1023;
    int o = (idx >> 10) & 1023;
    int k = idx >> 20;
    Wt[idx] = f2bf(W[((size_t)o * 1024 + i) * 3 + k]);
}

__global__ __launch_bounds__(256) void wdecprep_kernel(const float* __restrict__ W,
                                                       short* __restrict__ Wt) {
    int idx = blockIdx.x * 256 + threadIdx.x;           // 3*2*D*D
    int i = idx & 1023;
    int k2 = (idx >> 10) & 1;
    int n = (idx >> 11) & 1023;
    int s = idx >> 21;
    Wt[idx] = f2bf(W[(((size_t)(s * 1024 + n)) * 1024 + i) * 2 + k2]);
}

// generic transpose-cast: in fp32 [K][N] -> out bf16 [N][K]
__global__ __launch_bounds__(256) void tc_kernel(const float* __restrict__ in,
                                                 short* __restrict__ outp, int K, int N) {
    __shared__ float tile[32][33];
    int n0 = blockIdx.x << 5, k0 = blockIdx.y << 5;
    int tid = threadIdx.x;
    int cc = tid & 31, rr = tid >> 5;
#pragma unroll
    for (int p = 0; p < 4; p++) {
        int kk = (p << 3) + rr;
        tile[kk][cc] = in[(size_t)(k0 + kk) * N + n0 + cc];
    }
    __syncthreads();
#pragma unroll
    for (int p = 0; p < 4; p++) {
        int nn = (p << 3) + rr;
        outp[(size_t)(n0 + nn) * K + k0 + cc] = f2bf(tile[cc][nn]);
    }
}

// batched square (1024x1024) transpose-casts, z selects the weight
__global__ __launch_bounds__(256) void tcsq_kernel(
    const float* __restrict__ Wq, const float* __restrict__ Wk,
    const float* __restrict__ Wv, const float* __restrict__ Wo,
    short* __restrict__ wq4t, short* __restrict__ wkvt, short* __restrict__ wot) {
    const size_t M1 = 1024 * 1024;
    int z = blockIdx.z;
    const float* src;
    short* dst;
    if (z < 4)      { src = Wq + (size_t)z * M1;       dst = wq4t + (size_t)z * M1; }
    else if (z < 8) { src = Wk + (size_t)(z - 4) * M1; dst = wkvt + (size_t)(z - 4) * 2 * M1; }
    else if (z < 12){ src = Wv;                        dst = wkvt + (size_t)(z - 8) * 2 * M1 + M1; }
    else            { src = Wo;                        dst = wot; }
    __shared__ float tile[32][33];
    int n0 = blockIdx.x << 5, k0 = blockIdx.y << 5;
    int tid = threadIdx.x;
    int cc = tid & 31, rr = tid >> 5;
#pragma unroll
    for (int p = 0; p < 4; p++) {
        int kk = (p << 3) + rr;
        tile[kk][cc] = src[(size_t)(k0 + kk) * DD + n0 + cc];
    }
    __syncthreads();
#pragma unroll
    for (int p = 0; p < 4; p++) {
        int nn = (p << 3) + rr;
        dst[(size_t)(n0 + nn) * DD + k0 + cc] = f2bf(tile[cc][nn]);
    }
}

// zero-padded bf16 x: xpad[b][l+2][d] = bf16(x[b][l][d]), rows 0,1,L+2,L+3 = 0
__global__ __launch_bounds__(256) void xpad_kernel(const float* __restrict__ x,
                                                   short* __restrict__ xp) {
    int idx = blockIdx.x * 256 + threadIdx.x;           // 4*1028*1024
    int d = idx & 1023;
    int row = (idx >> 10) % 1028;
    int b = (idx >> 10) / 1028;
    int l = row - 2;
    float v = (l >= 0 && l < DL) ? x[((size_t)(b * DL + l)) * DD + d] : 0.f;
    xp[idx] = f2bf(v);
}

// softmax of agg_logits (S=4) + entropy aux loss
__global__ void aux_kernel(const float* __restrict__ logits,
                           float* __restrict__ w, float* __restrict__ aux) {
    if (threadIdx.x == 0 && blockIdx.x == 0) {
        float l0 = logits[0], l1 = logits[1], l2 = logits[2], l3 = logits[3];
        float m = fmaxf(fmaxf(l0, l1), fmaxf(l2, l3));
        float e0 = __expf(l0 - m), e1 = __expf(l1 - m);
        float e2 = __expf(l2 - m), e3 = __expf(l3 - m);
        float s = e0 + e1 + e2 + e3;
        float w0 = e0 / s, w1 = e1 / s, w2 = e2 / s, w3 = e3 / s;
        w[0] = w0; w[1] = w1; w[2] = w2; w[3] = w3;
        *aux = -(w0 * logf(w0 + 1e-9f) + w1 * logf(w1 + 1e-9f) +
                 w2 * logf(w2 + 1e-9f) + w3 * logf(w3 + 1e-9f));
    }
}

// ---------------------------------------------------------------- MFMA GEMM
// C[M,N] = act(A[M,K] @ B[K,N] + bias), A bf16 [M][K], Bt bf16 [N][K].
// 128x128 tile, BK=32, 4 waves -> 64x64 each. ACT: 0 none, 1 GELU. OBF: bf16 out.
template <int ACT, int OBF>
__global__ __launch_bounds__(256) void mgemm_kernel(
    const short* __restrict__ A, const short* __restrict__ Bt,
    const float* __restrict__ bias, void* __restrict__ Cv,
    int M, int N, int K) {
    __shared__ short As[128 * 32];
    __shared__ short Bs[128 * 32];
    int tid = threadIdx.x;
    int wave = tid >> 6, lane = tid & 63;
    int lq = lane & 15, quad = lane >> 4;
    int m0 = blockIdx.y << 7, n0 = blockIdx.x << 7;
    int wm = (wave & 1) << 6, wn = (wave >> 1) << 6;
    int r0 = tid >> 2, r1 = (256 + tid) >> 2;
    int kc0 = (tid & 3) << 3;
    const short* Ag0 = A + (size_t)(m0 + r0) * K + kc0;
    const short* Ag1 = A + (size_t)(m0 + r1) * K + kc0;
    const short* Bg0 = Bt + (size_t)(n0 + r0) * K + kc0;
    const short* Bg1 = Bt + (size_t)(n0 + r1) * K + kc0;
    float4v acc[4][4];
#pragma unroll
    for (int mi = 0; mi < 4; mi++)
#pragma unroll
        for (int ni = 0; ni < 4; ni++) acc[mi][ni] = (float4v){0.f, 0.f, 0.f, 0.f};

    for (int k0 = 0; k0 < K; k0 += 32) {
        __syncthreads();
        GLOAD_LDS16(Ag0 + k0, As + tid * 8);
        GLOAD_LDS16(Ag1 + k0, As + (256 + tid) * 8);
        GLOAD_LDS16(Bg0 + k0, Bs + tid * 8);
        GLOAD_LDS16(Bg1 + k0, Bs + (256 + tid) * 8);
        __syncthreads();
        short8 af[4], bfr[4];
#pragma unroll
        for (int mi = 0; mi < 4; mi++)
            af[mi] = *(const short8*)(As + ((wm + (mi << 4) + lq) << 5) + (quad << 3));
#pragma unroll
        for (int ni = 0; ni < 4; ni++)
            bfr[ni] = *(const short8*)(Bs + ((wn + (ni << 4) + lq) << 5) + (quad << 3));
#pragma unroll
        for (int mi = 0; mi < 4; mi++)
#pragma unroll
            for (int ni = 0; ni < 4; ni++)
                acc[mi][ni] = __builtin_amdgcn_mfma_f32_16x16x32_bf16(
                    af[mi], bfr[ni], acc[mi][ni], 0, 0, 0);
    }
#pragma unroll
    for (int ni = 0; ni < 4; ni++) {
        int col = n0 + wn + (ni << 4) + lq;
        float bv = bias ? bias[col] : 0.f;
#pragma unroll
        for (int mi = 0; mi < 4; mi++) {
#pragma unroll
            for (int r = 0; r < 4; r++) {
                int row = m0 + wm + (mi << 4) + (quad << 2) + r;
                float v = acc[mi][ni][r] + bv;
                if (ACT == 1) v = 0.5f * v * (1.0f + erff(v * 0.70710678118654752f));
                if (OBF) ((short*)Cv)[(size_t)row * N + col] = f2bf(v);
                else ((float*)Cv)[(size_t)row * N + col] = v;
            }
        }
    }
}

// ---------------------------------------------------------------- grouped KV GEMM
// One dispatch for all 4 scales' K|V projections. acts rows: s0 [0,4096),
// s1 [4096,6144), s2 [6144,7168), s3 [7168,7680). N=2048, K=1024 for all;
// per-scale weight slab selected from m-tile index. Out bf16 kvall[row][2048].
__global__ __launch_bounds__(256) void kvgemm_kernel(
    const short* __restrict__ acts, const short* __restrict__ wkvt,
    short* __restrict__ kvall) {
    __shared__ short As[128 * 32];
    __shared__ short Bs[128 * 32];
    int my = blockIdx.y;                       // 0..59
    int s = my < 32 ? 0 : my < 48 ? 1 : my < 56 ? 2 : 3;
    int m0 = my << 7;
    const short* Bt = wkvt + (size_t)s * 2097152;
    const int K = 1024, N = 2048;
    int tid = threadIdx.x;
    int wave = tid >> 6, lane = tid & 63;
    int lq = lane & 15, quad = lane >> 4;
    int n0 = blockIdx.x << 7;
    int wm = (wave & 1) << 6, wn = (wave >> 1) << 6;
    int r0 = tid >> 2, r1 = (256 + tid) >> 2;
    int kc0 = (tid & 3) << 3;
    const short* Ag0 = acts + (size_t)(m0 + r0) * K + kc0;
    const short* Ag1 = acts + (size_t)(m0 + r1) * K + kc0;
    const short* Bg0 = Bt + (size_t)(n0 + r0) * K + kc0;
    const short* Bg1 = Bt + (size_t)(n0 + r1) * K + kc0;
    float4v acc[4][4];
#pragma unroll
    for (int mi = 0; mi < 4; mi++)
#pragma unroll
        for (int ni = 0; ni < 4; ni++) acc[mi][ni] = (float4v){0.f, 0.f, 0.f, 0.f};
    for (int k0 = 0; k0 < K; k0 += 32) {
        __syncthreads();
        GLOAD_LDS16(Ag0 + k0, As + tid * 8);
        GLOAD_LDS16(Ag1 + k0, As + (256 + tid) * 8);
        GLOAD_LDS16(Bg0 + k0, Bs + tid * 8);
        GLOAD_LDS16(Bg1 + k0, Bs + (256 + tid) * 8);
        __syncthreads();
        short8 af[4], bfr[4];
#pragma unroll
        for (int mi = 0; mi < 4; mi++)
            af[mi] = *(const short8*)(As + ((wm + (mi << 4) + lq) << 5) + (quad << 3));
#pragma unroll
        for (int ni = 0; ni < 4; ni++)
            bfr[ni] = *(const short8*)(Bs + ((wn + (ni << 4) + lq) << 5) + (quad << 3));
#pragma unroll
        for (int mi = 0; mi < 4; mi++)
#pragma unroll
            for (int ni = 0; ni < 4; ni++)
                acc[mi][ni] = __builtin_amdgcn_mfma_f32_16x16x32_bf16(
                    af[mi], bfr[ni], acc[mi][ni], 0, 0, 0);
    }
#pragma unroll
    for (int ni = 0; ni < 4; ni++) {
        int col = n0 + wn + (ni << 4) + lq;
#pragma unroll
        for (int mi = 0; mi < 4; mi++)
#pragma unroll
            for (int r = 0; r < 4; r++) {
                int row = m0 + wm + (mi << 4) + (quad << 2) + r;
                kvall[(size_t)row * N + col] = f2bf(acc[mi][ni][r]);
            }
    }
}

// ---------------------------------------------------------------- split-K GEMM
// Partial-K GEMM: blockIdx.z selects K-half; fp32 partial outputs to
// Cout + z*M*N. Bias added by z==0 only. Downstream addln3 sums partials.
__global__ __launch_bounds__(256) void mgemm_pk_kernel(
    const short* __restrict__ A, const short* __restrict__ Bt,
    const float* __restrict__ bias, float* __restrict__ Cout,
    int M, int N, int Kfull, int KH) {
    __shared__ short As[128 * 32];
    __shared__ short Bs[128 * 32];
    int kz = blockIdx.z;
    const short* Ab = A + (size_t)kz * KH;
    const short* Btb = Bt + (size_t)kz * KH;
    float* Co = Cout + (size_t)kz * M * N;
    int tid = threadIdx.x;
    int wave = tid >> 6, lane = tid & 63;
    int lq = lane & 15, quad = lane >> 4;
    int m0 = blockIdx.y << 7, n0 = blockIdx.x << 7;
    int wm = (wave & 1) << 6, wn = (wave >> 1) << 6;
    int r0 = tid >> 2, r1 = (256 + tid) >> 2;
    int kc0 = (tid & 3) << 3;
    const short* Ag0 = Ab + (size_t)(m0 + r0) * Kfull + kc0;
    const short* Ag1 = Ab + (size_t)(m0 + r1) * Kfull + kc0;
    const short* Bg0 = Btb + (size_t)(n0 + r0) * Kfull + kc0;
    const short* Bg1 = Btb + (size_t)(n0 + r1) * Kfull + kc0;
    float4v acc[4][4];
#pragma unroll
    for (int mi = 0; mi < 4; mi++)
#pragma unroll
        for (int ni = 0; ni < 4; ni++) acc[mi][ni] = (float4v){0.f, 0.f, 0.f, 0.f};
    for (int k0 = 0; k0 < KH; k0 += 32) {
        __syncthreads();
        GLOAD_LDS16(Ag0 + k0, As + tid * 8);
        GLOAD_LDS16(Ag1 + k0, As + (256 + tid) * 8);
        GLOAD_LDS16(Bg0 + k0, Bs + tid * 8);
        GLOAD_LDS16(Bg1 + k0, Bs + (256 + tid) * 8);
        __syncthreads();
        short8 af[4], bfr[4];
#pragma unroll
        for (int mi = 0; mi < 4; mi++)
            af[mi] = *(const short8*)(As + ((wm + (mi << 4) + lq) << 5) + (quad << 3));
#pragma unroll
        for (int ni = 0; ni < 4; ni++)
            bfr[ni] = *(const short8*)(Bs + ((wn + (ni << 4) + lq) << 5) + (quad << 3));
#pragma unroll
        for (int mi = 0; mi < 4; mi++)
#pragma unroll
            for (int ni = 0; ni < 4; ni++)
                acc[mi][ni] = __builtin_amdgcn_mfma_f32_16x16x32_bf16(
                    af[mi], bfr[ni], acc[mi][ni], 0, 0, 0);
    }
#pragma unroll
    for (int ni = 0; ni < 4; ni++) {
        int col = n0 + wn + (ni << 4) + lq;
        float bv = (bias && kz == 0) ? bias[col] : 0.f;
#pragma unroll
        for (int mi = 0; mi < 4; mi++)
#pragma unroll
            for (int r = 0; r < 4; r++) {
                int row = m0 + wm + (mi << 4) + (quad << 2) + r;
                Co[(size_t)row * N + col] = acc[mi][ni][r] + bv;
            }
    }
}

// ---------------------------------------------------------------- conv MFMA
__global__ __launch_bounds__(256) void convdil_mfma_kernel(
    const short* __restrict__ xp, const short* __restrict__ Wt,
    const float* __restrict__ bvec, short* __restrict__ outp) {
    __shared__ short As[128 * 32];
    __shared__ short Bs[128 * 32];
    int tid = threadIdx.x;
    int wave = tid >> 6, lane = tid & 63;
    int lq = lane & 15, quad = lane >> 4;
    int m0 = blockIdx.y << 7, n0 = blockIdx.x << 7;
    int wm = (wave & 1) << 6, wn = (wave >> 1) << 6;
    int b = m0 >> 10, ll0 = m0 & 1023;
    int r0 = tid >> 2, r1 = (256 + tid) >> 2;
    int kc = (tid & 3) << 3;
    float4v acc[4][4];
#pragma unroll
    for (int mi = 0; mi < 4; mi++)
#pragma unroll
        for (int ni = 0; ni < 4; ni++) acc[mi][ni] = (float4v){0.f, 0.f, 0.f, 0.f};

    for (int kp = 0; kp < 3; kp++) {
        const short* Abase = xp + ((size_t)(b * 1028 + ll0 + 2 * kp)) * DD + kc;
        const short* Bbase = Wt + (size_t)kp * DD * DD;
        const short* Bg0 = Bbase + (size_t)(n0 + r0) * DD + kc;
        const short* Bg1 = Bbase + (size_t)(n0 + r1) * DD + kc;
        for (int k0 = 0; k0 < DD; k0 += 32) {
            __syncthreads();
            GLOAD_LDS16(Abase + (size_t)r0 * DD + k0, As + tid * 8);
            GLOAD_LDS16(Abase + (size_t)r1 * DD + k0, As + (256 + tid) * 8);
            GLOAD_LDS16(Bg0 + k0, Bs + tid * 8);
            GLOAD_LDS16(Bg1 + k0, Bs + (256 + tid) * 8);
            __syncthreads();
            short8 af[4], bfr[4];
#pragma unroll
            for (int mi = 0; mi < 4; mi++)
                af[mi] = *(const short8*)(As + ((wm + (mi << 4) + lq) << 5) + (quad << 3));
#pragma unroll
            for (int ni = 0; ni < 4; ni++)
                bfr[ni] = *(const short8*)(Bs + ((wn + (ni << 4) + lq) << 5) + (quad << 3));
#pragma unroll
            for (int mi = 0; mi < 4; mi++)
#pragma unroll
                for (int ni = 0; ni < 4; ni++)
                    acc[mi][ni] = __builtin_amdgcn_mfma_f32_16x16x32_bf16(
                        af[mi], bfr[ni], acc[mi][ni], 0, 0, 0);
        }
    }
#pragma unroll
    for (int ni = 0; ni < 4; ni++) {
        int col = n0 + wn + (ni << 4) + lq;
        float bv = bvec[col];
#pragma unroll
        for (int mi = 0; mi < 4; mi++)
#pragma unroll
            for (int r = 0; r < 4; r++) {
                int row = m0 + wm + (mi << 4) + (quad << 2) + r;
                float v = fmaxf(acc[mi][ni][r] + bv, 0.f);
                outp[(size_t)row * DD + col] = f2bf(v);
            }
    }
}

// ---------------------------------------------------------------- K fragment prep (all scales)
// kfr[s][bh][g][dc][lq][8] <- kvall K-part; one dispatch, scale from flat idx.
__global__ __launch_bounds__(256) void kfrag_all_kernel(const short* __restrict__ kvall,
                                                        short* __restrict__ kfr0) {
    int idx = blockIdx.x * 256 + threadIdx.x;       // 0..983039
    int s, base, rb;
    size_t doff;
    if (idx < 524288)      { s = 0; base = 0;      rb = 0;    doff = 0; }
    else if (idx < 786432) { s = 1; base = 524288; rb = 4096; doff = 4194304; }
    else if (idx < 917504) { s = 2; base = 786432; rb = 6144; doff = 6291456; }
    else                   { s = 3; base = 917504; rb = 7168; doff = 7340032; }
    int t = idx - base;
    int rem = t & 127;
    int h = rem >> 3, dc = rem & 7;
    int jg = t >> 7;
    int Ls = DL >> s;
    int b = jg >> (10 - s);
    int j = jg & (Ls - 1);
    short8 v = *(const short8*)(kvall + ((size_t)(rb + jg) << 11) + (h << 6) + (dc << 3));
    int bh = (b << 4) | h;
    int g = j >> 4, lq = j & 15;
    *(short8*)(kfr0 + doff + (((size_t)bh * (Ls >> 4) + g) << 10) + (dc << 7) + (lq << 3)) = v;
}

// ---------------------------------------------------------------- V fragment prep (all scales)
// vfr[s][bh][c][ks][t][lq][32] <- kvall V-part via LDS transpose; one dispatch.
__global__ __launch_bounds__(256) void vfrag_all_kernel(const short* __restrict__ kvall,
                                                        short* __restrict__ vfr0) {
    __shared__ short tile[32][33];
    int flat = blockIdx.x;                          // 0..7679
    int s, base, rb;
    size_t doff;
    if (flat < 4096)      { s = 0; base = 0;    rb = 0;    doff = 0; }
    else if (flat < 6144) { s = 1; base = 4096; rb = 4096; doff = 4194304; }
    else if (flat < 7168) { s = 2; base = 6144; rb = 6144; doff = 6291456; }
    else                  { s = 3; base = 7168; rb = 7168; doff = 7340032; }
    int rem = flat - base;
    int Ls = DL >> s;
    int nt = Ls >> 5;
    int j0t = rem & (nt - 1);
    int rest = rem >> (5 - s);
    int dt = rest & 1;
    int bh = rest >> 1;
    int j0 = j0t << 5, d0 = dt << 5;
    int b = bh >> 4, h = bh & 15;
    int tid = threadIdx.x;
    int cc = tid & 31, rr = tid >> 5;
#pragma unroll
    for (int p = 0; p < 4; p++) {
        int jj = (p << 3) + rr;
        tile[jj][cc] = kvall[((size_t)(rb + b * Ls + j0 + jj) << 11) + 1024 +
                             (h << 6) + d0 + cc];
    }
    __syncthreads();
    int c = j0 >> 6, ks = (j0 >> 5) & 1;
#pragma unroll
    for (int p = 0; p < 4; p++) {
        int d = d0 + (p << 3) + rr;
        int tt = d >> 4, lqv = d & 15;
        size_t off = doff + (((size_t)bh * (Ls >> 6) + c) << 12) + (ks << 11) +
                     (tt << 9) + (lqv << 5) + cc;
        vfr0[off] = tile[cc][(p << 3) + rr];
    }
}

// ---------------------------------------------------------------- attention
// Barrier-free flash attention. Block = 64 q-rows x one (b,h); 4 independent
// waves, each sweeping ALL 4 scales over its 16 q-rows (30 chunks, uniform).
// Fixed-max softmax + deferred denominator; convex aggregation folded
// in-register; single bf16 write to attb. Zero __syncthreads.
__global__ __launch_bounds__(256) void attn_fused4_kernel(
    const short* __restrict__ qb4, const short* __restrict__ kfr0,
    const short* __restrict__ vfr0, const float* __restrict__ wagg,
    short* __restrict__ attb) {
    __shared__ __align__(16) short plds[4][16][72];
    int tid = threadIdx.x;
    int w = tid >> 6, lane = tid & 63;
    int lq = lane & 15, quad = lane >> 4;
    int bh = blockIdx.y;
    int b = bh >> 4, h = bh & 15;
    int qrow0 = b * DL + (blockIdx.x << 6) + (w << 4);
    const float c_exp = 0.18033688f;    // log2(e)/8

    float fin[4][4];
#pragma unroll
    for (int t = 0; t < 4; t++)
#pragma unroll
        for (int r = 0; r < 4; r++) fin[t][r] = 0.f;

#pragma unroll 1
    for (int s = 0; s < 4; s++) {
        int Ls = DL >> s;
        size_t doff = s == 0 ? 0 : s == 1 ? 4194304 : s == 2 ? 6291456 : 7340032;

        const short* qbase = qb4 + ((size_t)(qrow0 + lq) << 12) + (s << 10) +
                             (h << 6) + (quad << 3);
        short8 qf0 = *(const short8*)qbase;
        short8 qf1 = *(const short8*)(qbase + 32);

        const short* kfb = kfr0 + doff + (((size_t)bh * (Ls >> 4)) << 10) +
                           (quad << 7) + (lq << 3);
        const short* vfb = vfr0 + doff + (((size_t)bh * (Ls >> 6)) << 12) +
                           (lq << 5) + (quad << 3);

        float4v O[4];
        float lpart[4] = {0.f, 0.f, 0.f, 0.f};
#pragma unroll
        for (int t = 0; t < 4; t++) O[t] = (float4v){0.f, 0.f, 0.f, 0.f};

        for (int c0 = 0; c0 < Ls; c0 += 64) {
            float4v S[4];
            int g0 = c0 >> 4;
#pragma unroll
            for (int t = 0; t < 4; t++) {
                const short* kp = kfb + ((size_t)(g0 + t) << 10);
                short8 kf0 = *(const short8*)kp;
                short8 kf1 = *(const short8*)(kp + 512);
                float4v z = (float4v){0.f, 0.f, 0.f, 0.f};
                z = __builtin_amdgcn_mfma_f32_16x16x32_bf16(qf0, kf0, z, 0, 0, 0);
                S[t] = __builtin_amdgcn_mfma_f32_16x16x32_bf16(qf1, kf1, z, 0, 0, 0);
            }
#pragma unroll
            for (int t = 0; t < 4; t++)
#pragma unroll
                for (int r = 0; r < 4; r++) {
                    float p = exp2f(S[t][r] * c_exp);
                    lpart[r] += p;
                    plds[w][(quad << 2) + r][(t << 4) + lq] =
                        (short)(__float_as_uint(p) >> 16);   // trunc-bf16
                }
            const short* vcb = vfb + ((size_t)(c0 >> 6) << 12);
#pragma unroll
            for (int ks = 0; ks < 2; ks++) {
                short8 af = *(const short8*)&plds[w][lq][(ks << 5) + (quad << 3)];
#pragma unroll
                for (int t = 0; t < 4; t++) {
                    short8 vf = *(const short8*)(vcb + (ks << 11) + (t << 9));
                    O[t] = __builtin_amdgcn_mfma_f32_16x16x32_bf16(af, vf, O[t], 0, 0, 0);
                }
            }
        }
        // per-scale: reduce denominator, fold convex weight into accumulator
        float wsc = wagg[s];
#pragma unroll
        for (int r = 0; r < 4; r++) {
            float l = lpart[r];
            l += __shfl_xor(l, 1, 64);
            l += __shfl_xor(l, 2, 64);
            l += __shfl_xor(l, 4, 64);
            l += __shfl_xor(l, 8, 64);
            float linv = wsc / l;
#pragma unroll
            for (int t = 0; t < 4; t++) fin[t][r] += O[t][r] * linv;
        }
    }
#pragma unroll
    for (int r = 0; r < 4; r++) {
        size_t rbase = ((size_t)(qrow0 + (quad << 2) + r) << 10) + (h << 6) + lq;
#pragma unroll
        for (int t = 0; t < 4; t++)
            attb[rbase + (t << 4)] = f2bf(fin[t][r]);
    }
}

// ---------------------------------------------------------------- add3 + LN
// out = LN(a + b0 + b1); OBF: also write bf16 copy.
template <int OBF>
__global__ __launch_bounds__(256) void addln3_kernel(
    const float* __restrict__ a, const float* __restrict__ b0,
    const float* __restrict__ b1, const float* __restrict__ gam,
    const float* __restrict__ bet, float* __restrict__ out,
    short* __restrict__ outb) {
    __shared__ float redA[4], redB[4];
    int row = blockIdx.x, tid = threadIdx.x;
    size_t base = (size_t)row * DD + (tid << 2);
    float4 av = *(const float4*)&a[base];
    float4 bv = *(const float4*)&b0[base];
    float4 cv = *(const float4*)&b1[base];
    float s0 = av.x + bv.x + cv.x, s1 = av.y + bv.y + cv.y;
    float s2 = av.z + bv.z + cv.z, s3 = av.w + bv.w + cv.w;
    float lsum = s0 + s1 + s2 + s3;
    float lsq = s0 * s0 + s1 * s1 + s2 * s2 + s3 * s3;
#pragma unroll
    for (int o = 32; o > 0; o >>= 1) {
        lsum += __shfl_down(lsum, o, 64);
        lsq += __shfl_down(lsq, o, 64);
    }
    int lane = tid & 63, wid = tid >> 6;
    if (lane == 0) { redA[wid] = lsum; redB[wid] = lsq; }
    __syncthreads();
    float tsum = redA[0] + redA[1] + redA[2] + redA[3];
    float tsq = redB[0] + redB[1] + redB[2] + redB[3];
    float mean = tsum * (1.0f / DD);
    float var = tsq * (1.0f / DD) - mean * mean;
    float rstd = rsqrtf(var + 1e-5f);
    float4 gv = *(const float4*)&gam[tid << 2];
    float4 bev = *(const float4*)&bet[tid << 2];
    float4 o;
    o.x = (s0 - mean) * rstd * gv.x + bev.x;
    o.y = (s1 - mean) * rstd * gv.y + bev.y;
    o.z = (s2 - mean) * rstd * gv.z + bev.z;
    o.w = (s3 - mean) * rstd * gv.w + bev.w;
    *(float4*)&out[base] = o;
    if (OBF) {
        ushort4 u;
        u.x = (unsigned short)f2bf(o.x);
        u.y = (unsigned short)f2bf(o.y);
        u.z = (unsigned short)f2bf(o.z);
        u.w = (unsigned short)f2bf(o.w);
        *(ushort4*)&outb[base] = u;
    }
}

// ---------------------------------------------------------------- launcher
extern "C" void kernel_launch(void* const* d_in, const int* in_sizes, int n_in,
                              void* d_out, int out_size, void* d_ws, size_t ws_size,
                              hipStream_t stream) {
    (void)in_sizes; (void)n_in; (void)out_size; (void)ws_size;
    const float* x   = (const float*)d_in[0];
    const float* Wdc = (const float*)d_in[1];
    const float* bdc = (const float*)d_in[2];
    const float* Wdec= (const float*)d_in[3];
    const float* Wq  = (const float*)d_in[4];
    const float* Wk  = (const float*)d_in[5];
    const float* Wv  = (const float*)d_in[6];
    const float* Wo  = (const float*)d_in[7];
    const float* agg = (const float*)d_in[8];
    const float* g1  = (const float*)d_in[9];
    const float* be1 = (const float*)d_in[10];
    const float* g2  = (const float*)d_in[11];
    const float* be2 = (const float*)d_in[12];
    const float* W1  = (const float*)d_in[13];
    const float* b1  = (const float*)d_in[14];
    const float* W2  = (const float*)d_in[15];
    const float* b2  = (const float*)d_in[16];
    float* out = (float*)d_out;

    float* ws = (float*)d_ws;
    size_t off = 0;
    auto alloc = [&](size_t nfloats) { float* p = ws + off; off += nfloats; return p; };
    const size_t M1 = 1024 * 1024;
    short* wdc_bt  = (short*)alloc(3 * M1 / 2);
    short* wdec_bt = (short*)alloc(3 * M1);
    short* wq4t    = (short*)alloc(2 * M1);
    short* wkvt    = (short*)alloc(4 * M1);
    short* wot     = (short*)alloc(M1 / 2);
    short* w1t     = (short*)alloc(2 * M1);
    short* w2t     = (short*)alloc(2 * M1);
    float* wagg    = alloc(64);
    short* xpad    = (short*)alloc(2105344);
    // activation buffers: MUST stay contiguous (grouped KV GEMM reads rows 0..7679)
    short* xcb     = (short*)alloc(2 * M1);         // rows [0,4096)
    short* s1b     = (short*)alloc(M1);             // rows [4096,6144)
    short* s2b     = (short*)alloc(M1 / 2);         // rows [6144,7168)
    short* s3b     = (short*)alloc(M1 / 4);         // rows [7168,7680)
    short* qb4     = (short*)alloc(8 * M1);         // later FFN hidden
    short* kvall   = (short*)alloc(7 * M1 + M1 / 2);// 7680 rows x 2048 bf16
    short* kfrall  = (short*)alloc(3 * M1 + 3 * M1 / 4);  // 7.5M shorts
    short* vfrall  = (short*)alloc(3 * M1 + 3 * M1 / 4);
    short* attb    = (short*)alloc(2 * M1);
    float* x1      = alloc(4 * M1);
    short* x1b     = (short*)alloc(2 * M1);
    float* pkbuf   = alloc(8 * M1);                 // split-K partials (2 x 4M fp32)
    short* hb      = qb4;                           // FFN hidden [4096][4096] bf16

    dim3 blk(256);
    // ---- prep
    wdcprep_kernel<<<dim3(3 * M1 / 256), blk, 0, stream>>>(Wdc, wdc_bt);
    wdecprep_kernel<<<dim3(6 * M1 / 256), blk, 0, stream>>>(Wdec, wdec_bt);
    tcsq_kernel<<<dim3(32, 32, 13), blk, 0, stream>>>(Wq, Wk, Wv, Wo, wq4t, wkvt, wot);
    tc_kernel<<<dim3(128, 32), blk, 0, stream>>>(W1, w1t, DD, DF);
    tc_kernel<<<dim3(32, 128), blk, 0, stream>>>(W2, w2t, DF, DD);
    xpad_kernel<<<dim3(2105344 * 2 / 256), blk, 0, stream>>>(x, xpad);
    aux_kernel<<<dim3(1), dim3(64), 0, stream>>>(agg, wagg, out + (size_t)DB * DL * DD);

    // 1. dilated conv + relu
    convdil_mfma_kernel<<<dim3(DD / 128, DB * DL / 128), blk, 0, stream>>>(
        xpad, wdc_bt, bdc, xcb);

    // 2. decomposition convs (sequential data dependence)
    mgemm_kernel<0, 1><<<dim3(DD / 128, (DB * DL / 2) / 128), blk, 0, stream>>>(
        xcb, wdec_bt, nullptr, s1b, DB * DL / 2, DD, 2 * DD);
    mgemm_kernel<0, 1><<<dim3(DD / 128, (DB * DL / 4) / 128), blk, 0, stream>>>(
        s1b, wdec_bt + 2 * M1, nullptr, s2b, DB * DL / 4, DD, 2 * DD);
    mgemm_kernel<0, 1><<<dim3(DD / 128, (DB * DL / 8) / 128), blk, 0, stream>>>(
        s2b, wdec_bt + 4 * M1, nullptr, s3b, DB * DL / 8, DD, 2 * DD);

    // 3a. batched Q projection (all 4 scales, N=4096)
    mgemm_kernel<0, 1><<<dim3(32, 32), blk, 0, stream>>>(
        xcb, wq4t, nullptr, qb4, DB * DL, 4 * DD, DD);

    // 3b. grouped K|V projection: ONE dispatch, all scales (960 blocks)
    kvgemm_kernel<<<dim3(16, 60), blk, 0, stream>>>(xcb, wkvt, kvall);

    // 3c. fragment-layout preps (one dispatch each)
    kfrag_all_kernel<<<dim3(3840), blk, 0, stream>>>(kvall, kfrall);
    vfrag_all_kernel<<<dim3(7680), blk, 0, stream>>>(kvall, vfrall);

    // 3d. barrier-free fused attention + in-register convex aggregation
    attn_fused4_kernel<<<dim3(DL / 64, DB * DH), blk, 0, stream>>>(
        qb4, kfrall, vfrall, wagg, attb);

    // 4. shared output projection (split-K x2 -> fp32 partials)
    mgemm_pk_kernel<<<dim3(8, 32, 2), blk, 0, stream>>>(
        attb, wot, nullptr, pkbuf, DB * DL, DD, DD, DD / 2);

    // 5. residual + LN1 (3-input)
    addln3_kernel<1><<<dim3(DB * DL), blk, 0, stream>>>(
        x, pkbuf, pkbuf + 4 * M1, g1, be1, x1, x1b);

    // 6. FFN: GELU GEMM then split-K x2 down-projection
    mgemm_kernel<1, 1><<<dim3(DF / 128, (DB * DL) / 128), blk, 0, stream>>>(
        x1b, w1t, b1, hb, DB * DL, DF, DD);
    mgemm_pk_kernel<<<dim3(8, 32, 2), blk, 0, stream>>>(
        hb, w2t, b2, pkbuf, DB * DL, DD, DF, DF / 2);

    // 7. residual + LN2 -> out (3-input)
    addln3_kernel<0><<<dim3(DB * DL), blk, 0, stream>>>(
        x1, pkbuf, pkbuf + 4 * M1, g2, be2, out, nullptr);
}

// Round 8
// 840.322 us; speedup vs baseline: 5.6898x; 1.0109x over previous
//
#include <hip/hip_runtime.h>
#include <cstddef>

#define DB 4
#define DL 1024
#define DD 1024
#define DH 16
#define DF 4096

typedef __attribute__((ext_vector_type(8))) short short8;
typedef __attribute__((ext_vector_type(4))) float float4v;

static __device__ __forceinline__ short f2bf(float f) {
    unsigned u = __float_as_uint(f);
    unsigned r = (u + 0x7FFFu + ((u >> 16) & 1u)) >> 16;   // RNE
    return (short)r;
}

#define GLOAD_LDS16(gp, lp)                                                          \
    __builtin_amdgcn_global_load_lds(                                                \
        (const __attribute__((address_space(1))) void*)(gp),                         \
        (__attribute__((address_space(3))) void*)(lp), 16, 0, 0)

// ---------------------------------------------------------------- mega-prep
// One dispatch for every independent prep op, decoded from blockIdx.x:
//   [0,12288)      wdc_bt[k][o][i]   = bf16(W_dc[(o*D+i)*3+k])
//   [12288,36864)  wdec_bt[s][n][k2*D+i] = bf16(W_dec[((s*D+n)*D+i)*2+k2])
//   [36864,50176)  13x square 1024^2 transpose-casts (Wq x4, Wk x4, Wv x4, Wo)
//   [50176,54272)  W1 -> w1t  (K=1024,N=4096)
//   [54272,58368)  W2 -> w2t  (K=4096,N=1024)
//   [58368,74816)  xpad (zero-padded bf16 x)
//   74816          agg softmax + entropy aux
__global__ __launch_bounds__(256) void prep_all_kernel(
    const float* __restrict__ Wdc, const float* __restrict__ Wdec,
    const float* __restrict__ Wq, const float* __restrict__ Wk,
    const float* __restrict__ Wv, const float* __restrict__ Wo,
    const float* __restrict__ W1, const float* __restrict__ W2,
    const float* __restrict__ x, const float* __restrict__ agg,
    short* __restrict__ wdc_bt, short* __restrict__ wdec_bt,
    short* __restrict__ wq4t, short* __restrict__ wkvt, short* __restrict__ wot,
    short* __restrict__ w1t, short* __restrict__ w2t, short* __restrict__ xpad,
    float* __restrict__ wagg, float* __restrict__ aux) {
    __shared__ float tile[32][33];
    const size_t M1 = 1024 * 1024;
    int blk = blockIdx.x, tid = threadIdx.x;
    if (blk < 12288) {
        int idx = blk * 256 + tid;
        int i = idx & 1023, o = (idx >> 10) & 1023, k = idx >> 20;
        wdc_bt[idx] = f2bf(Wdc[((size_t)o * 1024 + i) * 3 + k]);
        return;
    }
    if (blk < 36864) {
        int idx = (blk - 12288) * 256 + tid;
        int i = idx & 1023, k2 = (idx >> 10) & 1, n = (idx >> 11) & 1023, s = idx >> 21;
        wdec_bt[idx] = f2bf(Wdec[(((size_t)(s * 1024 + n)) * 1024 + i) * 2 + k2]);
        return;
    }
    if (blk < 58368) {
        const float* src; short* dst; int K, N, bx, by;
        if (blk < 50176) {
            int r = blk - 36864;
            int z = r >> 10, rem = r & 1023;
            bx = rem & 31; by = rem >> 5; K = 1024; N = 1024;
            if (z < 4)      { src = Wq + (size_t)z * M1;       dst = wq4t + (size_t)z * M1; }
            else if (z < 8) { src = Wk + (size_t)(z - 4) * M1; dst = wkvt + (size_t)(z - 4) * 2 * M1; }
            else if (z < 12){ src = Wv;                        dst = wkvt + (size_t)(z - 8) * 2 * M1 + M1; }
            else            { src = Wo;                        dst = wot; }
        } else if (blk < 54272) {
            int r = blk - 50176;
            bx = r & 127; by = r >> 7; K = 1024; N = 4096; src = W1; dst = w1t;
        } else {
            int r = blk - 54272;
            bx = r & 31; by = r >> 5; K = 4096; N = 1024; src = W2; dst = w2t;
        }
        int n0 = bx << 5, k0 = by << 5;
        int cc = tid & 31, rr = tid >> 5;
#pragma unroll
        for (int p = 0; p < 4; p++) {
            int kk = (p << 3) + rr;
            tile[kk][cc] = src[(size_t)(k0 + kk) * N + n0 + cc];
        }
        __syncthreads();
#pragma unroll
        for (int p = 0; p < 4; p++) {
            int nn = (p << 3) + rr;
            dst[(size_t)(n0 + nn) * K + k0 + cc] = f2bf(tile[cc][nn]);
        }
        return;
    }
    if (blk < 74816) {
        int idx = (blk - 58368) * 256 + tid;
        int d = idx & 1023;
        int row = (idx >> 10) % 1028;
        int b = (idx >> 10) / 1028;
        int l = row - 2;
        float v = (l >= 0 && l < DL) ? x[((size_t)(b * DL + l)) * DD + d] : 0.f;
        xpad[idx] = f2bf(v);
        return;
    }
    if (tid == 0) {
        float l0 = agg[0], l1 = agg[1], l2 = agg[2], l3 = agg[3];
        float m = fmaxf(fmaxf(l0, l1), fmaxf(l2, l3));
        float e0 = __expf(l0 - m), e1 = __expf(l1 - m);
        float e2 = __expf(l2 - m), e3 = __expf(l3 - m);
        float ssum = e0 + e1 + e2 + e3;
        float w0 = e0 / ssum, w1 = e1 / ssum, w2 = e2 / ssum, w3 = e3 / ssum;
        wagg[0] = w0; wagg[1] = w1; wagg[2] = w2; wagg[3] = w3;
        *aux = -(w0 * logf(w0 + 1e-9f) + w1 * logf(w1 + 1e-9f) +
                 w2 * logf(w2 + 1e-9f) + w3 * logf(w3 + 1e-9f));
    }
}

// ---------------------------------------------------------------- MFMA GEMM
// C[M,N] = act(A[M,K] @ B[K,N] + bias), A bf16 [M][K], Bt bf16 [N][K].
// 128x128 tile, BK=32, 4 waves -> 64x64 each. ACT: 0 none, 1 GELU. OBF: bf16 out.
template <int ACT, int OBF>
__global__ __launch_bounds__(256) void mgemm_kernel(
    const short* __restrict__ A, const short* __restrict__ Bt,
    const float* __restrict__ bias, void* __restrict__ Cv,
    int M, int N, int K) {
    __shared__ short As[128 * 32];
    __shared__ short Bs[128 * 32];
    int tid = threadIdx.x;
    int wave = tid >> 6, lane = tid & 63;
    int lq = lane & 15, quad = lane >> 4;
    int m0 = blockIdx.y << 7, n0 = blockIdx.x << 7;
    int wm = (wave & 1) << 6, wn = (wave >> 1) << 6;
    int r0 = tid >> 2, r1 = (256 + tid) >> 2;
    int kc0 = (tid & 3) << 3;
    const short* Ag0 = A + (size_t)(m0 + r0) * K + kc0;
    const short* Ag1 = A + (size_t)(m0 + r1) * K + kc0;
    const short* Bg0 = Bt + (size_t)(n0 + r0) * K + kc0;
    const short* Bg1 = Bt + (size_t)(n0 + r1) * K + kc0;
    float4v acc[4][4];
#pragma unroll
    for (int mi = 0; mi < 4; mi++)
#pragma unroll
        for (int ni = 0; ni < 4; ni++) acc[mi][ni] = (float4v){0.f, 0.f, 0.f, 0.f};

    for (int k0 = 0; k0 < K; k0 += 32) {
        __syncthreads();
        GLOAD_LDS16(Ag0 + k0, As + tid * 8);
        GLOAD_LDS16(Ag1 + k0, As + (256 + tid) * 8);
        GLOAD_LDS16(Bg0 + k0, Bs + tid * 8);
        GLOAD_LDS16(Bg1 + k0, Bs + (256 + tid) * 8);
        __syncthreads();
        short8 af[4], bfr[4];
#pragma unroll
        for (int mi = 0; mi < 4; mi++)
            af[mi] = *(const short8*)(As + ((wm + (mi << 4) + lq) << 5) + (quad << 3));
#pragma unroll
        for (int ni = 0; ni < 4; ni++)
            bfr[ni] = *(const short8*)(Bs + ((wn + (ni << 4) + lq) << 5) + (quad << 3));
#pragma unroll
        for (int mi = 0; mi < 4; mi++)
#pragma unroll
            for (int ni = 0; ni < 4; ni++)
                acc[mi][ni] = __builtin_amdgcn_mfma_f32_16x16x32_bf16(
                    af[mi], bfr[ni], acc[mi][ni], 0, 0, 0);
    }
#pragma unroll
    for (int ni = 0; ni < 4; ni++) {
        int col = n0 + wn + (ni << 4) + lq;
        float bv = bias ? bias[col] : 0.f;
#pragma unroll
        for (int mi = 0; mi < 4; mi++) {
#pragma unroll
            for (int r = 0; r < 4; r++) {
                int row = m0 + wm + (mi << 4) + (quad << 2) + r;
                float v = acc[mi][ni][r] + bv;
                if (ACT == 1) v = 0.5f * v * (1.0f + erff(v * 0.70710678118654752f));
                if (OBF) ((short*)Cv)[(size_t)row * N + col] = f2bf(v);
                else ((float*)Cv)[(size_t)row * N + col] = v;
            }
        }
    }
}

// ---------------------------------------------------------------- grouped KV GEMM
// One dispatch, all 4 scales. K-half columns (<1024) are written DIRECTLY in
// K-fragment layout (kfrall); V-half columns go row-major to kvall.
__global__ __launch_bounds__(256) void kvgemm_kernel(
    const short* __restrict__ acts, const short* __restrict__ wkvt,
    short* __restrict__ kvall, short* __restrict__ kfrall) {
    __shared__ short As[128 * 32];
    __shared__ short Bs[128 * 32];
    int my = blockIdx.y;                       // 0..59
    int s = my < 32 ? 0 : my < 48 ? 1 : my < 56 ? 2 : 3;
    int m0 = my << 7;
    int rb = s == 0 ? 0 : s == 1 ? 4096 : s == 2 ? 6144 : 7168;
    size_t doff = s == 0 ? 0 : s == 1 ? 4194304 : s == 2 ? 6291456 : 7340032;
    int Ls = DL >> s;
    const short* Bt = wkvt + (size_t)s * 2097152;
    const int K = 1024, N = 2048;
    int tid = threadIdx.x;
    int wave = tid >> 6, lane = tid & 63;
    int lq = lane & 15, quad = lane >> 4;
    int n0 = blockIdx.x << 7;
    int wm = (wave & 1) << 6, wn = (wave >> 1) << 6;
    int r0 = tid >> 2, r1 = (256 + tid) >> 2;
    int kc0 = (tid & 3) << 3;
    const short* Ag0 = acts + (size_t)(m0 + r0) * K + kc0;
    const short* Ag1 = acts + (size_t)(m0 + r1) * K + kc0;
    const short* Bg0 = Bt + (size_t)(n0 + r0) * K + kc0;
    const short* Bg1 = Bt + (size_t)(n0 + r1) * K + kc0;
    float4v acc[4][4];
#pragma unroll
    for (int mi = 0; mi < 4; mi++)
#pragma unroll
        for (int ni = 0; ni < 4; ni++) acc[mi][ni] = (float4v){0.f, 0.f, 0.f, 0.f};
    for (int k0 = 0; k0 < K; k0 += 32) {
        __syncthreads();
        GLOAD_LDS16(Ag0 + k0, As + tid * 8);
        GLOAD_LDS16(Ag1 + k0, As + (256 + tid) * 8);
        GLOAD_LDS16(Bg0 + k0, Bs + tid * 8);
        GLOAD_LDS16(Bg1 + k0, Bs + (256 + tid) * 8);
        __syncthreads();
        short8 af[4], bfr[4];
#pragma unroll
        for (int mi = 0; mi < 4; mi++)
            af[mi] = *(const short8*)(As + ((wm + (mi << 4) + lq) << 5) + (quad << 3));
#pragma unroll
        for (int ni = 0; ni < 4; ni++)
            bfr[ni] = *(const short8*)(Bs + ((wn + (ni << 4) + lq) << 5) + (quad << 3));
#pragma unroll
        for (int mi = 0; mi < 4; mi++)
#pragma unroll
            for (int ni = 0; ni < 4; ni++)
                acc[mi][ni] = __builtin_amdgcn_mfma_f32_16x16x32_bf16(
                    af[mi], bfr[ni], acc[mi][ni], 0, 0, 0);
    }
    bool isK = (n0 < 1024);
#pragma unroll
    for (int ni = 0; ni < 4; ni++) {
        int col = n0 + wn + (ni << 4) + lq;
        if (isK) {
            int h = col >> 6, dc = (col >> 3) & 7, di = col & 7;
#pragma unroll
            for (int mi = 0; mi < 4; mi++)
#pragma unroll
                for (int r = 0; r < 4; r++) {
                    int row = m0 + wm + (mi << 4) + (quad << 2) + r;
                    int jg = row - rb;
                    int b = jg >> (10 - s);
                    int j = jg & (Ls - 1);
                    int bh = (b << 4) | h;
                    size_t addr = doff + (((size_t)bh * (Ls >> 4) + (j >> 4)) << 10) +
                                  (dc << 7) + ((j & 15) << 3) + di;
                    kfrall[addr] = f2bf(acc[mi][ni][r]);
                }
        } else {
#pragma unroll
            for (int mi = 0; mi < 4; mi++)
#pragma unroll
                for (int r = 0; r < 4; r++) {
                    int row = m0 + wm + (mi << 4) + (quad << 2) + r;
                    kvall[(size_t)row * N + col] = f2bf(acc[mi][ni][r]);
                }
        }
    }
}

// ---------------------------------------------------------------- split-K GEMM
__global__ __launch_bounds__(256) void mgemm_pk_kernel(
    const short* __restrict__ A, const short* __restrict__ Bt,
    const float* __restrict__ bias, float* __restrict__ Cout,
    int M, int N, int Kfull, int KH) {
    __shared__ short As[128 * 32];
    __shared__ short Bs[128 * 32];
    int kz = blockIdx.z;
    const short* Ab = A + (size_t)kz * KH;
    const short* Btb = Bt + (size_t)kz * KH;
    float* Co = Cout + (size_t)kz * M * N;
    int tid = threadIdx.x;
    int wave = tid >> 6, lane = tid & 63;
    int lq = lane & 15, quad = lane >> 4;
    int m0 = blockIdx.y << 7, n0 = blockIdx.x << 7;
    int wm = (wave & 1) << 6, wn = (wave >> 1) << 6;
    int r0 = tid >> 2, r1 = (256 + tid) >> 2;
    int kc0 = (tid & 3) << 3;
    const short* Ag0 = Ab + (size_t)(m0 + r0) * Kfull + kc0;
    const short* Ag1 = Ab + (size_t)(m0 + r1) * Kfull + kc0;
    const short* Bg0 = Btb + (size_t)(n0 + r0) * Kfull + kc0;
    const short* Bg1 = Btb + (size_t)(n0 + r1) * Kfull + kc0;
    float4v acc[4][4];
#pragma unroll
    for (int mi = 0; mi < 4; mi++)
#pragma unroll
        for (int ni = 0; ni < 4; ni++) acc[mi][ni] = (float4v){0.f, 0.f, 0.f, 0.f};
    for (int k0 = 0; k0 < KH; k0 += 32) {
        __syncthreads();
        GLOAD_LDS16(Ag0 + k0, As + tid * 8);
        GLOAD_LDS16(Ag1 + k0, As + (256 + tid) * 8);
        GLOAD_LDS16(Bg0 + k0, Bs + tid * 8);
        GLOAD_LDS16(Bg1 + k0, Bs + (256 + tid) * 8);
        __syncthreads();
        short8 af[4], bfr[4];
#pragma unroll
        for (int mi = 0; mi < 4; mi++)
            af[mi] = *(const short8*)(As + ((wm + (mi << 4) + lq) << 5) + (quad << 3));
#pragma unroll
        for (int ni = 0; ni < 4; ni++)
            bfr[ni] = *(const short8*)(Bs + ((wn + (ni << 4) + lq) << 5) + (quad << 3));
#pragma unroll
        for (int mi = 0; mi < 4; mi++)
#pragma unroll
            for (int ni = 0; ni < 4; ni++)
                acc[mi][ni] = __builtin_amdgcn_mfma_f32_16x16x32_bf16(
                    af[mi], bfr[ni], acc[mi][ni], 0, 0, 0);
    }
#pragma unroll
    for (int ni = 0; ni < 4; ni++) {
        int col = n0 + wn + (ni << 4) + lq;
        float bv = (bias && kz == 0) ? bias[col] : 0.f;
#pragma unroll
        for (int mi = 0; mi < 4; mi++)
#pragma unroll
            for (int r = 0; r < 4; r++) {
                int row = m0 + wm + (mi << 4) + (quad << 2) + r;
                Co[(size_t)row * N + col] = acc[mi][ni][r] + bv;
            }
    }
}

// ---------------------------------------------------------------- conv tap-split
// blockIdx.z = tap; fp32 partials to pbuf + z*4M. relu+bias in convcomb.
__global__ __launch_bounds__(256) void convdil_pk_kernel(
    const short* __restrict__ xp, const short* __restrict__ Wt,
    float* __restrict__ pbuf) {
    __shared__ short As[128 * 32];
    __shared__ short Bs[128 * 32];
    int kp = blockIdx.z;
    int tid = threadIdx.x;
    int wave = tid >> 6, lane = tid & 63;
    int lq = lane & 15, quad = lane >> 4;
    int m0 = blockIdx.y << 7, n0 = blockIdx.x << 7;
    int wm = (wave & 1) << 6, wn = (wave >> 1) << 6;
    int b = m0 >> 10, ll0 = m0 & 1023;
    int r0 = tid >> 2, r1 = (256 + tid) >> 2;
    int kc = (tid & 3) << 3;
    float* Co = pbuf + (size_t)kp * DB * DL * DD;
    const short* Abase = xp + ((size_t)(b * 1028 + ll0 + 2 * kp)) * DD + kc;
    const short* Bbase = Wt + (size_t)kp * DD * DD;
    const short* Bg0 = Bbase + (size_t)(n0 + r0) * DD + kc;
    const short* Bg1 = Bbase + (size_t)(n0 + r1) * DD + kc;
    float4v acc[4][4];
#pragma unroll
    for (int mi = 0; mi < 4; mi++)
#pragma unroll
        for (int ni = 0; ni < 4; ni++) acc[mi][ni] = (float4v){0.f, 0.f, 0.f, 0.f};
    for (int k0 = 0; k0 < DD; k0 += 32) {
        __syncthreads();
        GLOAD_LDS16(Abase + (size_t)r0 * DD + k0, As + tid * 8);
        GLOAD_LDS16(Abase + (size_t)r1 * DD + k0, As + (256 + tid) * 8);
        GLOAD_LDS16(Bg0 + k0, Bs + tid * 8);
        GLOAD_LDS16(Bg1 + k0, Bs + (256 + tid) * 8);
        __syncthreads();
        short8 af[4], bfr[4];
#pragma unroll
        for (int mi = 0; mi < 4; mi++)
            af[mi] = *(const short8*)(As + ((wm + (mi << 4) + lq) << 5) + (quad << 3));
#pragma unroll
        for (int ni = 0; ni < 4; ni++)
            bfr[ni] = *(const short8*)(Bs + ((wn + (ni << 4) + lq) << 5) + (quad << 3));
#pragma unroll
        for (int mi = 0; mi < 4; mi++)
#pragma unroll
            for (int ni = 0; ni < 4; ni++)
                acc[mi][ni] = __builtin_amdgcn_mfma_f32_16x16x32_bf16(
                    af[mi], bfr[ni], acc[mi][ni], 0, 0, 0);
    }
#pragma unroll
    for (int ni = 0; ni < 4; ni++) {
        int col = n0 + wn + (ni << 4) + lq;
#pragma unroll
        for (int mi = 0; mi < 4; mi++)
#pragma unroll
            for (int r = 0; r < 4; r++) {
                int row = m0 + wm + (mi << 4) + (quad << 2) + r;
                Co[(size_t)row * DD + col] = acc[mi][ni][r];
            }
    }
}

// xcb = bf16(relu(p0+p1+p2 + bias)), 4 elems/thread over 4M
__global__ __launch_bounds__(256) void convcomb_kernel(
    const float* __restrict__ pbuf, const float* __restrict__ bvec,
    short* __restrict__ xcb) {
    const size_t M4 = (size_t)DB * DL * DD;
    int idx = (blockIdx.x * 256 + threadIdx.x) << 2;
    int col = idx & 1023;
    float4 p0 = *(const float4*)&pbuf[idx];
    float4 p1 = *(const float4*)&pbuf[M4 + idx];
    float4 p2 = *(const float4*)&pbuf[2 * M4 + idx];
    float4 bb = *(const float4*)&bvec[col];
    ushort4 u;
    u.x = (unsigned short)f2bf(fmaxf(p0.x + p1.x + p2.x + bb.x, 0.f));
    u.y = (unsigned short)f2bf(fmaxf(p0.y + p1.y + p2.y + bb.y, 0.f));
    u.z = (unsigned short)f2bf(fmaxf(p0.z + p1.z + p2.z + bb.z, 0.f));
    u.w = (unsigned short)f2bf(fmaxf(p0.w + p1.w + p2.w + bb.w, 0.f));
    *(ushort4*)&xcb[idx] = u;
}

// ---------------------------------------------------------------- V fragment prep
__global__ __launch_bounds__(256) void vfrag_all_kernel(const short* __restrict__ kvall,
                                                        short* __restrict__ vfr0) {
    __shared__ short tile[32][33];
    int flat = blockIdx.x;                          // 0..7679
    int s, base, rb;
    size_t doff;
    if (flat < 4096)      { s = 0; base = 0;    rb = 0;    doff = 0; }
    else if (flat < 6144) { s = 1; base = 4096; rb = 4096; doff = 4194304; }
    else if (flat < 7168) { s = 2; base = 6144; rb = 6144; doff = 6291456; }
    else                  { s = 3; base = 7168; rb = 7168; doff = 7340032; }
    int rem = flat - base;
    int Ls = DL >> s;
    int nt = Ls >> 5;
    int j0t = rem & (nt - 1);
    int rest = rem >> (5 - s);
    int dt = rest & 1;
    int bh = rest >> 1;
    int j0 = j0t << 5, d0 = dt << 5;
    int b = bh >> 4, h = bh & 15;
    int tid = threadIdx.x;
    int cc = tid & 31, rr = tid >> 5;
#pragma unroll
    for (int p = 0; p < 4; p++) {
        int jj = (p << 3) + rr;
        tile[jj][cc] = kvall[((size_t)(rb + b * Ls + j0 + jj) << 11) + 1024 +
                             (h << 6) + d0 + cc];
    }
    __syncthreads();
    int c = j0 >> 6, ks = (j0 >> 5) & 1;
#pragma unroll
    for (int p = 0; p < 4; p++) {
        int d = d0 + (p << 3) + rr;
        int tt = d >> 4, lqv = d & 15;
        size_t off = doff + (((size_t)bh * (Ls >> 6) + c) << 12) + (ks << 11) +
                     (tt << 9) + (lqv << 5) + cc;
        vfr0[off] = tile[cc][(p << 3) + rr];
    }
}

// ---------------------------------------------------------------- attention
// Scale-split flash attention: block = 16 q-rows x one (b,h), grid 64x64 =
// 4096 blocks x 4 waves = 16384 waves (2x slot oversubscription).
// w0: s0 keys[0,512) raw; w1: s0 keys[512,1024) raw; w2: s1 normalized;
// w3: s2 + s3, each normalized, accumulated into its slab.
// Per-wave LDS slab unioned: bf16 P staging during sweep, fp32 partial after.
// One barrier, then 4-way combine -> attb (bf16).
__global__ __launch_bounds__(256) void attn_fused5_kernel(
    const short* __restrict__ qb4, const short* __restrict__ kfr0,
    const short* __restrict__ vfr0, const float* __restrict__ wagg,
    short* __restrict__ attb) {
    __shared__ __align__(16) float slab[4][16][68];   // 17408 B (per-wave 4352 B)
    __shared__ __align__(16) short pscr[1168];        // w3 seg1 P staging
    __shared__ float lbuf[2][16];
    int tid = threadIdx.x;
    int w = tid >> 6, lane = tid & 63;
    int lq = lane & 15, quad = lane >> 4;
    int bh = blockIdx.y;
    int b = bh >> 4, h = bh & 15;
    int qrow0 = b * DL + (blockIdx.x << 4);
    const float c_exp = 0.18033688f;    // log2(e)/8
    int nseg = (w == 3) ? 2 : 1;

#pragma unroll 1
    for (int seg = 0; seg < nseg; seg++) {
        int s = (w <= 1) ? 0 : (w == 2) ? 1 : (seg == 0 ? 2 : 3);
        int Ls = DL >> s;
        int cbeg = (w == 1) ? 512 : 0;
        int cend = (w == 0) ? 512 : ((w == 1) ? 1024 : Ls);
        size_t doff = s == 0 ? 0 : s == 1 ? 4194304 : s == 2 ? 6291456 : 7340032;

        short* pl = (w == 3 && seg == 1) ? pscr : (short*)&slab[w][0][0];

        const short* qbase = qb4 + ((size_t)(qrow0 + lq) << 12) + (s << 10) +
                             (h << 6) + (quad << 3);
        short8 qf0 = *(const short8*)qbase;
        short8 qf1 = *(const short8*)(qbase + 32);

        const short* kfb = kfr0 + doff + (((size_t)bh * (Ls >> 4)) << 10) +
                           (quad << 7) + (lq << 3);
        const short* vfb = vfr0 + doff + (((size_t)bh * (Ls >> 6)) << 12) +
                           (lq << 5) + (quad << 3);

        float4v O[4];
        float lp[4] = {0.f, 0.f, 0.f, 0.f};
#pragma unroll
        for (int t = 0; t < 4; t++) O[t] = (float4v){0.f, 0.f, 0.f, 0.f};

        for (int c0 = cbeg; c0 < cend; c0 += 64) {
            float4v S[4];
            int g0 = c0 >> 4;
#pragma unroll
            for (int t = 0; t < 4; t++) {
                const short* kp = kfb + ((size_t)(g0 + t) << 10);
                short8 kf0 = *(const short8*)kp;
                short8 kf1 = *(const short8*)(kp + 512);
                float4v z = (float4v){0.f, 0.f, 0.f, 0.f};
                z = __builtin_amdgcn_mfma_f32_16x16x32_bf16(qf0, kf0, z, 0, 0, 0);
                S[t] = __builtin_amdgcn_mfma_f32_16x16x32_bf16(qf1, kf1, z, 0, 0, 0);
            }
#pragma unroll
            for (int t = 0; t < 4; t++)
#pragma unroll
                for (int r = 0; r < 4; r++) {
                    float p = exp2f(S[t][r] * c_exp);
                    lp[r] += p;
                    pl[(((quad << 2) + r) * 72) + (t << 4) + lq] =
                        (short)(__float_as_uint(p) >> 16);   // trunc-bf16
                }
            const short* vcb = vfb + ((size_t)(c0 >> 6) << 12);
#pragma unroll
            for (int ks = 0; ks < 2; ks++) {
                short8 af = *(const short8*)&pl[lq * 72 + (ks << 5) + (quad << 3)];
#pragma unroll
                for (int t = 0; t < 4; t++) {
                    short8 vf = *(const short8*)(vcb + (ks << 11) + (t << 9));
                    O[t] = __builtin_amdgcn_mfma_f32_16x16x32_bf16(af, vf, O[t], 0, 0, 0);
                }
            }
        }
        // reduce partial denominators across lq lanes
        float lsum[4];
#pragma unroll
        for (int r = 0; r < 4; r++) {
            float l = lp[r];
            l += __shfl_xor(l, 1, 64);
            l += __shfl_xor(l, 2, 64);
            l += __shfl_xor(l, 4, 64);
            l += __shfl_xor(l, 8, 64);
            lsum[r] = l;
        }
        // end-of-segment: write into own slab (safe: own P reads complete)
        if (w <= 1) {
#pragma unroll
            for (int r = 0; r < 4; r++) {
                if (lq == 0) lbuf[w][(quad << 2) + r] = lsum[r];
#pragma unroll
                for (int t = 0; t < 4; t++)
                    slab[w][(quad << 2) + r][(t << 4) + lq] = O[t][r];
            }
        } else {
            float wsc = wagg[s];
            if (w == 3 && seg == 1) {
#pragma unroll
                for (int r = 0; r < 4; r++) {
                    float li = wsc / lsum[r];
#pragma unroll
                    for (int t = 0; t < 4; t++)
                        slab[3][(quad << 2) + r][(t << 4) + lq] += O[t][r] * li;
                }
            } else {
#pragma unroll
                for (int r = 0; r < 4; r++) {
                    float li = wsc / lsum[r];
#pragma unroll
                    for (int t = 0; t < 4; t++)
                        slab[w][(quad << 2) + r][(t << 4) + lq] = O[t][r] * li;
                }
            }
        }
    }
    __syncthreads();
    // combine: wave w handles rows [4w, 4w+4), lane = output dim
    float w0agg = wagg[0];
    int d = lane;
#pragma unroll
    for (int rr = 0; rr < 4; rr++) {
        int row = (w << 2) + rr;
        float l01 = lbuf[0][row] + lbuf[1][row];
        float v = (slab[0][row][d] + slab[1][row][d]) * (w0agg / l01) +
                  slab[2][row][d] + slab[3][row][d];
        attb[((size_t)(qrow0 + row) << 10) + (h << 6) + d] = f2bf(v);
    }
}

// ---------------------------------------------------------------- add3 + LN
template <int OBF>
__global__ __launch_bounds__(256) void addln3_kernel(
    const float* __restrict__ a, const float* __restrict__ b0,
    const float* __restrict__ b1, const float* __restrict__ gam,
    const float* __restrict__ bet, float* __restrict__ out,
    short* __restrict__ outb) {
    __shared__ float redA[4], redB[4];
    int row = blockIdx.x, tid = threadIdx.x;
    size_t base = (size_t)row * DD + (tid << 2);
    float4 av = *(const float4*)&a[base];
    float4 bv = *(const float4*)&b0[base];
    float4 cv = *(const float4*)&b1[base];
    float s0 = av.x + bv.x + cv.x, s1 = av.y + bv.y + cv.y;
    float s2 = av.z + bv.z + cv.z, s3 = av.w + bv.w + cv.w;
    float lsum = s0 + s1 + s2 + s3;
    float lsq = s0 * s0 + s1 * s1 + s2 * s2 + s3 * s3;
#pragma unroll
    for (int o = 32; o > 0; o >>= 1) {
        lsum += __shfl_down(lsum, o, 64);
        lsq += __shfl_down(lsq, o, 64);
    }
    int lane = tid & 63, wid = tid >> 6;
    if (lane == 0) { redA[wid] = lsum; redB[wid] = lsq; }
    __syncthreads();
    float tsum = redA[0] + redA[1] + redA[2] + redA[3];
    float tsq = redB[0] + redB[1] + redB[2] + redB[3];
    float mean = tsum * (1.0f / DD);
    float var = tsq * (1.0f / DD) - mean * mean;
    float rstd = rsqrtf(var + 1e-5f);
    float4 gv = *(const float4*)&gam[tid << 2];
    float4 bev = *(const float4*)&bet[tid << 2];
    float4 o;
    o.x = (s0 - mean) * rstd * gv.x + bev.x;
    o.y = (s1 - mean) * rstd * gv.y + bev.y;
    o.z = (s2 - mean) * rstd * gv.z + bev.z;
    o.w = (s3 - mean) * rstd * gv.w + bev.w;
    *(float4*)&out[base] = o;
    if (OBF) {
        ushort4 u;
        u.x = (unsigned short)f2bf(o.x);
        u.y = (unsigned short)f2bf(o.y);
        u.z = (unsigned short)f2bf(o.z);
        u.w = (unsigned short)f2bf(o.w);
        *(ushort4*)&outb[base] = u;
    }
}

// ---------------------------------------------------------------- launcher
extern "C" void kernel_launch(void* const* d_in, const int* in_sizes, int n_in,
                              void* d_out, int out_size, void* d_ws, size_t ws_size,
                              hipStream_t stream) {
    (void)in_sizes; (void)n_in; (void)out_size; (void)ws_size;
    const float* x   = (const float*)d_in[0];
    const float* Wdc = (const float*)d_in[1];
    const float* bdc = (const float*)d_in[2];
    const float* Wdec= (const float*)d_in[3];
    const float* Wq  = (const float*)d_in[4];
    const float* Wk  = (const float*)d_in[5];
    const float* Wv  = (const float*)d_in[6];
    const float* Wo  = (const float*)d_in[7];
    const float* agg = (const float*)d_in[8];
    const float* g1  = (const float*)d_in[9];
    const float* be1 = (const float*)d_in[10];
    const float* g2  = (const float*)d_in[11];
    const float* be2 = (const float*)d_in[12];
    const float* W1  = (const float*)d_in[13];
    const float* b1  = (const float*)d_in[14];
    const float* W2  = (const float*)d_in[15];
    const float* b2  = (const float*)d_in[16];
    float* out = (float*)d_out;

    float* ws = (float*)d_ws;
    size_t off = 0;
    auto alloc = [&](size_t nfloats) { float* p = ws + off; off += nfloats; return p; };
    const size_t M1 = 1024 * 1024;
    short* wdc_bt  = (short*)alloc(3 * M1 / 2);
    short* wdec_bt = (short*)alloc(3 * M1);
    short* wq4t    = (short*)alloc(2 * M1);
    short* wkvt    = (short*)alloc(4 * M1);
    short* wot     = (short*)alloc(M1 / 2);
    short* w1t     = (short*)alloc(2 * M1);
    short* w2t     = (short*)alloc(2 * M1);
    float* wagg    = alloc(64);
    short* xpad    = (short*)alloc(2105344);
    // activation buffers: contiguous rows 0..7679 for grouped KV GEMM
    short* xcb     = (short*)alloc(2 * M1);         // rows [0,4096)
    short* s1b     = (short*)alloc(M1);             // rows [4096,6144)
    short* s2b     = (short*)alloc(M1 / 2);         // rows [6144,7168)
    short* s3b     = (short*)alloc(M1 / 4);         // rows [7168,7680)
    short* qb4     = (short*)alloc(8 * M1);         // later FFN hidden; conv partials 0/1 first
    short* kvall   = (short*)alloc(7 * M1 + M1 / 2);// V-half rows; conv partial 2 first
    short* kfrall  = (short*)alloc(3 * M1 + 3 * M1 / 4);
    short* vfrall  = (short*)alloc(3 * M1 + 3 * M1 / 4);
    short* attb    = (short*)alloc(2 * M1);
    float* x1      = alloc(4 * M1);
    short* x1b     = (short*)alloc(2 * M1);
    float* pkbuf   = alloc(8 * M1);                 // split-K partials (2 x 4M fp32)
    short* hb      = qb4;                           // FFN hidden [4096][4096] bf16
    // conv tap partials (12M fp32) alias dead-at-that-point regions:
    float* convp   = (float*)qb4;                   // taps 0,1 (8M fp32)
    float* convp2  = (float*)kvall;                 // tap 2 (4M fp32)

    dim3 blk(256);
    // ---- fused prep (weights, xpad, agg softmax/aux) : ONE dispatch
    prep_all_kernel<<<dim3(74817), blk, 0, stream>>>(
        Wdc, Wdec, Wq, Wk, Wv, Wo, W1, W2, x, agg,
        wdc_bt, wdec_bt, wq4t, wkvt, wot, w1t, w2t, xpad, wagg,
        out + (size_t)DB * DL * DD);

    // 1. dilated conv: tap-split x3 (fp32 partials) + relu/bias combine
    convdil_pk_kernel<<<dim3(DD / 128, DB * DL / 128, 3), blk, 0, stream>>>(
        xpad, wdc_bt, convp);   // taps 0,1 -> convp; tap 2 -> convp+8M? no:
    // NOTE: convdil_pk writes pbuf + z*4M; z=2 slab must be convp2. Since convp
    // spans only 8M floats, pass base convp and place tap2 there via pointer
    // arithmetic: we allocated qb4 (8M floats) + kvall contiguously, so
    // convp + 2*4M == (float*)kvall == convp2. (ws is one contiguous block.)
    (void)convp2;
    convcomb_kernel<<<dim3(4 * M1 / (256 * 4)), blk, 0, stream>>>(convp, bdc, xcb);

    // 2. decomposition convs (sequential data dependence)
    mgemm_kernel<0, 1><<<dim3(DD / 128, (DB * DL / 2) / 128), blk, 0, stream>>>(
        xcb, wdec_bt, nullptr, s1b, DB * DL / 2, DD, 2 * DD);
    mgemm_kernel<0, 1><<<dim3(DD / 128, (DB * DL / 4) / 128), blk, 0, stream>>>(
        s1b, wdec_bt + 2 * M1, nullptr, s2b, DB * DL / 4, DD, 2 * DD);
    mgemm_kernel<0, 1><<<dim3(DD / 128, (DB * DL / 8) / 128), blk, 0, stream>>>(
        s2b, wdec_bt + 4 * M1, nullptr, s3b, DB * DL / 8, DD, 2 * DD);

    // 3a. batched Q projection (all 4 scales, N=4096)
    mgemm_kernel<0, 1><<<dim3(32, 32), blk, 0, stream>>>(
        xcb, wq4t, nullptr, qb4, DB * DL, 4 * DD, DD);

    // 3b. grouped K|V projection: K-half straight to fragment layout
    kvgemm_kernel<<<dim3(16, 60), blk, 0, stream>>>(xcb, wkvt, kvall, kfrall);

    // 3c. V fragment prep
    vfrag_all_kernel<<<dim3(7680), blk, 0, stream>>>(kvall, vfrall);

    // 3d. scale-split fused attention (16384 waves, 1 barrier)
    attn_fused5_kernel<<<dim3(DL / 16, DB * DH), blk, 0, stream>>>(
        qb4, kfrall, vfrall, wagg, attb);

    // 4. shared output projection (split-K x2 -> fp32 partials)
    mgemm_pk_kernel<<<dim3(8, 32, 2), blk, 0, stream>>>(
        attb, wot, nullptr, pkbuf, DB * DL, DD, DD, DD / 2);

    // 5. residual + LN1 (3-input)
    addln3_kernel<1><<<dim3(DB * DL), blk, 0, stream>>>(
        x, pkbuf, pkbuf + 4 * M1, g1, be1, x1, x1b);

    // 6. FFN: GELU GEMM then split-K x2 down-projection
    mgemm_kernel<1, 1><<<dim3(DF / 128, (DB * DL) / 128), blk, 0, stream>>>(
        x1b, w1t, b1, hb, DB * DL, DF, DD);
    mgemm_pk_kernel<<<dim3(8, 32, 2), blk, 0, stream>>>(
        hb, w2t, b2, pkbuf, DB * DL, DD, DF, DF / 2);

    // 7. residual + LN2 -> out (3-input)
    addln3_kernel<0><<<dim3(DB * DL), blk, 0, stream>>>(
        x1, pkbuf, pkbuf + 4 * M1, g2, be2, out, nullptr);
}

// Round 9
// 766.071 us; speedup vs baseline: 6.2413x; 1.0969x over previous
//
#include <hip/hip_runtime.h>
#include <cstddef>

#define DB 4
#define DL 1024
#define DD 1024
#define DH 16
#define DF 4096

typedef __attribute__((ext_vector_type(8))) short short8;
typedef __attribute__((ext_vector_type(4))) float float4v;

static __device__ __forceinline__ short f2bf(float f) {
    unsigned u = __float_as_uint(f);
    unsigned r = (u + 0x7FFFu + ((u >> 16) & 1u)) >> 16;   // RNE
    return (short)r;
}

#define GLOAD_LDS16(gp, lp)                                                          \
    __builtin_amdgcn_global_load_lds(                                                \
        (const __attribute__((address_space(1))) void*)(gp),                         \
        (__attribute__((address_space(3))) void*)(lp), 16, 0, 0)

// ---------------------------------------------------------------- mega-prep
__global__ __launch_bounds__(256) void prep_all_kernel(
    const float* __restrict__ Wdc, const float* __restrict__ Wdec,
    const float* __restrict__ Wq, const float* __restrict__ Wk,
    const float* __restrict__ Wv, const float* __restrict__ Wo,
    const float* __restrict__ W1, const float* __restrict__ W2,
    const float* __restrict__ x, const float* __restrict__ agg,
    short* __restrict__ wdc_bt, short* __restrict__ wdec_bt,
    short* __restrict__ wq4t, short* __restrict__ wkvt, short* __restrict__ wot,
    short* __restrict__ w1t, short* __restrict__ w2t, short* __restrict__ xpad,
    float* __restrict__ wagg, float* __restrict__ aux) {
    __shared__ float tile[32][33];
    const size_t M1 = 1024 * 1024;
    int blk = blockIdx.x, tid = threadIdx.x;
    if (blk < 12288) {
        int idx = blk * 256 + tid;
        int i = idx & 1023, o = (idx >> 10) & 1023, k = idx >> 20;
        wdc_bt[idx] = f2bf(Wdc[((size_t)o * 1024 + i) * 3 + k]);
        return;
    }
    if (blk < 36864) {
        int idx = (blk - 12288) * 256 + tid;
        int i = idx & 1023, k2 = (idx >> 10) & 1, n = (idx >> 11) & 1023, s = idx >> 21;
        wdec_bt[idx] = f2bf(Wdec[(((size_t)(s * 1024 + n)) * 1024 + i) * 2 + k2]);
        return;
    }
    if (blk < 58368) {
        const float* src; short* dst; int K, N, bx, by;
        if (blk < 50176) {
            int r = blk - 36864;
            int z = r >> 10, rem = r & 1023;
            bx = rem & 31; by = rem >> 5; K = 1024; N = 1024;
            if (z < 4)      { src = Wq + (size_t)z * M1;       dst = wq4t + (size_t)z * M1; }
            else if (z < 8) { src = Wk + (size_t)(z - 4) * M1; dst = wkvt + (size_t)(z - 4) * 2 * M1; }
            else if (z < 12){ src = Wv;                        dst = wkvt + (size_t)(z - 8) * 2 * M1 + M1; }
            else            { src = Wo;                        dst = wot; }
        } else if (blk < 54272) {
            int r = blk - 50176;
            bx = r & 127; by = r >> 7; K = 1024; N = 4096; src = W1; dst = w1t;
        } else {
            int r = blk - 54272;
            bx = r & 31; by = r >> 5; K = 4096; N = 1024; src = W2; dst = w2t;
        }
        int n0 = bx << 5, k0 = by << 5;
        int cc = tid & 31, rr = tid >> 5;
#pragma unroll
        for (int p = 0; p < 4; p++) {
            int kk = (p << 3) + rr;
            tile[kk][cc] = src[(size_t)(k0 + kk) * N + n0 + cc];
        }
        __syncthreads();
#pragma unroll
        for (int p = 0; p < 4; p++) {
            int nn = (p << 3) + rr;
            dst[(size_t)(n0 + nn) * K + k0 + cc] = f2bf(tile[cc][nn]);
        }
        return;
    }
    if (blk < 74816) {
        int idx = (blk - 58368) * 256 + tid;
        int d = idx & 1023;
        int row = (idx >> 10) % 1028;
        int b = (idx >> 10) / 1028;
        int l = row - 2;
        float v = (l >= 0 && l < DL) ? x[((size_t)(b * DL + l)) * DD + d] : 0.f;
        xpad[idx] = f2bf(v);
        return;
    }
    if (tid == 0) {
        float l0 = agg[0], l1 = agg[1], l2 = agg[2], l3 = agg[3];
        float m = fmaxf(fmaxf(l0, l1), fmaxf(l2, l3));
        float e0 = __expf(l0 - m), e1 = __expf(l1 - m);
        float e2 = __expf(l2 - m), e3 = __expf(l3 - m);
        float ssum = e0 + e1 + e2 + e3;
        float w0 = e0 / ssum, w1 = e1 / ssum, w2 = e2 / ssum, w3 = e3 / ssum;
        wagg[0] = w0; wagg[1] = w1; wagg[2] = w2; wagg[3] = w3;
        *aux = -(w0 * logf(w0 + 1e-9f) + w1 * logf(w1 + 1e-9f) +
                 w2 * logf(w2 + 1e-9f) + w3 * logf(w3 + 1e-9f));
    }
}

// ---------------------------------------------------------------- MFMA GEMM
template <int ACT, int OBF>
__global__ __launch_bounds__(256) void mgemm_kernel(
    const short* __restrict__ A, const short* __restrict__ Bt,
    const float* __restrict__ bias, void* __restrict__ Cv,
    int M, int N, int K) {
    __shared__ short As[128 * 32];
    __shared__ short Bs[128 * 32];
    int tid = threadIdx.x;
    int wave = tid >> 6, lane = tid & 63;
    int lq = lane & 15, quad = lane >> 4;
    int m0 = blockIdx.y << 7, n0 = blockIdx.x << 7;
    int wm = (wave & 1) << 6, wn = (wave >> 1) << 6;
    int r0 = tid >> 2, r1 = (256 + tid) >> 2;
    int kc0 = (tid & 3) << 3;
    const short* Ag0 = A + (size_t)(m0 + r0) * K + kc0;
    const short* Ag1 = A + (size_t)(m0 + r1) * K + kc0;
    const short* Bg0 = Bt + (size_t)(n0 + r0) * K + kc0;
    const short* Bg1 = Bt + (size_t)(n0 + r1) * K + kc0;
    float4v acc[4][4];
#pragma unroll
    for (int mi = 0; mi < 4; mi++)
#pragma unroll
        for (int ni = 0; ni < 4; ni++) acc[mi][ni] = (float4v){0.f, 0.f, 0.f, 0.f};

    for (int k0 = 0; k0 < K; k0 += 32) {
        __syncthreads();
        GLOAD_LDS16(Ag0 + k0, As + tid * 8);
        GLOAD_LDS16(Ag1 + k0, As + (256 + tid) * 8);
        GLOAD_LDS16(Bg0 + k0, Bs + tid * 8);
        GLOAD_LDS16(Bg1 + k0, Bs + (256 + tid) * 8);
        __syncthreads();
        short8 af[4], bfr[4];
#pragma unroll
        for (int mi = 0; mi < 4; mi++)
            af[mi] = *(const short8*)(As + ((wm + (mi << 4) + lq) << 5) + (quad << 3));
#pragma unroll
        for (int ni = 0; ni < 4; ni++)
            bfr[ni] = *(const short8*)(Bs + ((wn + (ni << 4) + lq) << 5) + (quad << 3));
#pragma unroll
        for (int mi = 0; mi < 4; mi++)
#pragma unroll
            for (int ni = 0; ni < 4; ni++)
                acc[mi][ni] = __builtin_amdgcn_mfma_f32_16x16x32_bf16(
                    af[mi], bfr[ni], acc[mi][ni], 0, 0, 0);
    }
#pragma unroll
    for (int ni = 0; ni < 4; ni++) {
        int col = n0 + wn + (ni << 4) + lq;
        float bv = bias ? bias[col] : 0.f;
#pragma unroll
        for (int mi = 0; mi < 4; mi++) {
#pragma unroll
            for (int r = 0; r < 4; r++) {
                int row = m0 + wm + (mi << 4) + (quad << 2) + r;
                float v = acc[mi][ni][r] + bv;
                if (ACT == 1) v = 0.5f * v * (1.0f + erff(v * 0.70710678118654752f));
                if (OBF) ((short*)Cv)[(size_t)row * N + col] = f2bf(v);
                else ((float*)Cv)[(size_t)row * N + col] = v;
            }
        }
    }
}

// ---------------------------------------------------------------- grouped KV GEMM
// K-half columns written directly in K-fragment layout; V-half row-major.
__global__ __launch_bounds__(256) void kvgemm_kernel(
    const short* __restrict__ acts, const short* __restrict__ wkvt,
    short* __restrict__ kvall, short* __restrict__ kfrall) {
    __shared__ short As[128 * 32];
    __shared__ short Bs[128 * 32];
    int my = blockIdx.y;                       // 0..59
    int s = my < 32 ? 0 : my < 48 ? 1 : my < 56 ? 2 : 3;
    int m0 = my << 7;
    int rb = s == 0 ? 0 : s == 1 ? 4096 : s == 2 ? 6144 : 7168;
    size_t doff = s == 0 ? 0 : s == 1 ? 4194304 : s == 2 ? 6291456 : 7340032;
    int Ls = DL >> s;
    const short* Bt = wkvt + (size_t)s * 2097152;
    const int K = 1024, N = 2048;
    int tid = threadIdx.x;
    int wave = tid >> 6, lane = tid & 63;
    int lq = lane & 15, quad = lane >> 4;
    int n0 = blockIdx.x << 7;
    int wm = (wave & 1) << 6, wn = (wave >> 1) << 6;
    int r0 = tid >> 2, r1 = (256 + tid) >> 2;
    int kc0 = (tid & 3) << 3;
    const short* Ag0 = acts + (size_t)(m0 + r0) * K + kc0;
    const short* Ag1 = acts + (size_t)(m0 + r1) * K + kc0;
    const short* Bg0 = Bt + (size_t)(n0 + r0) * K + kc0;
    const short* Bg1 = Bt + (size_t)(n0 + r1) * K + kc0;
    float4v acc[4][4];
#pragma unroll
    for (int mi = 0; mi < 4; mi++)
#pragma unroll
        for (int ni = 0; ni < 4; ni++) acc[mi][ni] = (float4v){0.f, 0.f, 0.f, 0.f};
    for (int k0 = 0; k0 < K; k0 += 32) {
        __syncthreads();
        GLOAD_LDS16(Ag0 + k0, As + tid * 8);
        GLOAD_LDS16(Ag1 + k0, As + (256 + tid) * 8);
        GLOAD_LDS16(Bg0 + k0, Bs + tid * 8);
        GLOAD_LDS16(Bg1 + k0, Bs + (256 + tid) * 8);
        __syncthreads();
        short8 af[4], bfr[4];
#pragma unroll
        for (int mi = 0; mi < 4; mi++)
            af[mi] = *(const short8*)(As + ((wm + (mi << 4) + lq) << 5) + (quad << 3));
#pragma unroll
        for (int ni = 0; ni < 4; ni++)
            bfr[ni] = *(const short8*)(Bs + ((wn + (ni << 4) + lq) << 5) + (quad << 3));
#pragma unroll
        for (int mi = 0; mi < 4; mi++)
#pragma unroll
            for (int ni = 0; ni < 4; ni++)
                acc[mi][ni] = __builtin_amdgcn_mfma_f32_16x16x32_bf16(
                    af[mi], bfr[ni], acc[mi][ni], 0, 0, 0);
    }
    bool isK = (n0 < 1024);
#pragma unroll
    for (int ni = 0; ni < 4; ni++) {
        int col = n0 + wn + (ni << 4) + lq;
        if (isK) {
            int h = col >> 6, dc = (col >> 3) & 7, di = col & 7;
#pragma unroll
            for (int mi = 0; mi < 4; mi++)
#pragma unroll
                for (int r = 0; r < 4; r++) {
                    int row = m0 + wm + (mi << 4) + (quad << 2) + r;
                    int jg = row - rb;
                    int b = jg >> (10 - s);
                    int j = jg & (Ls - 1);
                    int bh = (b << 4) | h;
                    size_t addr = doff + (((size_t)bh * (Ls >> 4) + (j >> 4)) << 10) +
                                  (dc << 7) + ((j & 15) << 3) + di;
                    kfrall[addr] = f2bf(acc[mi][ni][r]);
                }
        } else {
#pragma unroll
            for (int mi = 0; mi < 4; mi++)
#pragma unroll
                for (int r = 0; r < 4; r++) {
                    int row = m0 + wm + (mi << 4) + (quad << 2) + r;
                    kvall[(size_t)row * N + col] = f2bf(acc[mi][ni][r]);
                }
        }
    }
}

// ---------------------------------------------------------------- split-K GEMM
// blockIdx.z selects K-slice; fp32 partials to Cout + z*M*N. Bias at z==0.
__global__ __launch_bounds__(256) void mgemm_pk_kernel(
    const short* __restrict__ A, const short* __restrict__ Bt,
    const float* __restrict__ bias, float* __restrict__ Cout,
    int M, int N, int Kfull, int KH) {
    __shared__ short As[128 * 32];
    __shared__ short Bs[128 * 32];
    int kz = blockIdx.z;
    const short* Ab = A + (size_t)kz * KH;
    const short* Btb = Bt + (size_t)kz * KH;
    float* Co = Cout + (size_t)kz * M * N;
    int tid = threadIdx.x;
    int wave = tid >> 6, lane = tid & 63;
    int lq = lane & 15, quad = lane >> 4;
    int m0 = blockIdx.y << 7, n0 = blockIdx.x << 7;
    int wm = (wave & 1) << 6, wn = (wave >> 1) << 6;
    int r0 = tid >> 2, r1 = (256 + tid) >> 2;
    int kc0 = (tid & 3) << 3;
    const short* Ag0 = Ab + (size_t)(m0 + r0) * Kfull + kc0;
    const short* Ag1 = Ab + (size_t)(m0 + r1) * Kfull + kc0;
    const short* Bg0 = Btb + (size_t)(n0 + r0) * Kfull + kc0;
    const short* Bg1 = Btb + (size_t)(n0 + r1) * Kfull + kc0;
    float4v acc[4][4];
#pragma unroll
    for (int mi = 0; mi < 4; mi++)
#pragma unroll
        for (int ni = 0; ni < 4; ni++) acc[mi][ni] = (float4v){0.f, 0.f, 0.f, 0.f};
    for (int k0 = 0; k0 < KH; k0 += 32) {
        __syncthreads();
        GLOAD_LDS16(Ag0 + k0, As + tid * 8);
        GLOAD_LDS16(Ag1 + k0, As + (256 + tid) * 8);
        GLOAD_LDS16(Bg0 + k0, Bs + tid * 8);
        GLOAD_LDS16(Bg1 + k0, Bs + (256 + tid) * 8);
        __syncthreads();
        short8 af[4], bfr[4];
#pragma unroll
        for (int mi = 0; mi < 4; mi++)
            af[mi] = *(const short8*)(As + ((wm + (mi << 4) + lq) << 5) + (quad << 3));
#pragma unroll
        for (int ni = 0; ni < 4; ni++)
            bfr[ni] = *(const short8*)(Bs + ((wn + (ni << 4) + lq) << 5) + (quad << 3));
#pragma unroll
        for (int mi = 0; mi < 4; mi++)
#pragma unroll
            for (int ni = 0; ni < 4; ni++)
                acc[mi][ni] = __builtin_amdgcn_mfma_f32_16x16x32_bf16(
                    af[mi], bfr[ni], acc[mi][ni], 0, 0, 0);
    }
#pragma unroll
    for (int ni = 0; ni < 4; ni++) {
        int col = n0 + wn + (ni << 4) + lq;
        float bv = (bias && kz == 0) ? bias[col] : 0.f;
#pragma unroll
        for (int mi = 0; mi < 4; mi++)
#pragma unroll
            for (int r = 0; r < 4; r++) {
                int row = m0 + wm + (mi << 4) + (quad << 2) + r;
                Co[(size_t)row * N + col] = acc[mi][ni][r] + bv;
            }
    }
}

// sum of 4 fp32 partial slabs -> bf16
__global__ __launch_bounds__(256) void sumcast4_kernel(
    const float* __restrict__ p, size_t stride, short* __restrict__ outp) {
    int idx = (blockIdx.x * 256 + threadIdx.x) << 2;
    float4 a0 = *(const float4*)&p[idx];
    float4 a1 = *(const float4*)&p[stride + idx];
    float4 a2 = *(const float4*)&p[2 * stride + idx];
    float4 a3 = *(const float4*)&p[3 * stride + idx];
    ushort4 u;
    u.x = (unsigned short)f2bf(a0.x + a1.x + a2.x + a3.x);
    u.y = (unsigned short)f2bf(a0.y + a1.y + a2.y + a3.y);
    u.z = (unsigned short)f2bf(a0.z + a1.z + a2.z + a3.z);
    u.w = (unsigned short)f2bf(a0.w + a1.w + a2.w + a3.w);
    *(ushort4*)&outp[idx] = u;
}

// ---------------------------------------------------------------- conv tap-split
__global__ __launch_bounds__(256) void convdil_pk_kernel(
    const short* __restrict__ xp, const short* __restrict__ Wt,
    float* __restrict__ pbuf) {
    __shared__ short As[128 * 32];
    __shared__ short Bs[128 * 32];
    int kp = blockIdx.z;
    int tid = threadIdx.x;
    int wave = tid >> 6, lane = tid & 63;
    int lq = lane & 15, quad = lane >> 4;
    int m0 = blockIdx.y << 7, n0 = blockIdx.x << 7;
    int wm = (wave & 1) << 6, wn = (wave >> 1) << 6;
    int b = m0 >> 10, ll0 = m0 & 1023;
    int r0 = tid >> 2, r1 = (256 + tid) >> 2;
    int kc = (tid & 3) << 3;
    float* Co = pbuf + (size_t)kp * DB * DL * DD;
    const short* Abase = xp + ((size_t)(b * 1028 + ll0 + 2 * kp)) * DD + kc;
    const short* Bbase = Wt + (size_t)kp * DD * DD;
    const short* Bg0 = Bbase + (size_t)(n0 + r0) * DD + kc;
    const short* Bg1 = Bbase + (size_t)(n0 + r1) * DD + kc;
    float4v acc[4][4];
#pragma unroll
    for (int mi = 0; mi < 4; mi++)
#pragma unroll
        for (int ni = 0; ni < 4; ni++) acc[mi][ni] = (float4v){0.f, 0.f, 0.f, 0.f};
    for (int k0 = 0; k0 < DD; k0 += 32) {
        __syncthreads();
        GLOAD_LDS16(Abase + (size_t)r0 * DD + k0, As + tid * 8);
        GLOAD_LDS16(Abase + (size_t)r1 * DD + k0, As + (256 + tid) * 8);
        GLOAD_LDS16(Bg0 + k0, Bs + tid * 8);
        GLOAD_LDS16(Bg1 + k0, Bs + (256 + tid) * 8);
        __syncthreads();
        short8 af[4], bfr[4];
#pragma unroll
        for (int mi = 0; mi < 4; mi++)
            af[mi] = *(const short8*)(As + ((wm + (mi << 4) + lq) << 5) + (quad << 3));
#pragma unroll
        for (int ni = 0; ni < 4; ni++)
            bfr[ni] = *(const short8*)(Bs + ((wn + (ni << 4) + lq) << 5) + (quad << 3));
#pragma unroll
        for (int mi = 0; mi < 4; mi++)
#pragma unroll
            for (int ni = 0; ni < 4; ni++)
                acc[mi][ni] = __builtin_amdgcn_mfma_f32_16x16x32_bf16(
                    af[mi], bfr[ni], acc[mi][ni], 0, 0, 0);
    }
#pragma unroll
    for (int ni = 0; ni < 4; ni++) {
        int col = n0 + wn + (ni << 4) + lq;
#pragma unroll
        for (int mi = 0; mi < 4; mi++)
#pragma unroll
            for (int r = 0; r < 4; r++) {
                int row = m0 + wm + (mi << 4) + (quad << 2) + r;
                Co[(size_t)row * DD + col] = acc[mi][ni][r];
            }
    }
}

// xcb = bf16(relu(p0+p1+p2 + bias)), 4 elems/thread over 4M
__global__ __launch_bounds__(256) void convcomb_kernel(
    const float* __restrict__ pbuf, const float* __restrict__ bvec,
    short* __restrict__ xcb) {
    const size_t M4 = (size_t)DB * DL * DD;
    int idx = (blockIdx.x * 256 + threadIdx.x) << 2;
    int col = idx & 1023;
    float4 p0 = *(const float4*)&pbuf[idx];
    float4 p1 = *(const float4*)&pbuf[M4 + idx];
    float4 p2 = *(const float4*)&pbuf[2 * M4 + idx];
    float4 bb = *(const float4*)&bvec[col];
    ushort4 u;
    u.x = (unsigned short)f2bf(fmaxf(p0.x + p1.x + p2.x + bb.x, 0.f));
    u.y = (unsigned short)f2bf(fmaxf(p0.y + p1.y + p2.y + bb.y, 0.f));
    u.z = (unsigned short)f2bf(fmaxf(p0.z + p1.z + p2.z + bb.z, 0.f));
    u.w = (unsigned short)f2bf(fmaxf(p0.w + p1.w + p2.w + bb.w, 0.f));
    *(ushort4*)&xcb[idx] = u;
}

// ---------------------------------------------------------------- V fragment prep
__global__ __launch_bounds__(256) void vfrag_all_kernel(const short* __restrict__ kvall,
                                                        short* __restrict__ vfr0) {
    __shared__ short tile[32][33];
    int flat = blockIdx.x;                          // 0..7679
    int s, base, rb;
    size_t doff;
    if (flat < 4096)      { s = 0; base = 0;    rb = 0;    doff = 0; }
    else if (flat < 6144) { s = 1; base = 4096; rb = 4096; doff = 4194304; }
    else if (flat < 7168) { s = 2; base = 6144; rb = 6144; doff = 6291456; }
    else                  { s = 3; base = 7168; rb = 7168; doff = 7340032; }
    int rem = flat - base;
    int Ls = DL >> s;
    int nt = Ls >> 5;
    int j0t = rem & (nt - 1);
    int rest = rem >> (5 - s);
    int dt = rest & 1;
    int bh = rest >> 1;
    int j0 = j0t << 5, d0 = dt << 5;
    int b = bh >> 4, h = bh & 15;
    int tid = threadIdx.x;
    int cc = tid & 31, rr = tid >> 5;
#pragma unroll
    for (int p = 0; p < 4; p++) {
        int jj = (p << 3) + rr;
        tile[jj][cc] = kvall[((size_t)(rb + b * Ls + j0 + jj) << 11) + 1024 +
                             (h << 6) + d0 + cc];
    }
    __syncthreads();
    int c = j0 >> 6, ks = (j0 >> 5) & 1;
#pragma unroll
    for (int p = 0; p < 4; p++) {
        int d = d0 + (p << 3) + rr;
        int tt = d >> 4, lqv = d & 15;
        size_t off = doff + (((size_t)bh * (Ls >> 6) + c) << 12) + (ks << 11) +
                     (tt << 9) + (lqv << 5) + cc;
        vfr0[off] = tile[cc][(p << 3) + rr];
    }
}

// ---------------------------------------------------------------- attention
// Barrier-free flash attention with XCD-locality swizzle: blockIdx.x = bh
// (linear id % 8 == bh % 8 -> all q-tiles of one head on one XCD; per-XCD
// K/V footprint ~4 MB = L2 size). 4 independent waves x 16 q-rows, each
// sweeping all 4 scales; convex aggregation in-register; zero __syncthreads.
__global__ __launch_bounds__(256) void attn_fused6_kernel(
    const short* __restrict__ qb4, const short* __restrict__ kfr0,
    const short* __restrict__ vfr0, const float* __restrict__ wagg,
    short* __restrict__ attb) {
    __shared__ __align__(16) short plds[4][16][72];
    int tid = threadIdx.x;
    int w = tid >> 6, lane = tid & 63;
    int lq = lane & 15, quad = lane >> 4;
    int bh = blockIdx.x;                 // XCD-local: id%8 == bh%8
    int b = bh >> 4, h = bh & 15;
    int qrow0 = b * DL + (blockIdx.y << 6) + (w << 4);
    const float c_exp = 0.18033688f;    // log2(e)/8

    float fin[4][4];
#pragma unroll
    for (int t = 0; t < 4; t++)
#pragma unroll
        for (int r = 0; r < 4; r++) fin[t][r] = 0.f;

#pragma unroll 1
    for (int s = 0; s < 4; s++) {
        int Ls = DL >> s;
        size_t doff = s == 0 ? 0 : s == 1 ? 4194304 : s == 2 ? 6291456 : 7340032;

        const short* qbase = qb4 + ((size_t)(qrow0 + lq) << 12) + (s << 10) +
                             (h << 6) + (quad << 3);
        short8 qf0 = *(const short8*)qbase;
        short8 qf1 = *(const short8*)(qbase + 32);

        const short* kfb = kfr0 + doff + (((size_t)bh * (Ls >> 4)) << 10) +
                           (quad << 7) + (lq << 3);
        const short* vfb = vfr0 + doff + (((size_t)bh * (Ls >> 6)) << 12) +
                           (lq << 5) + (quad << 3);

        float4v O[4];
        float lpart[4] = {0.f, 0.f, 0.f, 0.f};
#pragma unroll
        for (int t = 0; t < 4; t++) O[t] = (float4v){0.f, 0.f, 0.f, 0.f};

        for (int c0 = 0; c0 < Ls; c0 += 64) {
            float4v S[4];
            int g0 = c0 >> 4;
#pragma unroll
            for (int t = 0; t < 4; t++) {
                const short* kp = kfb + ((size_t)(g0 + t) << 10);
                short8 kf0 = *(const short8*)kp;
                short8 kf1 = *(const short8*)(kp + 512);
                float4v z = (float4v){0.f, 0.f, 0.f, 0.f};
                z = __builtin_amdgcn_mfma_f32_16x16x32_bf16(qf0, kf0, z, 0, 0, 0);
                S[t] = __builtin_amdgcn_mfma_f32_16x16x32_bf16(qf1, kf1, z, 0, 0, 0);
            }
#pragma unroll
            for (int t = 0; t < 4; t++)
#pragma unroll
                for (int r = 0; r < 4; r++) {
                    float p = exp2f(S[t][r] * c_exp);
                    lpart[r] += p;
                    plds[w][(quad << 2) + r][(t << 4) + lq] =
                        (short)(__float_as_uint(p) >> 16);   // trunc-bf16
                }
            const short* vcb = vfb + ((size_t)(c0 >> 6) << 12);
#pragma unroll
            for (int ks = 0; ks < 2; ks++) {
                short8 af = *(const short8*)&plds[w][lq][(ks << 5) + (quad << 3)];
#pragma unroll
                for (int t = 0; t < 4; t++) {
                    short8 vf = *(const short8*)(vcb + (ks << 11) + (t << 9));
                    O[t] = __builtin_amdgcn_mfma_f32_16x16x32_bf16(af, vf, O[t], 0, 0, 0);
                }
            }
        }
        float wsc = wagg[s];
#pragma unroll
        for (int r = 0; r < 4; r++) {
            float l = lpart[r];
            l += __shfl_xor(l, 1, 64);
            l += __shfl_xor(l, 2, 64);
            l += __shfl_xor(l, 4, 64);
            l += __shfl_xor(l, 8, 64);
            float linv = wsc / l;
#pragma unroll
            for (int t = 0; t < 4; t++) fin[t][r] += O[t][r] * linv;
        }
    }
#pragma unroll
    for (int r = 0; r < 4; r++) {
        size_t rbase = ((size_t)(qrow0 + (quad << 2) + r) << 10) + (h << 6) + lq;
#pragma unroll
        for (int t = 0; t < 4; t++)
            attb[rbase + (t << 4)] = f2bf(fin[t][r]);
    }
}

// ---------------------------------------------------------------- add-N + LN
// out = LN(a + sum_j pb[j*pstride + .]); OBF: also write bf16 copy.
template <int NP, int OBF>
__global__ __launch_bounds__(256) void addlnN_kernel(
    const float* __restrict__ a, const float* __restrict__ pb, size_t pstride,
    const float* __restrict__ gam, const float* __restrict__ bet,
    float* __restrict__ out, short* __restrict__ outb) {
    __shared__ float redA[4], redB[4];
    int row = blockIdx.x, tid = threadIdx.x;
    size_t base = (size_t)row * DD + (tid << 2);
    float4 av = *(const float4*)&a[base];
    float s0 = av.x, s1 = av.y, s2 = av.z, s3 = av.w;
#pragma unroll
    for (int j = 0; j < NP; j++) {
        float4 pv = *(const float4*)&pb[(size_t)j * pstride + base];
        s0 += pv.x; s1 += pv.y; s2 += pv.z; s3 += pv.w;
    }
    float lsum = s0 + s1 + s2 + s3;
    float lsq = s0 * s0 + s1 * s1 + s2 * s2 + s3 * s3;
#pragma unroll
    for (int o = 32; o > 0; o >>= 1) {
        lsum += __shfl_down(lsum, o, 64);
        lsq += __shfl_down(lsq, o, 64);
    }
    int lane = tid & 63, wid = tid >> 6;
    if (lane == 0) { redA[wid] = lsum; redB[wid] = lsq; }
    __syncthreads();
    float tsum = redA[0] + redA[1] + redA[2] + redA[3];
    float tsq = redB[0] + redB[1] + redB[2] + redB[3];
    float mean = tsum * (1.0f / DD);
    float var = tsq * (1.0f / DD) - mean * mean;
    float rstd = rsqrtf(var + 1e-5f);
    float4 gv = *(const float4*)&gam[tid << 2];
    float4 bev = *(const float4*)&bet[tid << 2];
    float4 o;
    o.x = (s0 - mean) * rstd * gv.x + bev.x;
    o.y = (s1 - mean) * rstd * gv.y + bev.y;
    o.z = (s2 - mean) * rstd * gv.z + bev.z;
    o.w = (s3 - mean) * rstd * gv.w + bev.w;
    *(float4*)&out[base] = o;
    if (OBF) {
        ushort4 u;
        u.x = (unsigned short)f2bf(o.x);
        u.y = (unsigned short)f2bf(o.y);
        u.z = (unsigned short)f2bf(o.z);
        u.w = (unsigned short)f2bf(o.w);
        *(ushort4*)&outb[base] = u;
    }
}

// ---------------------------------------------------------------- launcher
extern "C" void kernel_launch(void* const* d_in, const int* in_sizes, int n_in,
                              void* d_out, int out_size, void* d_ws, size_t ws_size,
                              hipStream_t stream) {
    (void)in_sizes; (void)n_in; (void)out_size; (void)ws_size;
    const float* x   = (const float*)d_in[0];
    const float* Wdc = (const float*)d_in[1];
    const float* bdc = (const float*)d_in[2];
    const float* Wdec= (const float*)d_in[3];
    const float* Wq  = (const float*)d_in[4];
    const float* Wk  = (const float*)d_in[5];
    const float* Wv  = (const float*)d_in[6];
    const float* Wo  = (const float*)d_in[7];
    const float* agg = (const float*)d_in[8];
    const float* g1  = (const float*)d_in[9];
    const float* be1 = (const float*)d_in[10];
    const float* g2  = (const float*)d_in[11];
    const float* be2 = (const float*)d_in[12];
    const float* W1  = (const float*)d_in[13];
    const float* b1  = (const float*)d_in[14];
    const float* W2  = (const float*)d_in[15];
    const float* b2  = (const float*)d_in[16];
    float* out = (float*)d_out;

    float* ws = (float*)d_ws;
    size_t off = 0;
    auto alloc = [&](size_t nfloats) { float* p = ws + off; off += nfloats; return p; };
    const size_t M1 = 1024 * 1024;
    short* wdc_bt  = (short*)alloc(3 * M1 / 2);
    short* wdec_bt = (short*)alloc(3 * M1);
    short* wq4t    = (short*)alloc(2 * M1);
    short* wkvt    = (short*)alloc(4 * M1);
    short* wot     = (short*)alloc(M1 / 2);
    short* w1t     = (short*)alloc(2 * M1);
    short* w2t     = (short*)alloc(2 * M1);
    float* wagg    = alloc(64);
    short* xpad    = (short*)alloc(2105344);
    // activation buffers: contiguous rows 0..7679 for grouped KV GEMM
    short* xcb     = (short*)alloc(2 * M1);         // rows [0,4096)
    short* s1b     = (short*)alloc(M1);             // rows [4096,6144)
    short* s2b     = (short*)alloc(M1 / 2);         // rows [6144,7168)
    short* s3b     = (short*)alloc(M1 / 4);         // rows [7168,7680)
    short* qb4     = (short*)alloc(8 * M1);         // later FFN hidden; conv partials first
    short* kvall   = (short*)alloc(7 * M1 + M1 / 2);// V-half rows; FFN2 partials later
    short* kfrall  = (short*)alloc(3 * M1 + 3 * M1 / 4);
    short* vfrall  = (short*)alloc(3 * M1 + 3 * M1 / 4);
    short* attb    = (short*)alloc(2 * M1);
    float* x1      = alloc(4 * M1);
    short* x1b     = (short*)alloc(2 * M1);
    float* pkbuf   = alloc(8 * M1);                 // Wo/dec split-K partials
    short* hb      = qb4;                           // FFN hidden [4096][4096] bf16
    float* convp   = (float*)qb4;                   // conv tap partials (12M fp32:
                                                    //  qb4 8M + kvall first 4M, contiguous)
    float* pk4     = (float*)kvall;                 // FFN2 4x4M fp32 partials
                                                    //  (kvall+kfrall+vfrall+1M of attb; all
                                                    //  dead after attention / Wo)

    dim3 blk(256);
    // ---- fused prep
    prep_all_kernel<<<dim3(74817), blk, 0, stream>>>(
        Wdc, Wdec, Wq, Wk, Wv, Wo, W1, W2, x, agg,
        wdc_bt, wdec_bt, wq4t, wkvt, wot, w1t, w2t, xpad, wagg,
        out + (size_t)DB * DL * DD);

    // 1. dilated conv: tap-split x3 + relu/bias combine
    convdil_pk_kernel<<<dim3(DD / 128, DB * DL / 128, 3), blk, 0, stream>>>(
        xpad, wdc_bt, convp);
    convcomb_kernel<<<dim3(4 * M1 / (256 * 4)), blk, 0, stream>>>(convp, bdc, xcb);

    // 2. decomposition convs: split-K x4 each (512/256/128 blocks) + sum-cast
    mgemm_pk_kernel<<<dim3(8, 16, 4), blk, 0, stream>>>(
        xcb, wdec_bt, nullptr, pkbuf, 2048, DD, 2 * DD, 512);
    sumcast4_kernel<<<dim3(2 * M1 / 1024), blk, 0, stream>>>(pkbuf, 2 * M1, s1b);
    mgemm_pk_kernel<<<dim3(8, 8, 4), blk, 0, stream>>>(
        s1b, wdec_bt + 2 * M1, nullptr, pkbuf, 1024, DD, 2 * DD, 512);
    sumcast4_kernel<<<dim3(M1 / 1024), blk, 0, stream>>>(pkbuf, M1, s2b);
    mgemm_pk_kernel<<<dim3(8, 4, 4), blk, 0, stream>>>(
        s2b, wdec_bt + 4 * M1, nullptr, pkbuf, 512, DD, 2 * DD, 512);
    sumcast4_kernel<<<dim3(M1 / 2048), blk, 0, stream>>>(pkbuf, M1 / 2, s3b);

    // 3a. batched Q projection (all 4 scales, N=4096)
    mgemm_kernel<0, 1><<<dim3(32, 32), blk, 0, stream>>>(
        xcb, wq4t, nullptr, qb4, DB * DL, 4 * DD, DD);

    // 3b. grouped K|V projection (K-half straight to fragment layout)
    kvgemm_kernel<<<dim3(16, 60), blk, 0, stream>>>(xcb, wkvt, kvall, kfrall);

    // 3c. V fragment prep
    vfrag_all_kernel<<<dim3(7680), blk, 0, stream>>>(kvall, vfrall);

    // 3d. fused attention, XCD-locality swizzled (bh fastest grid dim)
    attn_fused6_kernel<<<dim3(DB * DH, DL / 64), blk, 0, stream>>>(
        qb4, kfrall, vfrall, wagg, attb);

    // 4. shared output projection (split-K x2)
    mgemm_pk_kernel<<<dim3(8, 32, 2), blk, 0, stream>>>(
        attb, wot, nullptr, pkbuf, DB * DL, DD, DD, DD / 2);

    // 5. residual + LN1 (2 partials)
    addlnN_kernel<2, 1><<<dim3(DB * DL), blk, 0, stream>>>(
        x, pkbuf, 4 * M1, g1, be1, x1, x1b);

    // 6. FFN: GELU GEMM then split-K x4 down-projection (1024 blocks)
    mgemm_kernel<1, 1><<<dim3(DF / 128, (DB * DL) / 128), blk, 0, stream>>>(
        x1b, w1t, b1, hb, DB * DL, DF, DD);
    mgemm_pk_kernel<<<dim3(8, 32, 4), blk, 0, stream>>>(
        hb, w2t, b2, pk4, DB * DL, DD, DF, DF / 4);

    // 7. residual + LN2 -> out (4 partials)
    addlnN_kernel<4, 0><<<dim3(DB * DL), blk, 0, stream>>>(
        x1, pk4, 4 * M1, g2, be2, out, nullptr);
}